// Round 12
// baseline (1080.308 us; speedup 1.0000x reference)
//
#include <hip/hip_runtime.h>
#include <hip/hip_bf16.h>

__global__ void IGMC_15247133901635_kernel() {}

#define cG 5
#define cN 50000
#define cE 250000
#define cB 50
#define cL 200
#define cD 64
#define cR 5
#define cNR 250000
#define cGB 500
#define NBLK 977

// ---------------- fast-path workspace layout (bytes) ----------------
#define FP_UIDX   0
#define FP_BSUM   4096
#define FP_XLIST  28672
#define FP_EMBOUT 540672
#define FP_ATTK   668672
#define FP_METAH  672768
#define FP_XCAT   775168
#define FP_SAG    1159168
#define FP_INV    1559168
#define FP_CLS    2559168
#define FP_HA     3559168
#define FP_HB     9959168
#define FP_CUR    16359168
#define FP_OFF    21359168
#define FP_PERM   26359168
#define FP_INVC   31359168
#define FP_NEED   36359168ULL
// ---- pruned-path extras (tier 1) ----
#define FP2_MARK   36359168
#define FP2_LIST   37359168
#define FP2_CNT    38359168
#define FP2_COUNTS 38363264
#define FP2_NEED   38367360ULL

// ---------- per-graph prep (fallback) ----------
__global__ void k_prep(const float* xg, int* cls, int* cur) {
  int i = blockIdx.x * 256 + threadIdx.x;
  if (i < cNR) cur[i] = 0;
  if (i < cN) {
    int c = 0;
    if (xg[i * 4 + 1] == 1.0f) c = 1;
    else if (xg[i * 4 + 2] == 1.0f) c = 2;
    else if (xg[i * 4 + 3] == 1.0f) c = 3;
    cls[i] = c;
  }
}

__global__ void k_histg(const int* eid, const int* etg, int* cur) {
  int e = blockIdx.x * 256 + threadIdx.x;
  if (e < cE) atomicAdd(&cur[eid[e] * cR + etg[e]], 1);
}

__global__ void k_bsum(const int* cur, int* bsum) {
  __shared__ int sC[256];
  int t = threadIdx.x;
  int i = blockIdx.x * 256 + t;
  sC[t] = (i < cNR) ? cur[i] : 0;
  __syncthreads();
  for (int s = 128; s > 0; s >>= 1) {
    if (t < s) sC[t] += sC[t + s];
    __syncthreads();
  }
  if (t == 0) bsum[blockIdx.x] = sC[0];
}

__global__ void __launch_bounds__(1024) k_bscan(int* bsum) {
  __shared__ int sS[1024];
  int t = threadIdx.x;
  int v = (t < NBLK) ? bsum[t] : 0;
  sS[t] = v;
  __syncthreads();
  for (int off = 1; off < 1024; off <<= 1) {
    int add = (t >= off) ? sS[t - off] : 0;
    __syncthreads();
    sS[t] += add;
    __syncthreads();
  }
  if (t < NBLK) bsum[t] = sS[t] - v;
}

__global__ void k_mkoff(int* cur, int* off, const int* bbase) {
  __shared__ int sC[256];
  __shared__ int sO[256];
  int t = threadIdx.x;
  int i = blockIdx.x * 256 + t;
  int c = (i < cNR) ? cur[i] : 0;
  sC[t] = c;
  __syncthreads();
  if (t == 0) {
    int run = 0;
    for (int k = 0; k < 256; k++) { sO[k] = run; run += sC[k]; }
  }
  __syncthreads();
  if (i < cNR) {
    int v = bbase[blockIdx.x] + sO[t];
    off[i] = v;
    cur[i] = v;
  }
}

__global__ void k_scatter(const int* eis, const int* eid, const int* etg,
                          const int* cls, int* cur, int* perm) {
  int e = blockIdx.x * 256 + threadIdx.x;
  if (e >= cE) return;
  int src = eis[e];
  int r = etg[e];
  int bin = eid[e] * cR + r;
  int pos = atomicAdd(&cur[bin], 1);
  perm[pos] = src * 32 + r * 4 + cls[src];
}

__global__ void k_invc(const int* off, const int* cur, float* invc) {
  int i = blockIdx.x * 256 + threadIdx.x;
  if (i >= cNR) return;
  int st = off[i], en = cur[i];
  if (en > st) {
    float ic = 1.0f / (float)(en - st);
    for (int j = st; j < en; j++) invc[j] = ic;
  }
}

// ---------- batched CSR build (fast path): grid = 5*NBLK ----------
__global__ void k_prepB(const float* x, int* clsA, int* curA, int* markA) {
  int g = blockIdx.x / NBLK;
  int i = (blockIdx.x - g * NBLK) * 256 + threadIdx.x;
  if (i < cNR) curA[g * cNR + i] = 0;
  if (i < cN) {
    const float* xg = x + (long long)g * cN * 4;
    int c = 0;
    if (xg[i * 4 + 1] == 1.0f) c = 1;
    else if (xg[i * 4 + 2] == 1.0f) c = 2;
    else if (xg[i * 4 + 3] == 1.0f) c = 3;
    clsA[g * cN + i] = c;
    if (markA) markA[g * cN + i] = 0;
  }
}

__global__ void k_histgB(const int* ei, const int* et, int* curA) {
  int g = blockIdx.x / NBLK;
  int e = (blockIdx.x - g * NBLK) * 256 + threadIdx.x;
  if (e >= cE) return;
  const int* eid = ei + (long long)g * 2 * cE + cE;
  const int* etg = et + (long long)g * cE;
  atomicAdd(&curA[g * cNR + eid[e] * cR + etg[e]], 1);
}

__global__ void k_bsumB(const int* curA, int* bsumA) {
  __shared__ int sC[256];
  int g = blockIdx.x / NBLK;
  int b2 = blockIdx.x - g * NBLK;
  int t = threadIdx.x;
  int i = b2 * 256 + t;
  sC[t] = (i < cNR) ? curA[g * cNR + i] : 0;
  __syncthreads();
  for (int s = 128; s > 0; s >>= 1) {
    if (t < s) sC[t] += sC[t + s];
    __syncthreads();
  }
  if (t == 0) bsumA[g * NBLK + b2] = sC[0];
}

__global__ void __launch_bounds__(1024) k_bscanB(int* bsumA) {
  __shared__ int sS[1024];
  int g = blockIdx.x;   // grid = 5
  int t = threadIdx.x;
  int v = (t < NBLK) ? bsumA[g * NBLK + t] : 0;
  sS[t] = v;
  __syncthreads();
  for (int off = 1; off < 1024; off <<= 1) {
    int add = (t >= off) ? sS[t - off] : 0;
    __syncthreads();
    sS[t] += add;
    __syncthreads();
  }
  if (t < NBLK) bsumA[g * NBLK + t] = sS[t] - v;
}

// invc fill fused in (curA holds bin counts here; values/positions
// identical to the old separate k_invcB pass).
__global__ void k_mkoffB(int* curA, int* offA, const int* bsumA, float* invcA) {
  __shared__ int sC[256];
  __shared__ int sO[256];
  int g = blockIdx.x / NBLK;
  int b2 = blockIdx.x - g * NBLK;
  int t = threadIdx.x;
  int i = b2 * 256 + t;
  int c = (i < cNR) ? curA[g * cNR + i] : 0;
  sC[t] = c;
  __syncthreads();
  if (t == 0) {
    int run = 0;
    for (int k = 0; k < 256; k++) { sO[k] = run; run += sC[k]; }
  }
  __syncthreads();
  if (i < cNR) {
    int v = bsumA[g * NBLK + b2] + sO[t];
    offA[g * cNR + i] = v;
    curA[g * cNR + i] = v;
    if (c > 0) {
      float ic = 1.0f / (float)c;
      float* invc = invcA + (long long)g * cE;
      for (int j = v; j < v + c; j++) invc[j] = ic;
    }
  }
}

__global__ void k_scatterB(const int* ei, const int* et, const int* clsA,
                           int* curA, int* permA) {
  int g = blockIdx.x / NBLK;
  int e = (blockIdx.x - g * NBLK) * 256 + threadIdx.x;
  if (e >= cE) return;
  const int* eis = ei + (long long)g * 2 * cE;
  const int* eid = eis + cE;
  const int* etg = et + (long long)g * cE;
  int src = eis[e];
  int r = etg[e];
  int pos = atomicAdd(&curA[g * cNR + eid[e] * cR + r], 1);
  permA[g * cE + pos] = src * 32 + r * 4 + clsA[g * cN + src];
}

// ---------- inverse extraction map ----------
__global__ void k_invinit(int* inv) {
  int i = blockIdx.x * 256 + threadIdx.x;
  if (i < cG * cN) inv[i] = -1;
}

__global__ void k_mkinv(const int* uidx, int* inv) {
  int t = threadIdx.x;
  if (t < cG * 2 * cB) {
    int g = t / (2 * cB), r = t - g * 2 * cB;
    int c = r / cB, b = r - c * cB;
    int node = uidx[(g * 2 + c) * cB + b];
    inv[g * cN + node] = (g * cB + b) * 256 + c * 128;
  }
}

// ---------- dependency pruning: BFS over dst-keyed bins ----------
__global__ void k_mark(const int* uidx, int* markA, int* listA, int* cntA,
                       int* counts) {
  int g = blockIdx.x;   // grid = 5, 128 threads
  int t = threadIdx.x;
  if (t == 0) cntA[g] = 0;
  __syncthreads();
  if (t < 2 * cB) {
    int c = t / cB, b = t - c * cB;
    int node = uidx[(g * 2 + c) * cB + b];
    if (atomicExch(&markA[g * cN + node], 1) == 0) {
      int pos = atomicAdd(&cntA[g], 1);
      listA[g * cN + pos] = node;
    }
  }
  __syncthreads();
  if (t == 0) counts[g * 4 + 0] = atomicAdd(&cntA[g], 0);
}

#define EXB 196
__global__ void k_expand(const int* offA, const int* curA, const int* permA,
                         int* markA, int* listA, int* cntA, const int* counts,
                         int k) {
  int g = blockIdx.x / EXB;
  int i = (blockIdx.x - g * EXB) * 256 + threadIdx.x;
  int lo = (k == 1) ? 0 : counts[g * 4 + k - 2];
  int hi = counts[g * 4 + k - 1];
  int idx = lo + i;
  if (idx >= hi) return;
  int n = listA[g * cN + idx];
  int st = offA[g * cNR + n * 5], en = curA[g * cNR + n * 5 + 4];
  const int* perm = permA + (long long)g * cE;
  for (int j = st; j < en; j++) {
    int src = perm[j] >> 5;
    if (atomicExch(&markA[g * cN + src], 1) == 0) {
      int pos = atomicAdd(&cntA[g], 1);
      listA[g * cN + pos] = src;
    }
  }
}

__global__ void k_snap(int* counts, int* cntA, int k) {
  int t = threadIdx.x;
  if (t < cG) counts[t * 4 + k] = atomicAdd(&cntA[t], 0);
}

// ---------- RGCN layer 0 (optional list pruning + fused extract) ----------
__global__ void k_gather0(const int* off, const int* cur, const int* perm,
                          const float* invc, const int* cls, const float* basis0,
                          const float* comp0, const float* root0, const float* bias0,
                          float* hout, const int* inv, float* xlist,
                          const int* list, const int* cntp) {
  int cnt = cN;
  if (cntp) {
    cnt = *cntp;
    if (blockIdx.x * 8 >= cnt) return;
  }
  __shared__ float sW0[640];
  __shared__ float sRt[128];
  __shared__ float sB[32];
  int t = threadIdx.x;
  for (int idx = t; idx < 640; idx += 256) {
    int r = idx / 128, rem = idx - r * 128;
    sW0[idx] = comp0[r * 2] * basis0[rem] + comp0[r * 2 + 1] * basis0[128 + rem];
  }
  if (t < 128) sRt[t] = root0[t];
  if (t < 32) sB[t] = bias0[t];
  __syncthreads();
  int nd = t >> 5, li = t & 31;
  int idx8 = blockIdx.x * 8 + nd;
  int n;
  if (list) n = (idx8 < cnt) ? list[idx8] : list[0];
  else n = idx8;
  int st = off[n * 5], en = cur[n * 5 + 4];
  float tot = 0.0f;
  int j = st;
  for (; j + 1 < en; j += 2) {
    int p0 = perm[j], p1 = perm[j + 1];
    float i0 = invc[j], i1 = invc[j + 1];
    tot += sW0[(p0 & 31) * 32 + li] * i0 + sW0[(p1 & 31) * 32 + li] * i1;
  }
  if (j < en) tot += sW0[(perm[j] & 31) * 32 + li] * invc[j];
  float val = tanhf(tot + sRt[cls[n] * 32 + li] + sB[li]);
  hout[(long long)n * 32 + li] = val;
  if (inv) {
    int iv = inv[n];
    if (iv >= 0) xlist[iv + li] = val;
  }
}

// ---------- RGCN layers 1..3 (optional list pruning + fused extract) ----------
__global__ void k_gatherR(const int* off, const int* cur, const int* perm,
                          const float* invc, const float* hin, const float* basis,
                          const float* comp, const float* root, const float* bias,
                          float* hout, const int* inv, float* xlist, int layer,
                          const int* list, const int* cntp) {
  int cnt = cN;
  if (cntp) {
    cnt = *cntp;
    if (blockIdx.x * 8 >= cnt) return;
  }
  __shared__ float sB0[1024];
  __shared__ float sB1[1024];
  __shared__ float sRt[1024];
  __shared__ float sZ0[8][32];
  __shared__ float sZ1[8][32];
  __shared__ float sHl[8][32];
  __shared__ float sBias[32];
  __shared__ float sC0[8];
  __shared__ float sC1[8];
  int t = threadIdx.x;
  for (int idx = t; idx < 1024; idx += 256) {
    sB0[idx] = basis[idx];
    sB1[idx] = basis[1024 + idx];
    sRt[idx] = root[idx];
  }
  if (t < 32) sBias[t] = bias[t];
  if (t < cR) { sC0[t] = comp[t * 2]; sC1[t] = comp[t * 2 + 1]; }
  __syncthreads();
  int nd = t >> 5, li = t & 31;
  int idx8 = blockIdx.x * 8 + nd;
  int n;
  if (list) n = (idx8 < cnt) ? list[idx8] : list[0];
  else n = idx8;
  sHl[nd][li] = hin[(long long)n * 32 + li];
  int st = off[n * 5], en = cur[n * 5 + 4];
  float z0 = 0.0f, z1 = 0.0f;
  int j = st;
  for (; j + 1 < en; j += 2) {
    int p0 = perm[j], p1 = perm[j + 1];
    float i0 = invc[j], i1 = invc[j + 1];
    float s0 = hin[(long long)(p0 >> 5) * 32 + li];
    float s1 = hin[(long long)(p1 >> 5) * 32 + li];
    int r0 = (p0 >> 2) & 7, r1 = (p1 >> 2) & 7;
    float w00 = sC0[r0] * i0, w10 = sC1[r0] * i0;
    float w01 = sC0[r1] * i1, w11 = sC1[r1] * i1;
    z0 += w00 * s0 + w01 * s1;
    z1 += w10 * s0 + w11 * s1;
  }
  if (j < en) {
    int p0 = perm[j];
    float i0 = invc[j];
    float s0 = hin[(long long)(p0 >> 5) * 32 + li];
    int r0 = (p0 >> 2) & 7;
    z0 += sC0[r0] * i0 * s0;
    z1 += sC1[r0] * i0 * s0;
  }
  sZ0[nd][li] = z0;
  sZ1[nd][li] = z1;
  __syncthreads();
  float a = sBias[li];
  for (int i = 0; i < 32; i++)
    a += sZ0[nd][i] * sB0[i * 32 + li] + sZ1[nd][i] * sB1[i * 32 + li] +
         sHl[nd][i] * sRt[i * 32 + li];
  float val = tanhf(a);
  hout[(long long)n * 32 + li] = val;
  if (inv) {
    int iv = inv[n];
    if (iv >= 0) xlist[iv + layer * 32 + li] = val;
  }
}

// ---------- ordered compaction: first cB nodes with x[:,c]==1 ----------
__global__ void k_uidx(const float* x, int* uidx) {
  int g = blockIdx.x >> 1, c = blockIdx.x & 1;
  __shared__ int sFlag[256];
  __shared__ int sBase;
  int t = threadIdx.x;
  if (t < cB) uidx[(g * 2 + c) * cB + t] = 0;
  if (t == 0) sBase = 0;
  __syncthreads();
  for (int chunk = 0; chunk < cN; chunk += 256) {
    int n = chunk + t;
    sFlag[t] = (n < cN && x[((long long)g * cN + n) * 4 + c] == 1.0f) ? 1 : 0;
    __syncthreads();
    if (t == 0) {
      int base = sBase;
      for (int t2 = 0; t2 < 256; t2++) {
        if (sFlag[t2]) {
          if (base < cB) uidx[(g * 2 + c) * cB + base] = chunk + t2;
          base++;
        }
      }
      sBase = base;
    }
    __syncthreads();
    if (sBase >= cB) break;
  }
}

__global__ void k_extract(const float* h, const int* uidx, float* xlist, int g, int layer) {
  int i = blockIdx.x * 256 + threadIdx.x;
  if (i >= 2 * cB * 32) return;
  int o = i & 31;
  int rest = i >> 5;
  int b = rest % cB, c = rest / cB;
  int node = uidx[(g * 2 + c) * cB + b];
  xlist[(g * cB + b) * 256 + c * 128 + layer * 32 + o] = h[(long long)node * 32 + o];
}

// ---------- STAM: fused QKV + attention v6 ----------
__global__ void k_attn2(const int* tt, const float* emb, const float* pos,
                        const float* Qw, const float* Kw, const float* Vw,
                        float* hatt, int gb_base) {
  int gbl = blockIdx.x >> 2, hh = blockIdx.x & 3;
  int gb = gb_base + gbl;
  __shared__ float smem[12160];          // 48640 B: QKV 9600 + sT 2*1280
  float* sQ = smem;
  float* sK = smem + 3200;
  float* sV = smem + 6400;
  float* sT = smem + 9600;               // 2 bufs x 20 rows x 64
  int t = threadIdx.x;
  float wreg[64];
  int c48 = t % 48, rgrp = t / 48;       // rgrp<4 for t<192
  int mat = c48 >> 4, dh = c48 & 15;
  if (t < 192) {
    const float* W = (mat == 0) ? Qw : ((mat == 1) ? Kw : Vw);
    const float* wp = W + hh * 16 + dh;
#pragma unroll
    for (int i = 0; i < 64; i += 4) {
      wreg[i] = wp[i * 64];
      wreg[i + 1] = wp[(i + 1) * 64];
      wreg[i + 2] = wp[(i + 2) * 64];
      wreg[i + 3] = wp[(i + 3) * 64];
    }
  }
  const int* ttg = tt + (long long)gb * 200;
  float r[5];
#define LOADC(c)                                                        \
  {                                                                     \
    _Pragma("unroll")                                                   \
    for (int k = 0; k < 5; k++) {                                       \
      int idx = k * 256 + t;                                            \
      int row = idx >> 6, d2 = idx & 63;                                \
      int l = (c) * 20 + row;                                           \
      r[k] = emb[(long long)ttg[l] * 64 + d2] + pos[l * 64 + d2];       \
    }                                                                   \
  }
#define STOREC(pb)                                                      \
  {                                                                     \
    _Pragma("unroll")                                                   \
    for (int k = 0; k < 5; k++) sT[(pb) * 1280 + k * 256 + t] = r[k];   \
  }
  LOADC(0)
  STOREC(0)
  LOADC(1)
  for (int c = 0; c < 10; c++) {
    int p = c & 1;
    if (c >= 1) __syncthreads();
    if (c + 1 < 10) STOREC(1 - p)
    if (c + 2 < 10) LOADC(c + 2)
    __syncthreads();
    if (t < 192) {
      const float* base = sT + p * 1280;
      float acc0 = 0.0f, acc1 = 0.0f, acc2 = 0.0f, acc3 = 0.0f, acc4 = 0.0f;
#pragma unroll
      for (int i4 = 0; i4 < 16; i4++) {
        float w0 = wreg[i4 * 4], w1 = wreg[i4 * 4 + 1],
              w2 = wreg[i4 * 4 + 2], w3 = wreg[i4 * 4 + 3];
        float4 t0 = ((const float4*)(base + (rgrp * 5 + 0) * 64))[i4];
        float4 t1 = ((const float4*)(base + (rgrp * 5 + 1) * 64))[i4];
        float4 t2 = ((const float4*)(base + (rgrp * 5 + 2) * 64))[i4];
        float4 t3 = ((const float4*)(base + (rgrp * 5 + 3) * 64))[i4];
        float4 t4 = ((const float4*)(base + (rgrp * 5 + 4) * 64))[i4];
        acc0 += t0.x * w0 + t0.y * w1 + t0.z * w2 + t0.w * w3;
        acc1 += t1.x * w0 + t1.y * w1 + t1.z * w2 + t1.w * w3;
        acc2 += t2.x * w0 + t2.y * w1 + t2.z * w2 + t2.w * w3;
        acc3 += t3.x * w0 + t3.y * w1 + t3.z * w2 + t3.w * w3;
        acc4 += t4.x * w0 + t4.y * w1 + t4.z * w2 + t4.w * w3;
      }
      float* dst = (mat == 0) ? sQ : ((mat == 1) ? sK : sV);
      int ll = c * 20 + rgrp * 5;
      dst[(ll + 0) * 16 + dh] = acc0;
      dst[(ll + 1) * 16 + dh] = acc1;
      dst[(ll + 2) * 16 + dh] = acc2;
      dst[(ll + 3) * 16 + dh] = acc3;
      dst[(ll + 4) * 16 + dh] = acc4;
    }
  }
#undef LOADC
#undef STOREC
  __syncthreads();
  float4 oa0 = {0,0,0,0}, oa1 = {0,0,0,0}, oa2 = {0,0,0,0}, oa3 = {0,0,0,0};
  float4 ob0 = {0,0,0,0}, ob1 = {0,0,0,0}, ob2 = {0,0,0,0}, ob3 = {0,0,0,0};
  float lsa = 0.0f, lsb = 0.0f;
  if (t < 200) {
    int a = t % 100, mh = t / 100;
    float scale = 1.0f / sqrtf(200.0f);
    const float4* q4 = (const float4*)sQ;
    float4 qa0 = q4[(2 * a) * 4], qa1 = q4[(2 * a) * 4 + 1],
           qa2 = q4[(2 * a) * 4 + 2], qa3 = q4[(2 * a) * 4 + 3];
    float4 qb0 = q4[(2 * a + 1) * 4], qb1 = q4[(2 * a + 1) * 4 + 1],
           qb2 = q4[(2 * a + 1) * 4 + 2], qb3 = q4[(2 * a + 1) * 4 + 3];
    qa0.x *= scale; qa0.y *= scale; qa0.z *= scale; qa0.w *= scale;
    qa1.x *= scale; qa1.y *= scale; qa1.z *= scale; qa1.w *= scale;
    qa2.x *= scale; qa2.y *= scale; qa2.z *= scale; qa2.w *= scale;
    qa3.x *= scale; qa3.y *= scale; qa3.z *= scale; qa3.w *= scale;
    qb0.x *= scale; qb0.y *= scale; qb0.z *= scale; qb0.w *= scale;
    qb1.x *= scale; qb1.y *= scale; qb1.z *= scale; qb1.w *= scale;
    qb2.x *= scale; qb2.y *= scale; qb2.z *= scale; qb2.w *= scale;
    qb3.x *= scale; qb3.y *= scale; qb3.z *= scale; qb3.w *= scale;
    const float4* kk = ((const float4*)sK) + mh * 400;
    const float4* vv = ((const float4*)sV) + mh * 400;
#pragma unroll 2
    for (int m = 0; m < 100; m++) {
      float4 k0 = kk[m * 4], k1 = kk[m * 4 + 1], k2 = kk[m * 4 + 2],
             k3 = kk[m * 4 + 3];
      float sa = qa0.x * k0.x + qa0.y * k0.y + qa0.z * k0.z + qa0.w * k0.w +
                 qa1.x * k1.x + qa1.y * k1.y + qa1.z * k1.z + qa1.w * k1.w +
                 qa2.x * k2.x + qa2.y * k2.y + qa2.z * k2.z + qa2.w * k2.w +
                 qa3.x * k3.x + qa3.y * k3.y + qa3.z * k3.z + qa3.w * k3.w;
      float sb = qb0.x * k0.x + qb0.y * k0.y + qb0.z * k0.z + qb0.w * k0.w +
                 qb1.x * k1.x + qb1.y * k1.y + qb1.z * k1.z + qb1.w * k1.w +
                 qb2.x * k2.x + qb2.y * k2.y + qb2.z * k2.z + qb2.w * k2.w +
                 qb3.x * k3.x + qb3.y * k3.y + qb3.z * k3.z + qb3.w * k3.w;
      float ea = __expf(sa);
      float eb = __expf(sb);
      float4 v0 = vv[m * 4], v1 = vv[m * 4 + 1], v2 = vv[m * 4 + 2],
             v3 = vv[m * 4 + 3];
      lsa += ea; lsb += eb;
      oa0.x += ea * v0.x; oa0.y += ea * v0.y; oa0.z += ea * v0.z; oa0.w += ea * v0.w;
      oa1.x += ea * v1.x; oa1.y += ea * v1.y; oa1.z += ea * v1.z; oa1.w += ea * v1.w;
      oa2.x += ea * v2.x; oa2.y += ea * v2.y; oa2.z += ea * v2.z; oa2.w += ea * v2.w;
      oa3.x += ea * v3.x; oa3.y += ea * v3.y; oa3.z += ea * v3.z; oa3.w += ea * v3.w;
      ob0.x += eb * v0.x; ob0.y += eb * v0.y; ob0.z += eb * v0.z; ob0.w += eb * v0.w;
      ob1.x += eb * v1.x; ob1.y += eb * v1.y; ob1.z += eb * v1.z; ob1.w += eb * v1.w;
      ob2.x += eb * v2.x; ob2.y += eb * v2.y; ob2.z += eb * v2.z; ob2.w += eb * v2.w;
      ob3.x += eb * v3.x; ob3.y += eb * v3.y; ob3.z += eb * v3.z; ob3.w += eb * v3.w;
    }
  }
  __syncthreads();
  if (t < 200) {
    float* pp = smem + t * 34;
    pp[0]  = oa0.x; pp[1]  = oa0.y; pp[2]  = oa0.z; pp[3]  = oa0.w;
    pp[4]  = oa1.x; pp[5]  = oa1.y; pp[6]  = oa1.z; pp[7]  = oa1.w;
    pp[8]  = oa2.x; pp[9]  = oa2.y; pp[10] = oa2.z; pp[11] = oa2.w;
    pp[12] = oa3.x; pp[13] = oa3.y; pp[14] = oa3.z; pp[15] = oa3.w;
    pp[16] = lsa;
    pp[17] = ob0.x; pp[18] = ob0.y; pp[19] = ob0.z; pp[20] = ob0.w;
    pp[21] = ob1.x; pp[22] = ob1.y; pp[23] = ob1.z; pp[24] = ob1.w;
    pp[25] = ob2.x; pp[26] = ob2.y; pp[27] = ob2.z; pp[28] = ob2.w;
    pp[29] = ob3.x; pp[30] = ob3.y; pp[31] = ob3.z; pp[32] = ob3.w;
    pp[33] = lsb;
  }
  __syncthreads();
  if (t < 200) {
    int a = t >> 1, r2 = t & 1;
    const float* p0 = smem + a * 34 + r2 * 17;
    const float* p1 = smem + (100 + a) * 34 + r2 * 17;
    float inv = 1.0f / (p0[16] + p1[16]);
    float4 o0, o1, o2, o3;
    o0.x = (p0[0]  + p1[0])  * inv; o0.y = (p0[1]  + p1[1])  * inv;
    o0.z = (p0[2]  + p1[2])  * inv; o0.w = (p0[3]  + p1[3])  * inv;
    o1.x = (p0[4]  + p1[4])  * inv; o1.y = (p0[5]  + p1[5])  * inv;
    o1.z = (p0[6]  + p1[6])  * inv; o1.w = (p0[7]  + p1[7])  * inv;
    o2.x = (p0[8]  + p1[8])  * inv; o2.y = (p0[9]  + p1[9])  * inv;
    o2.z = (p0[10] + p1[10]) * inv; o2.w = (p0[11] + p1[11]) * inv;
    o3.x = (p0[12] + p1[12]) * inv; o3.y = (p0[13] + p1[13]) * inv;
    o3.z = (p0[14] + p1[14]) * inv; o3.w = (p0[15] + p1[15]) * inv;
    float4* outp = (float4*)(hatt + ((long long)gbl * 200 + t) * 64 + hh * 16);
    outp[0] = o0; outp[1] = o1; outp[2] = o2; outp[3] = o3;
  }
}

// ---------- STAM phase A (fallback): conv -> sAg ----------
__global__ void __launch_bounds__(512, 4) k_conv(
    const float* hatt, const int* tt, const int* cen,
    const float* emb, const float* pos, const float* convW,
    const float* convb, float* sAg, int gb_base) {
  int gbl = blockIdx.x;
  int gb = gb_base + gbl;
  __shared__ float sH[12800];
  int t = threadIdx.x;
  const float4* hb4 = (const float4*)(hatt + (long long)gbl * 12800);
  float4* sH4 = (float4*)sH;
  for (int i = t; i < 3200; i += 512) sH4[i] = hb4[i];
  int og = t >> 6, d = t & 63;
  float w1 = emb[(long long)cen[gb] * 64 + d];
  __syncthreads();
  int o0 = og * 25;
  {
    const float* cwb = convW + o0 * 200;
    float acc[13];
#pragma unroll
    for (int q = 0; q < 13; q++) acc[q] = 0.0f;
    for (int l2 = 0; l2 < 200; l2 += 4) {
      float s0 = sH[(l2 + 0) * 64 + d];
      float s1 = sH[(l2 + 1) * 64 + d];
      float s2 = sH[(l2 + 2) * 64 + d];
      float s3 = sH[(l2 + 3) * 64 + d];
#pragma unroll
      for (int q = 0; q < 13; q++) {
        float4 c4 = *(const float4*)(cwb + q * 200 + l2);
        acc[q] += c4.x * s0 + c4.y * s1 + c4.z * s2 + c4.w * s3;
      }
    }
    float tv[13];
#pragma unroll
    for (int q = 0; q < 13; q++) {
      int o = o0 + q;
      tv[q] = emb[(long long)tt[(long long)gb * 200 + o] * 64 + d] + pos[o * 64 + d];
    }
#pragma unroll
    for (int q = 0; q < 13; q++) {
      int o = o0 + q;
      float outv = tv[q] + acc[q] + convb[o] + sH[o * 64 + d];
      float r1 = outv * outv;
      float r2 = outv * w1;
      for (int s = 32; s > 0; s >>= 1) {
        r1 += __shfl_xor(r1, s);
        r2 += __shfl_xor(r2, s);
      }
      if (d == 0) {
        float dn = sqrtf(r1);
        if (dn < 1e-12f) dn = 1e-12f;
        sAg[(long long)gb * 200 + o] = r2 / dn;
      }
    }
  }
  {
    const float* cwb = convW + (o0 + 13) * 200;
    float acc[12];
#pragma unroll
    for (int q = 0; q < 12; q++) acc[q] = 0.0f;
    for (int l2 = 0; l2 < 200; l2 += 4) {
      float s0 = sH[(l2 + 0) * 64 + d];
      float s1 = sH[(l2 + 1) * 64 + d];
      float s2 = sH[(l2 + 2) * 64 + d];
      float s3 = sH[(l2 + 3) * 64 + d];
#pragma unroll
      for (int q = 0; q < 12; q++) {
        float4 c4 = *(const float4*)(cwb + q * 200 + l2);
        acc[q] += c4.x * s0 + c4.y * s1 + c4.z * s2 + c4.w * s3;
      }
    }
    float tv[12];
#pragma unroll
    for (int q = 0; q < 12; q++) {
      int o = o0 + 13 + q;
      tv[q] = emb[(long long)tt[(long long)gb * 200 + o] * 64 + d] + pos[o * 64 + d];
    }
#pragma unroll
    for (int q = 0; q < 12; q++) {
      int o = o0 + 13 + q;
      float outv = tv[q] + acc[q] + convb[o] + sH[o * 64 + d];
      float r1 = outv * outv;
      float r2 = outv * w1;
      for (int s = 32; s > 0; s >>= 1) {
        r1 += __shfl_xor(r1, s);
        r2 += __shfl_xor(r2, s);
      }
      if (d == 0) {
        float dn = sqrtf(r1);
        if (dn < 1e-12f) dn = 1e-12f;
        sAg[(long long)gb * 200 + o] = r2 / dn;
      }
    }
  }
}

// ---------- STAM phase A+B+C fused (fast path): conv + tw + _emb ----------
// sA kept in LDS (never hits global); tw reductions reuse sH region (dead
// after conv). Arithmetic/order identical to k_conv + k_tw.
__global__ void __launch_bounds__(512, 4) k_convtw(
    const float* hatt, const int* tt, const int* cen,
    const float* emb, const float* pos, const float* convW,
    const float* convb, const float* lab, float* embout, int gb_base) {
  int gbl = blockIdx.x;
  int gb = gb_base + gbl;
  __shared__ float sH[12800];
  __shared__ float sA[200];
  float* sP = sH;        // aliases: used only after conv phase done
  float* sR = sH + 256;
  int t = threadIdx.x;
  const float4* hb4 = (const float4*)(hatt + (long long)gbl * 12800);
  float4* sH4 = (float4*)sH;
  for (int i = t; i < 3200; i += 512) sH4[i] = hb4[i];
  int og = t >> 6, d = t & 63;
  float w1 = emb[(long long)cen[gb] * 64 + d];
  __syncthreads();
  int o0 = og * 25;
  {
    const float* cwb = convW + o0 * 200;
    float acc[13];
#pragma unroll
    for (int q = 0; q < 13; q++) acc[q] = 0.0f;
    for (int l2 = 0; l2 < 200; l2 += 4) {
      float s0 = sH[(l2 + 0) * 64 + d];
      float s1 = sH[(l2 + 1) * 64 + d];
      float s2 = sH[(l2 + 2) * 64 + d];
      float s3 = sH[(l2 + 3) * 64 + d];
#pragma unroll
      for (int q = 0; q < 13; q++) {
        float4 c4 = *(const float4*)(cwb + q * 200 + l2);
        acc[q] += c4.x * s0 + c4.y * s1 + c4.z * s2 + c4.w * s3;
      }
    }
    float tv[13];
#pragma unroll
    for (int q = 0; q < 13; q++) {
      int o = o0 + q;
      tv[q] = emb[(long long)tt[(long long)gb * 200 + o] * 64 + d] + pos[o * 64 + d];
    }
#pragma unroll
    for (int q = 0; q < 13; q++) {
      int o = o0 + q;
      float outv = tv[q] + acc[q] + convb[o] + sH[o * 64 + d];
      float r1 = outv * outv;
      float r2 = outv * w1;
      for (int s = 32; s > 0; s >>= 1) {
        r1 += __shfl_xor(r1, s);
        r2 += __shfl_xor(r2, s);
      }
      if (d == 0) {
        float dn = sqrtf(r1);
        if (dn < 1e-12f) dn = 1e-12f;
        sA[o] = r2 / dn;
      }
    }
  }
  {
    const float* cwb = convW + (o0 + 13) * 200;
    float acc[12];
#pragma unroll
    for (int q = 0; q < 12; q++) acc[q] = 0.0f;
    for (int l2 = 0; l2 < 200; l2 += 4) {
      float s0 = sH[(l2 + 0) * 64 + d];
      float s1 = sH[(l2 + 1) * 64 + d];
      float s2 = sH[(l2 + 2) * 64 + d];
      float s3 = sH[(l2 + 3) * 64 + d];
#pragma unroll
      for (int q = 0; q < 12; q++) {
        float4 c4 = *(const float4*)(cwb + q * 200 + l2);
        acc[q] += c4.x * s0 + c4.y * s1 + c4.z * s2 + c4.w * s3;
      }
    }
    float tv[12];
#pragma unroll
    for (int q = 0; q < 12; q++) {
      int o = o0 + 13 + q;
      tv[q] = emb[(long long)tt[(long long)gb * 200 + o] * 64 + d] + pos[o * 64 + d];
    }
#pragma unroll
    for (int q = 0; q < 12; q++) {
      int o = o0 + 13 + q;
      float outv = tv[q] + acc[q] + convb[o] + sH[o * 64 + d];
      float r1 = outv * outv;
      float r2 = outv * w1;
      for (int s = 32; s > 0; s >>= 1) {
        r1 += __shfl_xor(r1, s);
        r2 += __shfl_xor(r2, s);
      }
      if (d == 0) {
        float dn = sqrtf(r1);
        if (dn < 1e-12f) dn = 1e-12f;
        sA[o] = r2 / dn;
      }
    }
  }
  __syncthreads();                       // sA complete; sH dead -> sP/sR live
  // ---- tw phase (verbatim k_tw logic, barriers uniform over 512) ----
  float a0 = (t < 200) ? sA[t] : -1e30f;
  if (t < 256) sP[t] = a0;
  __syncthreads();
  for (int s = 128; s > 0; s >>= 1) {
    if (t < s) { float o2 = sP[t + s]; if (o2 > sP[t]) sP[t] = o2; }
    __syncthreads();
  }
  float mx = sP[0];
  __syncthreads();
  float a = 0.0f;
  if (t < 200) a = expf(a0 - mx) * lab[(long long)gb * 200 + t];
  if (t < 256) sP[t] = a;
  __syncthreads();
  for (int s = 128; s > 0; s >>= 1) {
    if (t < s) sP[t] += sP[t + s];
    __syncthreads();
  }
  float sum = sP[0];
  __syncthreads();
  if (t < 200) sA[t] = (sum > 0.0f) ? a / sum : 0.0f;
  __syncthreads();
  if (t < 256) {
    float acc2 = 0.0f;
    int og2 = t >> 6, d2 = t & 63;
    for (int l = og2 * 50; l < og2 * 50 + 50; l++)
      acc2 += sA[l] * emb[(long long)tt[(long long)gb * 200 + l] * 64 + d2];
    sR[t] = acc2;
  }
  __syncthreads();
  if (t < 64)
    embout[(long long)gb * 64 + t] = sR[t] + sR[64 + t] + sR[128 + t] + sR[192 + t];
}

// ---------- STAM phase B+C (fallback) ----------
__global__ void k_tw(const float* sAg, const int* tt, const float* lab,
                     const float* emb, float* embout) {
  int gb = blockIdx.x;
  __shared__ float sA[200];
  __shared__ float sP[256];
  __shared__ float sR[256];
  int t = threadIdx.x;
  float a0 = (t < 200) ? sAg[(long long)gb * 200 + t] : -1e30f;
  sP[t] = a0;
  __syncthreads();
  for (int s = 128; s > 0; s >>= 1) {
    if (t < s) { float o2 = sP[t + s]; if (o2 > sP[t]) sP[t] = o2; }
    __syncthreads();
  }
  float mx = sP[0];
  __syncthreads();
  float a = 0.0f;
  if (t < 200) a = expf(a0 - mx) * lab[(long long)gb * 200 + t];
  sP[t] = a;
  __syncthreads();
  for (int s = 128; s > 0; s >>= 1) {
    if (t < s) sP[t] += sP[t + s];
    __syncthreads();
  }
  float sum = sP[0];
  __syncthreads();
  if (t < 200) sA[t] = (sum > 0.0f) ? a / sum : 0.0f;
  __syncthreads();
  int og = t >> 6, d = t & 63;
  float acc2 = 0.0f;
  for (int l = og * 50; l < og * 50 + 50; l++)
    acc2 += sA[l] * emb[(long long)tt[(long long)gb * 200 + l] * 64 + d];
  sR[t] = acc2;
  __syncthreads();
  if (t < 64)
    embout[(long long)gb * 64 + t] = sR[t] + sR[64 + t] + sR[128 + t] + sR[192 + t];
}

// ---------- head (fallback kernels) ----------
__global__ void k_att1(const float* xlist, const float* aw1, const float* ab1,
                       const float* aw2, float* attK) {
  int blk = blockIdx.x;
  int b = blk / cG, g = blk - b * cG;
  int j = threadIdx.x;
  __shared__ float sRed[256];
  const float* sub = xlist + (g * cB + b) * 256;
  float acc = ab1[j];
  for (int i = 0; i < 256; i++) acc += sub[i] * aw1[i * 256 + j];
  if (acc < 0.0f) acc = 0.0f;
  sRed[j] = acc * aw2[j];
  __syncthreads();
  for (int s = 128; s > 0; s >>= 1) {
    if (j < s) sRed[j] += sRed[j + s];
    __syncthreads();
  }
  if (j == 0) attK[b * cG + g] = sRed[0];
}

__global__ void k_hm(const float* attK, const float* xlist, const float* mw1,
                     const float* mb1, float* metah) {
  int b = blockIdx.x;
  __shared__ float sAgg[256];
  int t = threadIdx.x;
  float a0 = attK[b * 5 + 0], a1 = attK[b * 5 + 1], a2 = attK[b * 5 + 2],
        a3 = attK[b * 5 + 3], a4 = attK[b * 5 + 4];
  float mx = a0;
  if (a1 > mx) mx = a1;
  if (a2 > mx) mx = a2;
  if (a3 > mx) mx = a3;
  if (a4 > mx) mx = a4;
  float e0 = expf(a0 - mx), e1 = expf(a1 - mx), e2 = expf(a2 - mx),
        e3 = expf(a3 - mx), e4 = expf(a4 - mx);
  float s = e0 + e1 + e2 + e3 + e4;
  sAgg[t] = (e0 * xlist[(0 * cB + b) * 256 + t] + e1 * xlist[(1 * cB + b) * 256 + t] +
             e2 * xlist[(2 * cB + b) * 256 + t] + e3 * xlist[(3 * cB + b) * 256 + t] +
             e4 * xlist[(4 * cB + b) * 256 + t]) / s;
  __syncthreads();
  for (int j = t; j < 512; j += 256) {
    float acc = mb1[j];
    for (int i = 0; i < 256; i++) acc += sAgg[i] * mw1[i * 512 + j];
    if (acc < 0.0f) acc = 0.0f;
    metah[b * 512 + j] = acc;
  }
}

__global__ void k_m2(const float* metah, const float* mw2, const float* mb2,
                     const float* xlist, const float* embout, float* xcat) {
  int i = blockIdx.x * 256 + threadIdx.x;
  if (i >= cB * 1920) return;
  int b = i / 1920, j = i - b * 1920;
  if (j < 1280) {
    float acc = mb2[j];
    const float* mh = metah + b * 512;
    for (int k = 0; k < 512; k++) acc += mh[k] * mw2[k * 1280 + j];
    int g = j >> 8, jj = j & 255;
    xcat[b * 1920 + j] = acc * xlist[(g * cB + b) * 256 + jj];
  } else {
    int jj = j - 1280;
    int g = jj >> 7, r = jj & 127;
    xcat[b * 1920 + j] = embout[(g * 100 + 2 * b + (r >> 6)) * 64 + (r & 63)];
  }
}

__global__ void k_l12(const float* xcat, const float* l1w, const float* l1b,
                      const float* l2w, const float* l2b, float* out) {
  int b = blockIdx.x;
  int t = threadIdx.x;
  __shared__ float sHH[128];
  float acc = l1b[t];
  const float* xc = xcat + b * 1920;
  for (int i = 0; i < 1920; i++) acc += xc[i] * l1w[i * 128 + t];
  if (acc < 0.0f) acc = 0.0f;
  sHH[t] = acc * l2w[t];
  __syncthreads();
  for (int s = 64; s > 0; s >>= 1) {
    if (t < s) sHH[t] += sHH[t + s];
    __syncthreads();
  }
  if (t == 0) out[b] = sHH[0] + l2b[0];
}

// ---------- head fused (fast path): att1 x5 -> hm -> m2 -> l12 per b ----------
// All dot/reduction orders copied verbatim from the fallback kernels.
__global__ void k_head(const float* xlist, const float* aw1, const float* ab1,
                       const float* aw2, const float* mw1, const float* mb1,
                       const float* mw2, const float* mb2, const float* embout,
                       const float* l1w, const float* l1b, const float* l2w,
                       const float* l2b, float* out) {
  int b = blockIdx.x;   // grid = 50, 256 threads
  __shared__ float sRed[256];
  __shared__ float sK5[5];
  __shared__ float sAgg[256];
  __shared__ float sMh[512];
  __shared__ float sXc[1920];
  __shared__ float sHH[128];
  int t = threadIdx.x;
  // phase 1: att1 (k_att1 body per g)
  for (int g = 0; g < cG; g++) {
    const float* sub = xlist + (g * cB + b) * 256;
    float acc = ab1[t];
    for (int i = 0; i < 256; i++) acc += sub[i] * aw1[i * 256 + t];
    if (acc < 0.0f) acc = 0.0f;
    sRed[t] = acc * aw2[t];
    __syncthreads();
    for (int s = 128; s > 0; s >>= 1) {
      if (t < s) sRed[t] += sRed[t + s];
      __syncthreads();
    }
    if (t == 0) sK5[g] = sRed[0];
    __syncthreads();
  }
  // phase 2: hm
  {
    float a0 = sK5[0], a1 = sK5[1], a2 = sK5[2], a3 = sK5[3], a4 = sK5[4];
    float mx = a0;
    if (a1 > mx) mx = a1;
    if (a2 > mx) mx = a2;
    if (a3 > mx) mx = a3;
    if (a4 > mx) mx = a4;
    float e0 = expf(a0 - mx), e1 = expf(a1 - mx), e2 = expf(a2 - mx),
          e3 = expf(a3 - mx), e4 = expf(a4 - mx);
    float s = e0 + e1 + e2 + e3 + e4;
    sAgg[t] = (e0 * xlist[(0 * cB + b) * 256 + t] + e1 * xlist[(1 * cB + b) * 256 + t] +
               e2 * xlist[(2 * cB + b) * 256 + t] + e3 * xlist[(3 * cB + b) * 256 + t] +
               e4 * xlist[(4 * cB + b) * 256 + t]) / s;
    __syncthreads();
    for (int j = t; j < 512; j += 256) {
      float acc = mb1[j];
      for (int i = 0; i < 256; i++) acc += sAgg[i] * mw1[i * 512 + j];
      if (acc < 0.0f) acc = 0.0f;
      sMh[j] = acc;
    }
    __syncthreads();
  }
  // phase 3: m2 (k_m2 body, xcat -> LDS)
  for (int j = t; j < 1920; j += 256) {
    if (j < 1280) {
      float acc = mb2[j];
      for (int k = 0; k < 512; k++) acc += sMh[k] * mw2[k * 1280 + j];
      int g = j >> 8, jj = j & 255;
      sXc[j] = acc * xlist[(g * cB + b) * 256 + jj];
    } else {
      int jj = j - 1280;
      int g = jj >> 7, r = jj & 127;
      sXc[j] = embout[(g * 100 + 2 * b + (r >> 6)) * 64 + (r & 63)];
    }
  }
  __syncthreads();
  // phase 4: l12
  if (t < 128) {
    float acc = l1b[t];
    for (int i = 0; i < 1920; i++) acc += sXc[i] * l1w[i * 128 + t];
    if (acc < 0.0f) acc = 0.0f;
    sHH[t] = acc * l2w[t];
  }
  __syncthreads();
  for (int s = 64; s > 0; s >>= 1) {
    if (t < s) sHH[t] += sHH[t + s];
    __syncthreads();
  }
  if (t == 0) out[b] = sHH[0] + l2b[0];
}

extern "C" void kernel_launch(void* const* d_in, const int* in_sizes, int n_in,
                              void* d_out, int out_size, void* d_ws, size_t ws_size,
                              hipStream_t stream) {
  const float* x      = (const float*)d_in[0];
  const int* ei       = (const int*)d_in[1];
  const int* et       = (const int*)d_in[2];
  const int* cen      = (const int*)d_in[3];
  const int* tt       = (const int*)d_in[4];
  const float* lab    = (const float*)d_in[5];
  const float* emb    = (const float*)d_in[6];
  const float* basis0 = (const float*)d_in[7];
  const float* comp0  = (const float*)d_in[8];
  const float* root0  = (const float*)d_in[9];
  const float* bias0  = (const float*)d_in[10];
  const float* basisR = (const float*)d_in[11];
  const float* compR  = (const float*)d_in[12];
  const float* rootR  = (const float*)d_in[13];
  const float* biasR  = (const float*)d_in[14];
  const float* pos    = (const float*)d_in[15];
  const float* Qw     = (const float*)d_in[16];
  const float* Kw     = (const float*)d_in[17];
  const float* Vw     = (const float*)d_in[18];
  const float* convW  = (const float*)d_in[19];
  const float* convb  = (const float*)d_in[20];
  const float* aw1    = (const float*)d_in[21];
  const float* ab1    = (const float*)d_in[22];
  const float* aw2    = (const float*)d_in[23];
  const float* mw1    = (const float*)d_in[24];
  const float* mb1    = (const float*)d_in[25];
  const float* mw2    = (const float*)d_in[26];
  const float* mb2    = (const float*)d_in[27];
  const float* l1w    = (const float*)d_in[28];
  const float* l1b    = (const float*)d_in[29];
  const float* l2w    = (const float*)d_in[30];
  const float* l2b    = (const float*)d_in[31];
  float* out          = (float*)d_out;
  char* p = (char*)d_ws;
  (void)in_sizes; (void)n_in; (void)out_size;

  if (ws_size >= FP_NEED) {
    int*   uidx   = (int*)(p + FP_UIDX);
    int*   bsumA  = (int*)(p + FP_BSUM);
    float* xlist  = (float*)(p + FP_XLIST);
    float* embout = (float*)(p + FP_EMBOUT);
    int*   inv    = (int*)(p + FP_INV);
    int*   clsA   = (int*)(p + FP_CLS);
    float* h_a    = (float*)(p + FP_HA);
    float* h_b    = (float*)(p + FP_HB);
    int*   curA   = (int*)(p + FP_CUR);
    int*   offA   = (int*)(p + FP_OFF);
    int*   permA  = (int*)(p + FP_PERM);
    float* invcA  = (float*)(p + FP_INVC);
    // full-size hatt[500] = 25.6 MB at FP_HA: h_a/h_b dead after RGCN,
    // curA/offA dead after gathers; attn/conv run strictly after both.
    float* hatt   = h_a;

    bool pruned = (ws_size >= FP2_NEED);
    int* markA  = pruned ? (int*)(p + FP2_MARK) : nullptr;
    int* listA  = pruned ? (int*)(p + FP2_LIST) : nullptr;
    int* cntA   = pruned ? (int*)(p + FP2_CNT) : nullptr;
    int* counts = pruned ? (int*)(p + FP2_COUNTS) : nullptr;

    k_invinit<<<NBLK, 256, 0, stream>>>(inv);
    k_uidx<<<cG * 2, 256, 0, stream>>>(x, uidx);
    k_mkinv<<<1, 512, 0, stream>>>(uidx, inv);

    k_prepB<<<cG * NBLK, 256, 0, stream>>>(x, clsA, curA, markA);
    k_histgB<<<cG * NBLK, 256, 0, stream>>>(ei, et, curA);
    k_bsumB<<<cG * NBLK, 256, 0, stream>>>(curA, bsumA);
    k_bscanB<<<cG, 1024, 0, stream>>>(bsumA);
    k_mkoffB<<<cG * NBLK, 256, 0, stream>>>(curA, offA, bsumA, invcA);
    k_scatterB<<<cG * NBLK, 256, 0, stream>>>(ei, et, clsA, curA, permA);

    if (pruned) {
      k_mark<<<cG, 128, 0, stream>>>(uidx, markA, listA, cntA, counts);
      for (int k = 1; k <= 3; k++) {
        k_expand<<<cG * EXB, 256, 0, stream>>>(offA, curA, permA, markA, listA,
                                               cntA, counts, k);
        k_snap<<<1, 64, 0, stream>>>(counts, cntA, k);
      }
    }

    for (int g = 0; g < cG; g++) {
      const int*   offg  = offA + (long long)g * cNR;
      const int*   curg  = curA + (long long)g * cNR;
      const int*   permg = permA + (long long)g * cE;
      const float* invcg = invcA + (long long)g * cE;
      const int*   clsg  = clsA + (long long)g * cN;
      const int*   invg  = inv + (long long)g * cN;
      const int*   listg = pruned ? (listA + (long long)g * cN) : nullptr;
      const int* c0 = pruned ? (counts + g * 4 + 3) : nullptr;
      k_gather0<<<6250, 256, 0, stream>>>(offg, curg, permg, invcg, clsg, basis0,
                                          comp0, root0, bias0, h_b, invg, xlist,
                                          listg, c0);
      float* hin = h_b;
      float* hou = h_a;
      for (int l = 0; l < 3; l++) {
        const int* cl = pruned ? (counts + g * 4 + (2 - l)) : nullptr;
        k_gatherR<<<6250, 256, 0, stream>>>(offg, curg, permg, invcg, hin,
                                            basisR + l * 2048, compR + l * 10,
                                            rootR + l * 1024, biasR + l * 32, hou,
                                            invg, xlist, l + 1, listg, cl);
        float* tmp = hin; hin = hou; hou = tmp;
      }
    }

    // single launches: all 500 gb in one grid (hatt is full-size here)
    k_attn2<<<2000, 256, 0, stream>>>(tt, emb, pos, Qw, Kw, Vw, hatt, 0);
    k_convtw<<<500, 512, 0, stream>>>(hatt, tt, cen, emb, pos, convW, convb,
                                      lab, embout, 0);
    k_head<<<cB, 256, 0, stream>>>(xlist, aw1, ab1, aw2, mw1, mb1, mw2, mb2,
                                   embout, l1w, l1b, l2w, l2b, out);
    return;
  }

  // ---------------- fallback: exact R5 layout & schedule ----------------
  int*   uidx   = (int*)(p);
  int*   clsb   = (int*)(p + 4096);
  int*   cur    = (int*)(p + 208896);
  int*   off    = (int*)(p + 1212416);
  int*   perm   = (int*)(p + 2215936);
  float* invc   = (float*)(p + 3219456);
  int*   bsum   = (int*)(p + 4222976);
  float* xlist  = (float*)(p + 4227072);
  float* embout = (float*)(p + 4741120);
  float* attK   = (float*)(p + 4870144);
  float* metah  = (float*)(p + 4874240);
  float* xcat   = (float*)(p + 4980736);
  char*  arena  = p + 5368832;
  float* h_a    = (float*)(arena);
  float* h_b    = (float*)(arena + 6400000);
  float* hatt   = (float*)(arena);
  float* sAg    = (float*)(p + 4874240);

  k_uidx<<<cG * 2, 256, 0, stream>>>(x, uidx);

  for (int g = 0; g < cG; g++) {
    const int* eis = ei + (long long)g * 2 * cE;
    const int* eid = eis + cE;
    const int* etg = et + (long long)g * cE;
    const float* xg = x + (long long)g * cN * 4;
    k_prep<<<NBLK, 256, 0, stream>>>(xg, clsb, cur);
    k_histg<<<NBLK, 256, 0, stream>>>(eid, etg, cur);
    k_bsum<<<NBLK, 256, 0, stream>>>(cur, bsum);
    k_bscan<<<1, 1024, 0, stream>>>(bsum);
    k_mkoff<<<NBLK, 256, 0, stream>>>(cur, off, bsum);
    k_scatter<<<NBLK, 256, 0, stream>>>(eis, eid, etg, clsb, cur, perm);
    k_invc<<<NBLK, 256, 0, stream>>>(off, cur, invc);
    k_gather0<<<6250, 256, 0, stream>>>(off, cur, perm, invc, clsb, basis0, comp0,
                                        root0, bias0, h_b, nullptr, nullptr,
                                        nullptr, nullptr);
    k_extract<<<13, 256, 0, stream>>>(h_b, uidx, xlist, g, 0);
    float* hin = h_b;
    float* hou = h_a;
    for (int l = 0; l < 3; l++) {
      k_gatherR<<<6250, 256, 0, stream>>>(off, cur, perm, invc, hin,
                                          basisR + l * 2048, compR + l * 10,
                                          rootR + l * 1024, biasR + l * 32, hou,
                                          nullptr, nullptr, 0, nullptr, nullptr);
      k_extract<<<13, 256, 0, stream>>>(hou, uidx, xlist, g, l + 1);
      float* tmp = hin; hin = hou; hou = tmp;
    }
  }

  for (int c = 0; c < 2; c++) {
    k_attn2<<<1000, 256, 0, stream>>>(tt, emb, pos, Qw, Kw, Vw, hatt, c * 250);
    k_conv<<<250, 512, 0, stream>>>(hatt, tt, cen, emb, pos, convW, convb, sAg,
                                    c * 250);
  }
  k_tw<<<500, 256, 0, stream>>>(sAg, tt, lab, emb, embout);

  k_att1<<<cB * cG, 256, 0, stream>>>(xlist, aw1, ab1, aw2, attK);
  k_hm<<<cB, 256, 0, stream>>>(attK, xlist, mw1, mb1, metah);
  k_m2<<<375, 256, 0, stream>>>(metah, mw2, mb2, xlist, embout, xcat);
  k_l12<<<cB, 128, 0, stream>>>(xcat, l1w, l1b, l2w, l2b, out);
}

// Round 13
// 968.345 us; speedup vs baseline: 1.1156x; 1.1156x over previous
//
#include <hip/hip_runtime.h>
#include <hip/hip_bf16.h>

__global__ void IGMC_15247133901635_kernel() {}

#define cG 5
#define cN 50000
#define cE 250000
#define cB 50
#define cL 200
#define cD 64
#define cR 5
#define cNR 250000
#define cGB 500
#define NBLK 977

// ---------------- fast-path workspace layout (bytes) ----------------
#define FP_UIDX   0
#define FP_BSUM   4096
#define FP_XLIST  28672
#define FP_EMBOUT 540672
#define FP_ATTK   668672
#define FP_METAH  672768
#define FP_XCAT   775168
#define FP_SAG    1159168
#define FP_INV    1559168
#define FP_CLS    2559168
#define FP_HA     3559168
#define FP_HB     9959168
#define FP_CUR    16359168
#define FP_OFF    21359168
#define FP_PERM   26359168
#define FP_INVC   31359168
#define FP_NEED   36359168ULL
// ---- pruned-path extras (tier 1) ----
#define FP2_MARK   36359168
#define FP2_LIST   37359168
#define FP2_CNT    38359168
#define FP2_COUNTS 38363264
#define FP2_NEED   38367360ULL

// ---------- per-graph prep (fallback) ----------
__global__ void k_prep(const float* xg, int* cls, int* cur) {
  int i = blockIdx.x * 256 + threadIdx.x;
  if (i < cNR) cur[i] = 0;
  if (i < cN) {
    int c = 0;
    if (xg[i * 4 + 1] == 1.0f) c = 1;
    else if (xg[i * 4 + 2] == 1.0f) c = 2;
    else if (xg[i * 4 + 3] == 1.0f) c = 3;
    cls[i] = c;
  }
}

__global__ void k_histg(const int* eid, const int* etg, int* cur) {
  int e = blockIdx.x * 256 + threadIdx.x;
  if (e < cE) atomicAdd(&cur[eid[e] * cR + etg[e]], 1);
}

__global__ void k_bsum(const int* cur, int* bsum) {
  __shared__ int sC[256];
  int t = threadIdx.x;
  int i = blockIdx.x * 256 + t;
  sC[t] = (i < cNR) ? cur[i] : 0;
  __syncthreads();
  for (int s = 128; s > 0; s >>= 1) {
    if (t < s) sC[t] += sC[t + s];
    __syncthreads();
  }
  if (t == 0) bsum[blockIdx.x] = sC[0];
}

__global__ void __launch_bounds__(1024) k_bscan(int* bsum) {
  __shared__ int sS[1024];
  int t = threadIdx.x;
  int v = (t < NBLK) ? bsum[t] : 0;
  sS[t] = v;
  __syncthreads();
  for (int off = 1; off < 1024; off <<= 1) {
    int add = (t >= off) ? sS[t - off] : 0;
    __syncthreads();
    sS[t] += add;
    __syncthreads();
  }
  if (t < NBLK) bsum[t] = sS[t] - v;
}

__global__ void k_mkoff(int* cur, int* off, const int* bbase) {
  __shared__ int sC[256];
  __shared__ int sO[256];
  int t = threadIdx.x;
  int i = blockIdx.x * 256 + t;
  int c = (i < cNR) ? cur[i] : 0;
  sC[t] = c;
  __syncthreads();
  if (t == 0) {
    int run = 0;
    for (int k = 0; k < 256; k++) { sO[k] = run; run += sC[k]; }
  }
  __syncthreads();
  if (i < cNR) {
    int v = bbase[blockIdx.x] + sO[t];
    off[i] = v;
    cur[i] = v;
  }
}

__global__ void k_scatter(const int* eis, const int* eid, const int* etg,
                          const int* cls, int* cur, int* perm) {
  int e = blockIdx.x * 256 + threadIdx.x;
  if (e >= cE) return;
  int src = eis[e];
  int r = etg[e];
  int bin = eid[e] * cR + r;
  int pos = atomicAdd(&cur[bin], 1);
  perm[pos] = src * 32 + r * 4 + cls[src];
}

__global__ void k_invc(const int* off, const int* cur, float* invc) {
  int i = blockIdx.x * 256 + threadIdx.x;
  if (i >= cNR) return;
  int st = off[i], en = cur[i];
  if (en > st) {
    float ic = 1.0f / (float)(en - st);
    for (int j = st; j < en; j++) invc[j] = ic;
  }
}

// ---------- batched CSR build (fast path): grid = 5*NBLK ----------
__global__ void k_prepB(const float* x, int* clsA, int* curA, int* markA) {
  int g = blockIdx.x / NBLK;
  int i = (blockIdx.x - g * NBLK) * 256 + threadIdx.x;
  if (i < cNR) curA[g * cNR + i] = 0;
  if (i < cN) {
    const float* xg = x + (long long)g * cN * 4;
    int c = 0;
    if (xg[i * 4 + 1] == 1.0f) c = 1;
    else if (xg[i * 4 + 2] == 1.0f) c = 2;
    else if (xg[i * 4 + 3] == 1.0f) c = 3;
    clsA[g * cN + i] = c;
    if (markA) markA[g * cN + i] = 0;
  }
}

__global__ void k_histgB(const int* ei, const int* et, int* curA) {
  int g = blockIdx.x / NBLK;
  int e = (blockIdx.x - g * NBLK) * 256 + threadIdx.x;
  if (e >= cE) return;
  const int* eid = ei + (long long)g * 2 * cE + cE;
  const int* etg = et + (long long)g * cE;
  atomicAdd(&curA[g * cNR + eid[e] * cR + etg[e]], 1);
}

__global__ void k_bsumB(const int* curA, int* bsumA) {
  __shared__ int sC[256];
  int g = blockIdx.x / NBLK;
  int b2 = blockIdx.x - g * NBLK;
  int t = threadIdx.x;
  int i = b2 * 256 + t;
  sC[t] = (i < cNR) ? curA[g * cNR + i] : 0;
  __syncthreads();
  for (int s = 128; s > 0; s >>= 1) {
    if (t < s) sC[t] += sC[t + s];
    __syncthreads();
  }
  if (t == 0) bsumA[g * NBLK + b2] = sC[0];
}

__global__ void __launch_bounds__(1024) k_bscanB(int* bsumA) {
  __shared__ int sS[1024];
  int g = blockIdx.x;   // grid = 5
  int t = threadIdx.x;
  int v = (t < NBLK) ? bsumA[g * NBLK + t] : 0;
  sS[t] = v;
  __syncthreads();
  for (int off = 1; off < 1024; off <<= 1) {
    int add = (t >= off) ? sS[t - off] : 0;
    __syncthreads();
    sS[t] += add;
    __syncthreads();
  }
  if (t < NBLK) bsumA[g * NBLK + t] = sS[t] - v;
}

// invc fill fused in (curA holds bin counts here; values/positions
// identical to the old separate k_invcB pass).
__global__ void k_mkoffB(int* curA, int* offA, const int* bsumA, float* invcA) {
  __shared__ int sC[256];
  __shared__ int sO[256];
  int g = blockIdx.x / NBLK;
  int b2 = blockIdx.x - g * NBLK;
  int t = threadIdx.x;
  int i = b2 * 256 + t;
  int c = (i < cNR) ? curA[g * cNR + i] : 0;
  sC[t] = c;
  __syncthreads();
  if (t == 0) {
    int run = 0;
    for (int k = 0; k < 256; k++) { sO[k] = run; run += sC[k]; }
  }
  __syncthreads();
  if (i < cNR) {
    int v = bsumA[g * NBLK + b2] + sO[t];
    offA[g * cNR + i] = v;
    curA[g * cNR + i] = v;
    if (c > 0) {
      float ic = 1.0f / (float)c;
      float* invc = invcA + (long long)g * cE;
      for (int j = v; j < v + c; j++) invc[j] = ic;
    }
  }
}

__global__ void k_scatterB(const int* ei, const int* et, const int* clsA,
                           int* curA, int* permA) {
  int g = blockIdx.x / NBLK;
  int e = (blockIdx.x - g * NBLK) * 256 + threadIdx.x;
  if (e >= cE) return;
  const int* eis = ei + (long long)g * 2 * cE;
  const int* eid = eis + cE;
  const int* etg = et + (long long)g * cE;
  int src = eis[e];
  int r = etg[e];
  int pos = atomicAdd(&curA[g * cNR + eid[e] * cR + r], 1);
  permA[g * cE + pos] = src * 32 + r * 4 + clsA[g * cN + src];
}

// ---------- inverse extraction map ----------
__global__ void k_invinit(int* inv) {
  int i = blockIdx.x * 256 + threadIdx.x;
  if (i < cG * cN) inv[i] = -1;
}

__global__ void k_mkinv(const int* uidx, int* inv) {
  int t = threadIdx.x;
  if (t < cG * 2 * cB) {
    int g = t / (2 * cB), r = t - g * 2 * cB;
    int c = r / cB, b = r - c * cB;
    int node = uidx[(g * 2 + c) * cB + b];
    inv[g * cN + node] = (g * cB + b) * 256 + c * 128;
  }
}

// ---------- dependency pruning: BFS over dst-keyed bins ----------
__global__ void k_mark(const int* uidx, int* markA, int* listA, int* cntA,
                       int* counts) {
  int g = blockIdx.x;   // grid = 5, 128 threads
  int t = threadIdx.x;
  if (t == 0) cntA[g] = 0;
  __syncthreads();
  if (t < 2 * cB) {
    int c = t / cB, b = t - c * cB;
    int node = uidx[(g * 2 + c) * cB + b];
    if (atomicExch(&markA[g * cN + node], 1) == 0) {
      int pos = atomicAdd(&cntA[g], 1);
      listA[g * cN + pos] = node;
    }
  }
  __syncthreads();
  if (t == 0) counts[g * 4 + 0] = atomicAdd(&cntA[g], 0);
}

#define EXB 196
__global__ void k_expand(const int* offA, const int* curA, const int* permA,
                         int* markA, int* listA, int* cntA, const int* counts,
                         int k) {
  int g = blockIdx.x / EXB;
  int i = (blockIdx.x - g * EXB) * 256 + threadIdx.x;
  int lo = (k == 1) ? 0 : counts[g * 4 + k - 2];
  int hi = counts[g * 4 + k - 1];
  int idx = lo + i;
  if (idx >= hi) return;
  int n = listA[g * cN + idx];
  int st = offA[g * cNR + n * 5], en = curA[g * cNR + n * 5 + 4];
  const int* perm = permA + (long long)g * cE;
  for (int j = st; j < en; j++) {
    int src = perm[j] >> 5;
    if (atomicExch(&markA[g * cN + src], 1) == 0) {
      int pos = atomicAdd(&cntA[g], 1);
      listA[g * cN + pos] = src;
    }
  }
}

__global__ void k_snap(int* counts, int* cntA, int k) {
  int t = threadIdx.x;
  if (t < cG) counts[t * 4 + k] = atomicAdd(&cntA[t], 0);
}

// ---------- RGCN layer 0 (optional list pruning + fused extract) ----------
__global__ void k_gather0(const int* off, const int* cur, const int* perm,
                          const float* invc, const int* cls, const float* basis0,
                          const float* comp0, const float* root0, const float* bias0,
                          float* hout, const int* inv, float* xlist,
                          const int* list, const int* cntp) {
  int cnt = cN;
  if (cntp) {
    cnt = *cntp;
    if (blockIdx.x * 8 >= cnt) return;
  }
  __shared__ float sW0[640];
  __shared__ float sRt[128];
  __shared__ float sB[32];
  int t = threadIdx.x;
  for (int idx = t; idx < 640; idx += 256) {
    int r = idx / 128, rem = idx - r * 128;
    sW0[idx] = comp0[r * 2] * basis0[rem] + comp0[r * 2 + 1] * basis0[128 + rem];
  }
  if (t < 128) sRt[t] = root0[t];
  if (t < 32) sB[t] = bias0[t];
  __syncthreads();
  int nd = t >> 5, li = t & 31;
  int idx8 = blockIdx.x * 8 + nd;
  int n;
  if (list) n = (idx8 < cnt) ? list[idx8] : list[0];
  else n = idx8;
  int st = off[n * 5], en = cur[n * 5 + 4];
  float tot = 0.0f;
  int j = st;
  for (; j + 1 < en; j += 2) {
    int p0 = perm[j], p1 = perm[j + 1];
    float i0 = invc[j], i1 = invc[j + 1];
    tot += sW0[(p0 & 31) * 32 + li] * i0 + sW0[(p1 & 31) * 32 + li] * i1;
  }
  if (j < en) tot += sW0[(perm[j] & 31) * 32 + li] * invc[j];
  float val = tanhf(tot + sRt[cls[n] * 32 + li] + sB[li]);
  hout[(long long)n * 32 + li] = val;
  if (inv) {
    int iv = inv[n];
    if (iv >= 0) xlist[iv + li] = val;
  }
}

// ---------- RGCN layers 1..3 (optional list pruning + fused extract) ----------
__global__ void k_gatherR(const int* off, const int* cur, const int* perm,
                          const float* invc, const float* hin, const float* basis,
                          const float* comp, const float* root, const float* bias,
                          float* hout, const int* inv, float* xlist, int layer,
                          const int* list, const int* cntp) {
  int cnt = cN;
  if (cntp) {
    cnt = *cntp;
    if (blockIdx.x * 8 >= cnt) return;
  }
  __shared__ float sB0[1024];
  __shared__ float sB1[1024];
  __shared__ float sRt[1024];
  __shared__ float sZ0[8][32];
  __shared__ float sZ1[8][32];
  __shared__ float sHl[8][32];
  __shared__ float sBias[32];
  __shared__ float sC0[8];
  __shared__ float sC1[8];
  int t = threadIdx.x;
  for (int idx = t; idx < 1024; idx += 256) {
    sB0[idx] = basis[idx];
    sB1[idx] = basis[1024 + idx];
    sRt[idx] = root[idx];
  }
  if (t < 32) sBias[t] = bias[t];
  if (t < cR) { sC0[t] = comp[t * 2]; sC1[t] = comp[t * 2 + 1]; }
  __syncthreads();
  int nd = t >> 5, li = t & 31;
  int idx8 = blockIdx.x * 8 + nd;
  int n;
  if (list) n = (idx8 < cnt) ? list[idx8] : list[0];
  else n = idx8;
  sHl[nd][li] = hin[(long long)n * 32 + li];
  int st = off[n * 5], en = cur[n * 5 + 4];
  float z0 = 0.0f, z1 = 0.0f;
  int j = st;
  for (; j + 1 < en; j += 2) {
    int p0 = perm[j], p1 = perm[j + 1];
    float i0 = invc[j], i1 = invc[j + 1];
    float s0 = hin[(long long)(p0 >> 5) * 32 + li];
    float s1 = hin[(long long)(p1 >> 5) * 32 + li];
    int r0 = (p0 >> 2) & 7, r1 = (p1 >> 2) & 7;
    float w00 = sC0[r0] * i0, w10 = sC1[r0] * i0;
    float w01 = sC0[r1] * i1, w11 = sC1[r1] * i1;
    z0 += w00 * s0 + w01 * s1;
    z1 += w10 * s0 + w11 * s1;
  }
  if (j < en) {
    int p0 = perm[j];
    float i0 = invc[j];
    float s0 = hin[(long long)(p0 >> 5) * 32 + li];
    int r0 = (p0 >> 2) & 7;
    z0 += sC0[r0] * i0 * s0;
    z1 += sC1[r0] * i0 * s0;
  }
  sZ0[nd][li] = z0;
  sZ1[nd][li] = z1;
  __syncthreads();
  float a = sBias[li];
  for (int i = 0; i < 32; i++)
    a += sZ0[nd][i] * sB0[i * 32 + li] + sZ1[nd][i] * sB1[i * 32 + li] +
         sHl[nd][i] * sRt[i * 32 + li];
  float val = tanhf(a);
  hout[(long long)n * 32 + li] = val;
  if (inv) {
    int iv = inv[n];
    if (iv >= 0) xlist[iv + layer * 32 + li] = val;
  }
}

// ---------- ordered compaction: first cB nodes with x[:,c]==1 ----------
__global__ void k_uidx(const float* x, int* uidx) {
  int g = blockIdx.x >> 1, c = blockIdx.x & 1;
  __shared__ int sFlag[256];
  __shared__ int sBase;
  int t = threadIdx.x;
  if (t < cB) uidx[(g * 2 + c) * cB + t] = 0;
  if (t == 0) sBase = 0;
  __syncthreads();
  for (int chunk = 0; chunk < cN; chunk += 256) {
    int n = chunk + t;
    sFlag[t] = (n < cN && x[((long long)g * cN + n) * 4 + c] == 1.0f) ? 1 : 0;
    __syncthreads();
    if (t == 0) {
      int base = sBase;
      for (int t2 = 0; t2 < 256; t2++) {
        if (sFlag[t2]) {
          if (base < cB) uidx[(g * 2 + c) * cB + base] = chunk + t2;
          base++;
        }
      }
      sBase = base;
    }
    __syncthreads();
    if (sBase >= cB) break;
  }
}

__global__ void k_extract(const float* h, const int* uidx, float* xlist, int g, int layer) {
  int i = blockIdx.x * 256 + threadIdx.x;
  if (i >= 2 * cB * 32) return;
  int o = i & 31;
  int rest = i >> 5;
  int b = rest % cB, c = rest / cB;
  int node = uidx[(g * 2 + c) * cB + b];
  xlist[(g * cB + b) * 256 + c * 128 + layer * 32 + o] = h[(long long)node * 32 + o];
}

// ---------- STAM: fused QKV + attention v6 ----------
__global__ void k_attn2(const int* tt, const float* emb, const float* pos,
                        const float* Qw, const float* Kw, const float* Vw,
                        float* hatt, int gb_base) {
  int gbl = blockIdx.x >> 2, hh = blockIdx.x & 3;
  int gb = gb_base + gbl;
  __shared__ float smem[12160];          // 48640 B: QKV 9600 + sT 2*1280
  float* sQ = smem;
  float* sK = smem + 3200;
  float* sV = smem + 6400;
  float* sT = smem + 9600;               // 2 bufs x 20 rows x 64
  int t = threadIdx.x;
  float wreg[64];
  int c48 = t % 48, rgrp = t / 48;       // rgrp<4 for t<192
  int mat = c48 >> 4, dh = c48 & 15;
  if (t < 192) {
    const float* W = (mat == 0) ? Qw : ((mat == 1) ? Kw : Vw);
    const float* wp = W + hh * 16 + dh;
#pragma unroll
    for (int i = 0; i < 64; i += 4) {
      wreg[i] = wp[i * 64];
      wreg[i + 1] = wp[(i + 1) * 64];
      wreg[i + 2] = wp[(i + 2) * 64];
      wreg[i + 3] = wp[(i + 3) * 64];
    }
  }
  const int* ttg = tt + (long long)gb * 200;
  float r[5];
#define LOADC(c)                                                        \
  {                                                                     \
    _Pragma("unroll")                                                   \
    for (int k = 0; k < 5; k++) {                                       \
      int idx = k * 256 + t;                                            \
      int row = idx >> 6, d2 = idx & 63;                                \
      int l = (c) * 20 + row;                                           \
      r[k] = emb[(long long)ttg[l] * 64 + d2] + pos[l * 64 + d2];       \
    }                                                                   \
  }
#define STOREC(pb)                                                      \
  {                                                                     \
    _Pragma("unroll")                                                   \
    for (int k = 0; k < 5; k++) sT[(pb) * 1280 + k * 256 + t] = r[k];   \
  }
  LOADC(0)
  STOREC(0)
  LOADC(1)
  for (int c = 0; c < 10; c++) {
    int p = c & 1;
    if (c >= 1) __syncthreads();
    if (c + 1 < 10) STOREC(1 - p)
    if (c + 2 < 10) LOADC(c + 2)
    __syncthreads();
    if (t < 192) {
      const float* base = sT + p * 1280;
      float acc0 = 0.0f, acc1 = 0.0f, acc2 = 0.0f, acc3 = 0.0f, acc4 = 0.0f;
#pragma unroll
      for (int i4 = 0; i4 < 16; i4++) {
        float w0 = wreg[i4 * 4], w1 = wreg[i4 * 4 + 1],
              w2 = wreg[i4 * 4 + 2], w3 = wreg[i4 * 4 + 3];
        float4 t0 = ((const float4*)(base + (rgrp * 5 + 0) * 64))[i4];
        float4 t1 = ((const float4*)(base + (rgrp * 5 + 1) * 64))[i4];
        float4 t2 = ((const float4*)(base + (rgrp * 5 + 2) * 64))[i4];
        float4 t3 = ((const float4*)(base + (rgrp * 5 + 3) * 64))[i4];
        float4 t4 = ((const float4*)(base + (rgrp * 5 + 4) * 64))[i4];
        acc0 += t0.x * w0 + t0.y * w1 + t0.z * w2 + t0.w * w3;
        acc1 += t1.x * w0 + t1.y * w1 + t1.z * w2 + t1.w * w3;
        acc2 += t2.x * w0 + t2.y * w1 + t2.z * w2 + t2.w * w3;
        acc3 += t3.x * w0 + t3.y * w1 + t3.z * w2 + t3.w * w3;
        acc4 += t4.x * w0 + t4.y * w1 + t4.z * w2 + t4.w * w3;
      }
      float* dst = (mat == 0) ? sQ : ((mat == 1) ? sK : sV);
      int ll = c * 20 + rgrp * 5;
      dst[(ll + 0) * 16 + dh] = acc0;
      dst[(ll + 1) * 16 + dh] = acc1;
      dst[(ll + 2) * 16 + dh] = acc2;
      dst[(ll + 3) * 16 + dh] = acc3;
      dst[(ll + 4) * 16 + dh] = acc4;
    }
  }
#undef LOADC
#undef STOREC
  __syncthreads();
  float4 oa0 = {0,0,0,0}, oa1 = {0,0,0,0}, oa2 = {0,0,0,0}, oa3 = {0,0,0,0};
  float4 ob0 = {0,0,0,0}, ob1 = {0,0,0,0}, ob2 = {0,0,0,0}, ob3 = {0,0,0,0};
  float lsa = 0.0f, lsb = 0.0f;
  if (t < 200) {
    int a = t % 100, mh = t / 100;
    float scale = 1.0f / sqrtf(200.0f);
    const float4* q4 = (const float4*)sQ;
    float4 qa0 = q4[(2 * a) * 4], qa1 = q4[(2 * a) * 4 + 1],
           qa2 = q4[(2 * a) * 4 + 2], qa3 = q4[(2 * a) * 4 + 3];
    float4 qb0 = q4[(2 * a + 1) * 4], qb1 = q4[(2 * a + 1) * 4 + 1],
           qb2 = q4[(2 * a + 1) * 4 + 2], qb3 = q4[(2 * a + 1) * 4 + 3];
    qa0.x *= scale; qa0.y *= scale; qa0.z *= scale; qa0.w *= scale;
    qa1.x *= scale; qa1.y *= scale; qa1.z *= scale; qa1.w *= scale;
    qa2.x *= scale; qa2.y *= scale; qa2.z *= scale; qa2.w *= scale;
    qa3.x *= scale; qa3.y *= scale; qa3.z *= scale; qa3.w *= scale;
    qb0.x *= scale; qb0.y *= scale; qb0.z *= scale; qb0.w *= scale;
    qb1.x *= scale; qb1.y *= scale; qb1.z *= scale; qb1.w *= scale;
    qb2.x *= scale; qb2.y *= scale; qb2.z *= scale; qb2.w *= scale;
    qb3.x *= scale; qb3.y *= scale; qb3.z *= scale; qb3.w *= scale;
    const float4* kk = ((const float4*)sK) + mh * 400;
    const float4* vv = ((const float4*)sV) + mh * 400;
#pragma unroll 2
    for (int m = 0; m < 100; m++) {
      float4 k0 = kk[m * 4], k1 = kk[m * 4 + 1], k2 = kk[m * 4 + 2],
             k3 = kk[m * 4 + 3];
      float sa = qa0.x * k0.x + qa0.y * k0.y + qa0.z * k0.z + qa0.w * k0.w +
                 qa1.x * k1.x + qa1.y * k1.y + qa1.z * k1.z + qa1.w * k1.w +
                 qa2.x * k2.x + qa2.y * k2.y + qa2.z * k2.z + qa2.w * k2.w +
                 qa3.x * k3.x + qa3.y * k3.y + qa3.z * k3.z + qa3.w * k3.w;
      float sb = qb0.x * k0.x + qb0.y * k0.y + qb0.z * k0.z + qb0.w * k0.w +
                 qb1.x * k1.x + qb1.y * k1.y + qb1.z * k1.z + qb1.w * k1.w +
                 qb2.x * k2.x + qb2.y * k2.y + qb2.z * k2.z + qb2.w * k2.w +
                 qb3.x * k3.x + qb3.y * k3.y + qb3.z * k3.z + qb3.w * k3.w;
      float ea = __expf(sa);
      float eb = __expf(sb);
      float4 v0 = vv[m * 4], v1 = vv[m * 4 + 1], v2 = vv[m * 4 + 2],
             v3 = vv[m * 4 + 3];
      lsa += ea; lsb += eb;
      oa0.x += ea * v0.x; oa0.y += ea * v0.y; oa0.z += ea * v0.z; oa0.w += ea * v0.w;
      oa1.x += ea * v1.x; oa1.y += ea * v1.y; oa1.z += ea * v1.z; oa1.w += ea * v1.w;
      oa2.x += ea * v2.x; oa2.y += ea * v2.y; oa2.z += ea * v2.z; oa2.w += ea * v2.w;
      oa3.x += ea * v3.x; oa3.y += ea * v3.y; oa3.z += ea * v3.z; oa3.w += ea * v3.w;
      ob0.x += eb * v0.x; ob0.y += eb * v0.y; ob0.z += eb * v0.z; ob0.w += eb * v0.w;
      ob1.x += eb * v1.x; ob1.y += eb * v1.y; ob1.z += eb * v1.z; ob1.w += eb * v1.w;
      ob2.x += eb * v2.x; ob2.y += eb * v2.y; ob2.z += eb * v2.z; ob2.w += eb * v2.w;
      ob3.x += eb * v3.x; ob3.y += eb * v3.y; ob3.z += eb * v3.z; ob3.w += eb * v3.w;
    }
  }
  __syncthreads();
  if (t < 200) {
    float* pp = smem + t * 34;
    pp[0]  = oa0.x; pp[1]  = oa0.y; pp[2]  = oa0.z; pp[3]  = oa0.w;
    pp[4]  = oa1.x; pp[5]  = oa1.y; pp[6]  = oa1.z; pp[7]  = oa1.w;
    pp[8]  = oa2.x; pp[9]  = oa2.y; pp[10] = oa2.z; pp[11] = oa2.w;
    pp[12] = oa3.x; pp[13] = oa3.y; pp[14] = oa3.z; pp[15] = oa3.w;
    pp[16] = lsa;
    pp[17] = ob0.x; pp[18] = ob0.y; pp[19] = ob0.z; pp[20] = ob0.w;
    pp[21] = ob1.x; pp[22] = ob1.y; pp[23] = ob1.z; pp[24] = ob1.w;
    pp[25] = ob2.x; pp[26] = ob2.y; pp[27] = ob2.z; pp[28] = ob2.w;
    pp[29] = ob3.x; pp[30] = ob3.y; pp[31] = ob3.z; pp[32] = ob3.w;
    pp[33] = lsb;
  }
  __syncthreads();
  if (t < 200) {
    int a = t >> 1, r2 = t & 1;
    const float* p0 = smem + a * 34 + r2 * 17;
    const float* p1 = smem + (100 + a) * 34 + r2 * 17;
    float inv = 1.0f / (p0[16] + p1[16]);
    float4 o0, o1, o2, o3;
    o0.x = (p0[0]  + p1[0])  * inv; o0.y = (p0[1]  + p1[1])  * inv;
    o0.z = (p0[2]  + p1[2])  * inv; o0.w = (p0[3]  + p1[3])  * inv;
    o1.x = (p0[4]  + p1[4])  * inv; o1.y = (p0[5]  + p1[5])  * inv;
    o1.z = (p0[6]  + p1[6])  * inv; o1.w = (p0[7]  + p1[7])  * inv;
    o2.x = (p0[8]  + p1[8])  * inv; o2.y = (p0[9]  + p1[9])  * inv;
    o2.z = (p0[10] + p1[10]) * inv; o2.w = (p0[11] + p1[11]) * inv;
    o3.x = (p0[12] + p1[12]) * inv; o3.y = (p0[13] + p1[13]) * inv;
    o3.z = (p0[14] + p1[14]) * inv; o3.w = (p0[15] + p1[15]) * inv;
    float4* outp = (float4*)(hatt + ((long long)gbl * 200 + t) * 64 + hh * 16);
    outp[0] = o0; outp[1] = o1; outp[2] = o2; outp[3] = o3;
  }
}

// ---------- STAM phase A (fallback): conv -> sAg ----------
__global__ void __launch_bounds__(512, 4) k_conv(
    const float* hatt, const int* tt, const int* cen,
    const float* emb, const float* pos, const float* convW,
    const float* convb, float* sAg, int gb_base) {
  int gbl = blockIdx.x;
  int gb = gb_base + gbl;
  __shared__ float sH[12800];
  int t = threadIdx.x;
  const float4* hb4 = (const float4*)(hatt + (long long)gbl * 12800);
  float4* sH4 = (float4*)sH;
  for (int i = t; i < 3200; i += 512) sH4[i] = hb4[i];
  int og = t >> 6, d = t & 63;
  float w1 = emb[(long long)cen[gb] * 64 + d];
  __syncthreads();
  int o0 = og * 25;
  {
    const float* cwb = convW + o0 * 200;
    float acc[13];
#pragma unroll
    for (int q = 0; q < 13; q++) acc[q] = 0.0f;
    for (int l2 = 0; l2 < 200; l2 += 4) {
      float s0 = sH[(l2 + 0) * 64 + d];
      float s1 = sH[(l2 + 1) * 64 + d];
      float s2 = sH[(l2 + 2) * 64 + d];
      float s3 = sH[(l2 + 3) * 64 + d];
#pragma unroll
      for (int q = 0; q < 13; q++) {
        float4 c4 = *(const float4*)(cwb + q * 200 + l2);
        acc[q] += c4.x * s0 + c4.y * s1 + c4.z * s2 + c4.w * s3;
      }
    }
    float tv[13];
#pragma unroll
    for (int q = 0; q < 13; q++) {
      int o = o0 + q;
      tv[q] = emb[(long long)tt[(long long)gb * 200 + o] * 64 + d] + pos[o * 64 + d];
    }
#pragma unroll
    for (int q = 0; q < 13; q++) {
      int o = o0 + q;
      float outv = tv[q] + acc[q] + convb[o] + sH[o * 64 + d];
      float r1 = outv * outv;
      float r2 = outv * w1;
      for (int s = 32; s > 0; s >>= 1) {
        r1 += __shfl_xor(r1, s);
        r2 += __shfl_xor(r2, s);
      }
      if (d == 0) {
        float dn = sqrtf(r1);
        if (dn < 1e-12f) dn = 1e-12f;
        sAg[(long long)gb * 200 + o] = r2 / dn;
      }
    }
  }
  {
    const float* cwb = convW + (o0 + 13) * 200;
    float acc[12];
#pragma unroll
    for (int q = 0; q < 12; q++) acc[q] = 0.0f;
    for (int l2 = 0; l2 < 200; l2 += 4) {
      float s0 = sH[(l2 + 0) * 64 + d];
      float s1 = sH[(l2 + 1) * 64 + d];
      float s2 = sH[(l2 + 2) * 64 + d];
      float s3 = sH[(l2 + 3) * 64 + d];
#pragma unroll
      for (int q = 0; q < 12; q++) {
        float4 c4 = *(const float4*)(cwb + q * 200 + l2);
        acc[q] += c4.x * s0 + c4.y * s1 + c4.z * s2 + c4.w * s3;
      }
    }
    float tv[12];
#pragma unroll
    for (int q = 0; q < 12; q++) {
      int o = o0 + 13 + q;
      tv[q] = emb[(long long)tt[(long long)gb * 200 + o] * 64 + d] + pos[o * 64 + d];
    }
#pragma unroll
    for (int q = 0; q < 12; q++) {
      int o = o0 + 13 + q;
      float outv = tv[q] + acc[q] + convb[o] + sH[o * 64 + d];
      float r1 = outv * outv;
      float r2 = outv * w1;
      for (int s = 32; s > 0; s >>= 1) {
        r1 += __shfl_xor(r1, s);
        r2 += __shfl_xor(r2, s);
      }
      if (d == 0) {
        float dn = sqrtf(r1);
        if (dn < 1e-12f) dn = 1e-12f;
        sAg[(long long)gb * 200 + o] = r2 / dn;
      }
    }
  }
}

// ---------- STAM phase A+B+C fused (fast path): conv + tw + _emb ----------
__global__ void __launch_bounds__(512, 4) k_convtw(
    const float* hatt, const int* tt, const int* cen,
    const float* emb, const float* pos, const float* convW,
    const float* convb, const float* lab, float* embout, int gb_base) {
  int gbl = blockIdx.x;
  int gb = gb_base + gbl;
  __shared__ float sH[12800];
  __shared__ float sA[200];
  float* sP = sH;        // aliases: used only after conv phase done
  float* sR = sH + 256;
  int t = threadIdx.x;
  const float4* hb4 = (const float4*)(hatt + (long long)gbl * 12800);
  float4* sH4 = (float4*)sH;
  for (int i = t; i < 3200; i += 512) sH4[i] = hb4[i];
  int og = t >> 6, d = t & 63;
  float w1 = emb[(long long)cen[gb] * 64 + d];
  __syncthreads();
  int o0 = og * 25;
  {
    const float* cwb = convW + o0 * 200;
    float acc[13];
#pragma unroll
    for (int q = 0; q < 13; q++) acc[q] = 0.0f;
    for (int l2 = 0; l2 < 200; l2 += 4) {
      float s0 = sH[(l2 + 0) * 64 + d];
      float s1 = sH[(l2 + 1) * 64 + d];
      float s2 = sH[(l2 + 2) * 64 + d];
      float s3 = sH[(l2 + 3) * 64 + d];
#pragma unroll
      for (int q = 0; q < 13; q++) {
        float4 c4 = *(const float4*)(cwb + q * 200 + l2);
        acc[q] += c4.x * s0 + c4.y * s1 + c4.z * s2 + c4.w * s3;
      }
    }
    float tv[13];
#pragma unroll
    for (int q = 0; q < 13; q++) {
      int o = o0 + q;
      tv[q] = emb[(long long)tt[(long long)gb * 200 + o] * 64 + d] + pos[o * 64 + d];
    }
#pragma unroll
    for (int q = 0; q < 13; q++) {
      int o = o0 + q;
      float outv = tv[q] + acc[q] + convb[o] + sH[o * 64 + d];
      float r1 = outv * outv;
      float r2 = outv * w1;
      for (int s = 32; s > 0; s >>= 1) {
        r1 += __shfl_xor(r1, s);
        r2 += __shfl_xor(r2, s);
      }
      if (d == 0) {
        float dn = sqrtf(r1);
        if (dn < 1e-12f) dn = 1e-12f;
        sA[o] = r2 / dn;
      }
    }
  }
  {
    const float* cwb = convW + (o0 + 13) * 200;
    float acc[12];
#pragma unroll
    for (int q = 0; q < 12; q++) acc[q] = 0.0f;
    for (int l2 = 0; l2 < 200; l2 += 4) {
      float s0 = sH[(l2 + 0) * 64 + d];
      float s1 = sH[(l2 + 1) * 64 + d];
      float s2 = sH[(l2 + 2) * 64 + d];
      float s3 = sH[(l2 + 3) * 64 + d];
#pragma unroll
      for (int q = 0; q < 12; q++) {
        float4 c4 = *(const float4*)(cwb + q * 200 + l2);
        acc[q] += c4.x * s0 + c4.y * s1 + c4.z * s2 + c4.w * s3;
      }
    }
    float tv[12];
#pragma unroll
    for (int q = 0; q < 12; q++) {
      int o = o0 + 13 + q;
      tv[q] = emb[(long long)tt[(long long)gb * 200 + o] * 64 + d] + pos[o * 64 + d];
    }
#pragma unroll
    for (int q = 0; q < 12; q++) {
      int o = o0 + 13 + q;
      float outv = tv[q] + acc[q] + convb[o] + sH[o * 64 + d];
      float r1 = outv * outv;
      float r2 = outv * w1;
      for (int s = 32; s > 0; s >>= 1) {
        r1 += __shfl_xor(r1, s);
        r2 += __shfl_xor(r2, s);
      }
      if (d == 0) {
        float dn = sqrtf(r1);
        if (dn < 1e-12f) dn = 1e-12f;
        sA[o] = r2 / dn;
      }
    }
  }
  __syncthreads();                       // sA complete; sH dead -> sP/sR live
  float a0 = (t < 200) ? sA[t] : -1e30f;
  if (t < 256) sP[t] = a0;
  __syncthreads();
  for (int s = 128; s > 0; s >>= 1) {
    if (t < s) { float o2 = sP[t + s]; if (o2 > sP[t]) sP[t] = o2; }
    __syncthreads();
  }
  float mx = sP[0];
  __syncthreads();
  float a = 0.0f;
  if (t < 200) a = expf(a0 - mx) * lab[(long long)gb * 200 + t];
  if (t < 256) sP[t] = a;
  __syncthreads();
  for (int s = 128; s > 0; s >>= 1) {
    if (t < s) sP[t] += sP[t + s];
    __syncthreads();
  }
  float sum = sP[0];
  __syncthreads();
  if (t < 200) sA[t] = (sum > 0.0f) ? a / sum : 0.0f;
  __syncthreads();
  if (t < 256) {
    float acc2 = 0.0f;
    int og2 = t >> 6, d2 = t & 63;
    for (int l = og2 * 50; l < og2 * 50 + 50; l++)
      acc2 += sA[l] * emb[(long long)tt[(long long)gb * 200 + l] * 64 + d2];
    sR[t] = acc2;
  }
  __syncthreads();
  if (t < 64)
    embout[(long long)gb * 64 + t] = sR[t] + sR[64 + t] + sR[128 + t] + sR[192 + t];
}

// ---------- STAM phase B+C (fallback) ----------
__global__ void k_tw(const float* sAg, const int* tt, const float* lab,
                     const float* emb, float* embout) {
  int gb = blockIdx.x;
  __shared__ float sA[200];
  __shared__ float sP[256];
  __shared__ float sR[256];
  int t = threadIdx.x;
  float a0 = (t < 200) ? sAg[(long long)gb * 200 + t] : -1e30f;
  sP[t] = a0;
  __syncthreads();
  for (int s = 128; s > 0; s >>= 1) {
    if (t < s) { float o2 = sP[t + s]; if (o2 > sP[t]) sP[t] = o2; }
    __syncthreads();
  }
  float mx = sP[0];
  __syncthreads();
  float a = 0.0f;
  if (t < 200) a = expf(a0 - mx) * lab[(long long)gb * 200 + t];
  sP[t] = a;
  __syncthreads();
  for (int s = 128; s > 0; s >>= 1) {
    if (t < s) sP[t] += sP[t + s];
    __syncthreads();
  }
  float sum = sP[0];
  __syncthreads();
  if (t < 200) sA[t] = (sum > 0.0f) ? a / sum : 0.0f;
  __syncthreads();
  int og = t >> 6, d = t & 63;
  float acc2 = 0.0f;
  for (int l = og * 50; l < og * 50 + 50; l++)
    acc2 += sA[l] * emb[(long long)tt[(long long)gb * 200 + l] * 64 + d];
  sR[t] = acc2;
  __syncthreads();
  if (t < 64)
    embout[(long long)gb * 64 + t] = sR[t] + sR[64 + t] + sR[128 + t] + sR[192 + t];
}

// ---------- head ----------
__global__ void k_att1(const float* xlist, const float* aw1, const float* ab1,
                       const float* aw2, float* attK) {
  int blk = blockIdx.x;
  int b = blk / cG, g = blk - b * cG;
  int j = threadIdx.x;
  __shared__ float sRed[256];
  const float* sub = xlist + (g * cB + b) * 256;
  float acc = ab1[j];
  for (int i = 0; i < 256; i++) acc += sub[i] * aw1[i * 256 + j];
  if (acc < 0.0f) acc = 0.0f;
  sRed[j] = acc * aw2[j];
  __syncthreads();
  for (int s = 128; s > 0; s >>= 1) {
    if (j < s) sRed[j] += sRed[j + s];
    __syncthreads();
  }
  if (j == 0) attK[b * cG + g] = sRed[0];
}

__global__ void k_hm(const float* attK, const float* xlist, const float* mw1,
                     const float* mb1, float* metah) {
  int b = blockIdx.x;
  __shared__ float sAgg[256];
  int t = threadIdx.x;
  float a0 = attK[b * 5 + 0], a1 = attK[b * 5 + 1], a2 = attK[b * 5 + 2],
        a3 = attK[b * 5 + 3], a4 = attK[b * 5 + 4];
  float mx = a0;
  if (a1 > mx) mx = a1;
  if (a2 > mx) mx = a2;
  if (a3 > mx) mx = a3;
  if (a4 > mx) mx = a4;
  float e0 = expf(a0 - mx), e1 = expf(a1 - mx), e2 = expf(a2 - mx),
        e3 = expf(a3 - mx), e4 = expf(a4 - mx);
  float s = e0 + e1 + e2 + e3 + e4;
  sAgg[t] = (e0 * xlist[(0 * cB + b) * 256 + t] + e1 * xlist[(1 * cB + b) * 256 + t] +
             e2 * xlist[(2 * cB + b) * 256 + t] + e3 * xlist[(3 * cB + b) * 256 + t] +
             e4 * xlist[(4 * cB + b) * 256 + t]) / s;
  __syncthreads();
  for (int j = t; j < 512; j += 256) {
    float acc = mb1[j];
    for (int i = 0; i < 256; i++) acc += sAgg[i] * mw1[i * 512 + j];
    if (acc < 0.0f) acc = 0.0f;
    metah[b * 512 + j] = acc;
  }
}

__global__ void k_m2(const float* metah, const float* mw2, const float* mb2,
                     const float* xlist, const float* embout, float* xcat) {
  int i = blockIdx.x * 256 + threadIdx.x;
  if (i >= cB * 1920) return;
  int b = i / 1920, j = i - b * 1920;
  if (j < 1280) {
    float acc = mb2[j];
    const float* mh = metah + b * 512;
    for (int k = 0; k < 512; k++) acc += mh[k] * mw2[k * 1280 + j];
    int g = j >> 8, jj = j & 255;
    xcat[b * 1920 + j] = acc * xlist[(g * cB + b) * 256 + jj];
  } else {
    int jj = j - 1280;
    int g = jj >> 7, r = jj & 127;
    xcat[b * 1920 + j] = embout[(g * 100 + 2 * b + (r >> 6)) * 64 + (r & 63)];
  }
}

__global__ void k_l12(const float* xcat, const float* l1w, const float* l1b,
                      const float* l2w, const float* l2b, float* out) {
  int b = blockIdx.x;
  int t = threadIdx.x;
  __shared__ float sHH[128];
  float acc = l1b[t];
  const float* xc = xcat + b * 1920;
  for (int i = 0; i < 1920; i++) acc += xc[i] * l1w[i * 128 + t];
  if (acc < 0.0f) acc = 0.0f;
  sHH[t] = acc * l2w[t];
  __syncthreads();
  for (int s = 64; s > 0; s >>= 1) {
    if (t < s) sHH[t] += sHH[t + s];
    __syncthreads();
  }
  if (t == 0) out[b] = sHH[0] + l2b[0];
}

extern "C" void kernel_launch(void* const* d_in, const int* in_sizes, int n_in,
                              void* d_out, int out_size, void* d_ws, size_t ws_size,
                              hipStream_t stream) {
  const float* x      = (const float*)d_in[0];
  const int* ei       = (const int*)d_in[1];
  const int* et       = (const int*)d_in[2];
  const int* cen      = (const int*)d_in[3];
  const int* tt       = (const int*)d_in[4];
  const float* lab    = (const float*)d_in[5];
  const float* emb    = (const float*)d_in[6];
  const float* basis0 = (const float*)d_in[7];
  const float* comp0  = (const float*)d_in[8];
  const float* root0  = (const float*)d_in[9];
  const float* bias0  = (const float*)d_in[10];
  const float* basisR = (const float*)d_in[11];
  const float* compR  = (const float*)d_in[12];
  const float* rootR  = (const float*)d_in[13];
  const float* biasR  = (const float*)d_in[14];
  const float* pos    = (const float*)d_in[15];
  const float* Qw     = (const float*)d_in[16];
  const float* Kw     = (const float*)d_in[17];
  const float* Vw     = (const float*)d_in[18];
  const float* convW  = (const float*)d_in[19];
  const float* convb  = (const float*)d_in[20];
  const float* aw1    = (const float*)d_in[21];
  const float* ab1    = (const float*)d_in[22];
  const float* aw2    = (const float*)d_in[23];
  const float* mw1    = (const float*)d_in[24];
  const float* mb1    = (const float*)d_in[25];
  const float* mw2    = (const float*)d_in[26];
  const float* mb2    = (const float*)d_in[27];
  const float* l1w    = (const float*)d_in[28];
  const float* l1b    = (const float*)d_in[29];
  const float* l2w    = (const float*)d_in[30];
  const float* l2b    = (const float*)d_in[31];
  float* out          = (float*)d_out;
  char* p = (char*)d_ws;
  (void)in_sizes; (void)n_in; (void)out_size;

  if (ws_size >= FP_NEED) {
    int*   uidx   = (int*)(p + FP_UIDX);
    int*   bsumA  = (int*)(p + FP_BSUM);
    float* xlist  = (float*)(p + FP_XLIST);
    float* embout = (float*)(p + FP_EMBOUT);
    float* attK   = (float*)(p + FP_ATTK);
    float* metah  = (float*)(p + FP_METAH);
    float* xcat   = (float*)(p + FP_XCAT);
    int*   inv    = (int*)(p + FP_INV);
    int*   clsA   = (int*)(p + FP_CLS);
    float* h_a    = (float*)(p + FP_HA);
    float* h_b    = (float*)(p + FP_HB);
    int*   curA   = (int*)(p + FP_CUR);
    int*   offA   = (int*)(p + FP_OFF);
    int*   permA  = (int*)(p + FP_PERM);
    float* invcA  = (float*)(p + FP_INVC);
    // full-size hatt[500] = 25.6 MB at FP_HA: h_a/h_b dead after RGCN,
    // curA/offA dead after gathers; attn/conv run strictly after both.
    float* hatt   = h_a;

    bool pruned = (ws_size >= FP2_NEED);
    int* markA  = pruned ? (int*)(p + FP2_MARK) : nullptr;
    int* listA  = pruned ? (int*)(p + FP2_LIST) : nullptr;
    int* cntA   = pruned ? (int*)(p + FP2_CNT) : nullptr;
    int* counts = pruned ? (int*)(p + FP2_COUNTS) : nullptr;

    k_invinit<<<NBLK, 256, 0, stream>>>(inv);
    k_uidx<<<cG * 2, 256, 0, stream>>>(x, uidx);
    k_mkinv<<<1, 512, 0, stream>>>(uidx, inv);

    k_prepB<<<cG * NBLK, 256, 0, stream>>>(x, clsA, curA, markA);
    k_histgB<<<cG * NBLK, 256, 0, stream>>>(ei, et, curA);
    k_bsumB<<<cG * NBLK, 256, 0, stream>>>(curA, bsumA);
    k_bscanB<<<cG, 1024, 0, stream>>>(bsumA);
    k_mkoffB<<<cG * NBLK, 256, 0, stream>>>(curA, offA, bsumA, invcA);
    k_scatterB<<<cG * NBLK, 256, 0, stream>>>(ei, et, clsA, curA, permA);

    if (pruned) {
      k_mark<<<cG, 128, 0, stream>>>(uidx, markA, listA, cntA, counts);
      for (int k = 1; k <= 3; k++) {
        k_expand<<<cG * EXB, 256, 0, stream>>>(offA, curA, permA, markA, listA,
                                               cntA, counts, k);
        k_snap<<<1, 64, 0, stream>>>(counts, cntA, k);
      }
    }

    for (int g = 0; g < cG; g++) {
      const int*   offg  = offA + (long long)g * cNR;
      const int*   curg  = curA + (long long)g * cNR;
      const int*   permg = permA + (long long)g * cE;
      const float* invcg = invcA + (long long)g * cE;
      const int*   clsg  = clsA + (long long)g * cN;
      const int*   invg  = inv + (long long)g * cN;
      const int*   listg = pruned ? (listA + (long long)g * cN) : nullptr;
      const int* c0 = pruned ? (counts + g * 4 + 3) : nullptr;
      k_gather0<<<6250, 256, 0, stream>>>(offg, curg, permg, invcg, clsg, basis0,
                                          comp0, root0, bias0, h_b, invg, xlist,
                                          listg, c0);
      float* hin = h_b;
      float* hou = h_a;
      for (int l = 0; l < 3; l++) {
        const int* cl = pruned ? (counts + g * 4 + (2 - l)) : nullptr;
        k_gatherR<<<6250, 256, 0, stream>>>(offg, curg, permg, invcg, hin,
                                            basisR + l * 2048, compR + l * 10,
                                            rootR + l * 1024, biasR + l * 32, hou,
                                            invg, xlist, l + 1, listg, cl);
        float* tmp = hin; hin = hou; hou = tmp;
      }
    }

    // single launches: all 500 gb in one grid (hatt is full-size here)
    k_attn2<<<2000, 256, 0, stream>>>(tt, emb, pos, Qw, Kw, Vw, hatt, 0);
    k_convtw<<<500, 512, 0, stream>>>(hatt, tt, cen, emb, pos, convW, convb,
                                      lab, embout, 0);

    k_att1<<<cB * cG, 256, 0, stream>>>(xlist, aw1, ab1, aw2, attK);
    k_hm<<<cB, 256, 0, stream>>>(attK, xlist, mw1, mb1, metah);
    k_m2<<<375, 256, 0, stream>>>(metah, mw2, mb2, xlist, embout, xcat);
    k_l12<<<cB, 128, 0, stream>>>(xcat, l1w, l1b, l2w, l2b, out);
    return;
  }

  // ---------------- fallback: exact R5 layout & schedule ----------------
  int*   uidx   = (int*)(p);
  int*   clsb   = (int*)(p + 4096);
  int*   cur    = (int*)(p + 208896);
  int*   off    = (int*)(p + 1212416);
  int*   perm   = (int*)(p + 2215936);
  float* invc   = (float*)(p + 3219456);
  int*   bsum   = (int*)(p + 4222976);
  float* xlist  = (float*)(p + 4227072);
  float* embout = (float*)(p + 4741120);
  float* attK   = (float*)(p + 4870144);
  float* metah  = (float*)(p + 4874240);
  float* xcat   = (float*)(p + 4980736);
  char*  arena  = p + 5368832;
  float* h_a    = (float*)(arena);
  float* h_b    = (float*)(arena + 6400000);
  float* hatt   = (float*)(arena);
  float* sAg    = (float*)(p + 4874240);

  k_uidx<<<cG * 2, 256, 0, stream>>>(x, uidx);

  for (int g = 0; g < cG; g++) {
    const int* eis = ei + (long long)g * 2 * cE;
    const int* eid = eis + cE;
    const int* etg = et + (long long)g * cE;
    const float* xg = x + (long long)g * cN * 4;
    k_prep<<<NBLK, 256, 0, stream>>>(xg, clsb, cur);
    k_histg<<<NBLK, 256, 0, stream>>>(eid, etg, cur);
    k_bsum<<<NBLK, 256, 0, stream>>>(cur, bsum);
    k_bscan<<<1, 1024, 0, stream>>>(bsum);
    k_mkoff<<<NBLK, 256, 0, stream>>>(cur, off, bsum);
    k_scatter<<<NBLK, 256, 0, stream>>>(eis, eid, etg, clsb, cur, perm);
    k_invc<<<NBLK, 256, 0, stream>>>(off, cur, invc);
    k_gather0<<<6250, 256, 0, stream>>>(off, cur, perm, invc, clsb, basis0, comp0,
                                        root0, bias0, h_b, nullptr, nullptr,
                                        nullptr, nullptr);
    k_extract<<<13, 256, 0, stream>>>(h_b, uidx, xlist, g, 0);
    float* hin = h_b;
    float* hou = h_a;
    for (int l = 0; l < 3; l++) {
      k_gatherR<<<6250, 256, 0, stream>>>(off, cur, perm, invc, hin,
                                          basisR + l * 2048, compR + l * 10,
                                          rootR + l * 1024, biasR + l * 32, hou,
                                          nullptr, nullptr, 0, nullptr, nullptr);
      k_extract<<<13, 256, 0, stream>>>(hou, uidx, xlist, g, l + 1);
      float* tmp = hin; hin = hou; hou = tmp;
    }
  }

  for (int c = 0; c < 2; c++) {
    k_attn2<<<1000, 256, 0, stream>>>(tt, emb, pos, Qw, Kw, Vw, hatt, c * 250);
    k_conv<<<250, 512, 0, stream>>>(hatt, tt, cen, emb, pos, convW, convb, sAg,
                                    c * 250);
  }
  k_tw<<<500, 256, 0, stream>>>(sAg, tt, lab, emb, embout);

  k_att1<<<cB * cG, 256, 0, stream>>>(xlist, aw1, ab1, aw2, attK);
  k_hm<<<cB, 256, 0, stream>>>(attK, xlist, mw1, mb1, metah);
  k_m2<<<375, 256, 0, stream>>>(metah, mw2, mb2, xlist, embout, xcat);
  k_l12<<<cB, 128, 0, stream>>>(xcat, l1w, l1b, l2w, l2b, out);
}

// Round 14
// 884.921 us; speedup vs baseline: 1.2208x; 1.0943x over previous
//
#include <hip/hip_runtime.h>
#include <hip/hip_bf16.h>

__global__ void IGMC_15247133901635_kernel() {}

#define cG 5
#define cN 50000
#define cE 250000
#define cB 50
#define cL 200
#define cD 64
#define cR 5
#define cNR 250000
#define cGB 500
#define NBLK 977
#define GB0 6250

// ---------------- fast-path workspace layout (bytes) ----------------
#define FP_UIDX   0
#define FP_BSUM   4096
#define FP_XLIST  28672
#define FP_EMBOUT 540672
#define FP_ATTK   668672
#define FP_METAH  672768
#define FP_XCAT   775168
#define FP_SAG    1159168
#define FP_INV    1559168
#define FP_CLS    2559168
#define FP_HA     3559168
#define FP_HB     9959168
#define FP_CUR    16359168
#define FP_OFF    21359168
#define FP_PERM   26359168
#define FP_INVC   31359168
#define FP_NEED   36359168ULL
// ---- pruned-path extras (tier 1) ----
#define FP2_MARK   36359168
#define FP2_LIST   37359168
#define FP2_CNT    38359168
#define FP2_COUNTS 38363264
#define FP2_NEED   38367360ULL
// ---- batched-gather extras (tier 2): per-graph h buffers ----
#define FP3_HA     38367360            // 5 * cN * 32 * 4 = 32,000,000
#define FP3_HB     70367360            // 32,000,000
#define FP3_NEED   102367360ULL
// tier2: hatt[500] (25.6 MB) aliases hA5 (dead after gathers).

// ---------- per-graph prep (fallback) ----------
__global__ void k_prep(const float* xg, int* cls, int* cur) {
  int i = blockIdx.x * 256 + threadIdx.x;
  if (i < cNR) cur[i] = 0;
  if (i < cN) {
    int c = 0;
    if (xg[i * 4 + 1] == 1.0f) c = 1;
    else if (xg[i * 4 + 2] == 1.0f) c = 2;
    else if (xg[i * 4 + 3] == 1.0f) c = 3;
    cls[i] = c;
  }
}

__global__ void k_histg(const int* eid, const int* etg, int* cur) {
  int e = blockIdx.x * 256 + threadIdx.x;
  if (e < cE) atomicAdd(&cur[eid[e] * cR + etg[e]], 1);
}

__global__ void k_bsum(const int* cur, int* bsum) {
  __shared__ int sC[256];
  int t = threadIdx.x;
  int i = blockIdx.x * 256 + t;
  sC[t] = (i < cNR) ? cur[i] : 0;
  __syncthreads();
  for (int s = 128; s > 0; s >>= 1) {
    if (t < s) sC[t] += sC[t + s];
    __syncthreads();
  }
  if (t == 0) bsum[blockIdx.x] = sC[0];
}

__global__ void __launch_bounds__(1024) k_bscan(int* bsum) {
  __shared__ int sS[1024];
  int t = threadIdx.x;
  int v = (t < NBLK) ? bsum[t] : 0;
  sS[t] = v;
  __syncthreads();
  for (int off = 1; off < 1024; off <<= 1) {
    int add = (t >= off) ? sS[t - off] : 0;
    __syncthreads();
    sS[t] += add;
    __syncthreads();
  }
  if (t < NBLK) bsum[t] = sS[t] - v;
}

__global__ void k_mkoff(int* cur, int* off, const int* bbase) {
  __shared__ int sC[256];
  __shared__ int sO[256];
  int t = threadIdx.x;
  int i = blockIdx.x * 256 + t;
  int c = (i < cNR) ? cur[i] : 0;
  sC[t] = c;
  __syncthreads();
  if (t == 0) {
    int run = 0;
    for (int k = 0; k < 256; k++) { sO[k] = run; run += sC[k]; }
  }
  __syncthreads();
  if (i < cNR) {
    int v = bbase[blockIdx.x] + sO[t];
    off[i] = v;
    cur[i] = v;
  }
}

__global__ void k_scatter(const int* eis, const int* eid, const int* etg,
                          const int* cls, int* cur, int* perm) {
  int e = blockIdx.x * 256 + threadIdx.x;
  if (e >= cE) return;
  int src = eis[e];
  int r = etg[e];
  int bin = eid[e] * cR + r;
  int pos = atomicAdd(&cur[bin], 1);
  perm[pos] = src * 32 + r * 4 + cls[src];
}

__global__ void k_invc(const int* off, const int* cur, float* invc) {
  int i = blockIdx.x * 256 + threadIdx.x;
  if (i >= cNR) return;
  int st = off[i], en = cur[i];
  if (en > st) {
    float ic = 1.0f / (float)(en - st);
    for (int j = st; j < en; j++) invc[j] = ic;
  }
}

// ---------- batched CSR build (fast path): grid = 5*NBLK ----------
__global__ void k_prepB(const float* x, int* clsA, int* curA, int* markA) {
  int g = blockIdx.x / NBLK;
  int i = (blockIdx.x - g * NBLK) * 256 + threadIdx.x;
  if (i < cNR) curA[g * cNR + i] = 0;
  if (i < cN) {
    const float* xg = x + (long long)g * cN * 4;
    int c = 0;
    if (xg[i * 4 + 1] == 1.0f) c = 1;
    else if (xg[i * 4 + 2] == 1.0f) c = 2;
    else if (xg[i * 4 + 3] == 1.0f) c = 3;
    clsA[g * cN + i] = c;
    if (markA) markA[g * cN + i] = 0;
  }
}

__global__ void k_histgB(const int* ei, const int* et, int* curA) {
  int g = blockIdx.x / NBLK;
  int e = (blockIdx.x - g * NBLK) * 256 + threadIdx.x;
  if (e >= cE) return;
  const int* eid = ei + (long long)g * 2 * cE + cE;
  const int* etg = et + (long long)g * cE;
  atomicAdd(&curA[g * cNR + eid[e] * cR + etg[e]], 1);
}

__global__ void k_bsumB(const int* curA, int* bsumA) {
  __shared__ int sC[256];
  int g = blockIdx.x / NBLK;
  int b2 = blockIdx.x - g * NBLK;
  int t = threadIdx.x;
  int i = b2 * 256 + t;
  sC[t] = (i < cNR) ? curA[g * cNR + i] : 0;
  __syncthreads();
  for (int s = 128; s > 0; s >>= 1) {
    if (t < s) sC[t] += sC[t + s];
    __syncthreads();
  }
  if (t == 0) bsumA[g * NBLK + b2] = sC[0];
}

__global__ void __launch_bounds__(1024) k_bscanB(int* bsumA) {
  __shared__ int sS[1024];
  int g = blockIdx.x;   // grid = 5
  int t = threadIdx.x;
  int v = (t < NBLK) ? bsumA[g * NBLK + t] : 0;
  sS[t] = v;
  __syncthreads();
  for (int off = 1; off < 1024; off <<= 1) {
    int add = (t >= off) ? sS[t - off] : 0;
    __syncthreads();
    sS[t] += add;
    __syncthreads();
  }
  if (t < NBLK) bsumA[g * NBLK + t] = sS[t] - v;
}

// invc fill fused (curA holds bin counts here; identical values/positions).
__global__ void k_mkoffB(int* curA, int* offA, const int* bsumA, float* invcA) {
  __shared__ int sC[256];
  __shared__ int sO[256];
  int g = blockIdx.x / NBLK;
  int b2 = blockIdx.x - g * NBLK;
  int t = threadIdx.x;
  int i = b2 * 256 + t;
  int c = (i < cNR) ? curA[g * cNR + i] : 0;
  sC[t] = c;
  __syncthreads();
  if (t == 0) {
    int run = 0;
    for (int k = 0; k < 256; k++) { sO[k] = run; run += sC[k]; }
  }
  __syncthreads();
  if (i < cNR) {
    int v = bsumA[g * NBLK + b2] + sO[t];
    offA[g * cNR + i] = v;
    curA[g * cNR + i] = v;
    if (c > 0) {
      float ic = 1.0f / (float)c;
      float* invc = invcA + (long long)g * cE;
      for (int j = v; j < v + c; j++) invc[j] = ic;
    }
  }
}

__global__ void k_scatterB(const int* ei, const int* et, const int* clsA,
                           int* curA, int* permA) {
  int g = blockIdx.x / NBLK;
  int e = (blockIdx.x - g * NBLK) * 256 + threadIdx.x;
  if (e >= cE) return;
  const int* eis = ei + (long long)g * 2 * cE;
  const int* eid = eis + cE;
  const int* etg = et + (long long)g * cE;
  int src = eis[e];
  int r = etg[e];
  int pos = atomicAdd(&curA[g * cNR + eid[e] * cR + r], 1);
  permA[g * cE + pos] = src * 32 + r * 4 + clsA[g * cN + src];
}

// ---------- inverse extraction map ----------
__global__ void k_invinit(int* inv) {
  int i = blockIdx.x * 256 + threadIdx.x;
  if (i < cG * cN) inv[i] = -1;
}

__global__ void k_mkinv(const int* uidx, int* inv) {
  int t = threadIdx.x;
  if (t < cG * 2 * cB) {
    int g = t / (2 * cB), r = t - g * 2 * cB;
    int c = r / cB, b = r - c * cB;
    int node = uidx[(g * 2 + c) * cB + b];
    inv[g * cN + node] = (g * cB + b) * 256 + c * 128;
  }
}

// ---------- dependency pruning: BFS over dst-keyed bins ----------
__global__ void k_mark(const int* uidx, int* markA, int* listA, int* cntA,
                       int* counts) {
  int g = blockIdx.x;   // grid = 5, 128 threads
  int t = threadIdx.x;
  if (t == 0) cntA[g] = 0;
  __syncthreads();
  if (t < 2 * cB) {
    int c = t / cB, b = t - c * cB;
    int node = uidx[(g * 2 + c) * cB + b];
    if (atomicExch(&markA[g * cN + node], 1) == 0) {
      int pos = atomicAdd(&cntA[g], 1);
      listA[g * cN + pos] = node;
    }
  }
  __syncthreads();
  if (t == 0) counts[g * 4 + 0] = atomicAdd(&cntA[g], 0);
}

#define EXB 196
__global__ void k_expand(const int* offA, const int* curA, const int* permA,
                         int* markA, int* listA, int* cntA, const int* counts,
                         int k) {
  int g = blockIdx.x / EXB;
  int i = (blockIdx.x - g * EXB) * 256 + threadIdx.x;
  int lo = (k == 1) ? 0 : counts[g * 4 + k - 2];
  int hi = counts[g * 4 + k - 1];
  int idx = lo + i;
  if (idx >= hi) return;
  int n = listA[g * cN + idx];
  int st = offA[g * cNR + n * 5], en = curA[g * cNR + n * 5 + 4];
  const int* perm = permA + (long long)g * cE;
  for (int j = st; j < en; j++) {
    int src = perm[j] >> 5;
    if (atomicExch(&markA[g * cN + src], 1) == 0) {
      int pos = atomicAdd(&cntA[g], 1);
      listA[g * cN + pos] = src;
    }
  }
}

__global__ void k_snap(int* counts, int* cntA, int k) {
  int t = threadIdx.x;
  if (t < cG) counts[t * 4 + k] = atomicAdd(&cntA[t], 0);
}

// ---------- RGCN layer 0 (per-graph; optional pruning + fused extract) ----------
__global__ void k_gather0(const int* off, const int* cur, const int* perm,
                          const float* invc, const int* cls, const float* basis0,
                          const float* comp0, const float* root0, const float* bias0,
                          float* hout, const int* inv, float* xlist,
                          const int* list, const int* cntp) {
  int cnt = cN;
  if (cntp) {
    cnt = *cntp;
    if (blockIdx.x * 8 >= cnt) return;
  }
  __shared__ float sW0[640];
  __shared__ float sRt[128];
  __shared__ float sB[32];
  int t = threadIdx.x;
  for (int idx = t; idx < 640; idx += 256) {
    int r = idx / 128, rem = idx - r * 128;
    sW0[idx] = comp0[r * 2] * basis0[rem] + comp0[r * 2 + 1] * basis0[128 + rem];
  }
  if (t < 128) sRt[t] = root0[t];
  if (t < 32) sB[t] = bias0[t];
  __syncthreads();
  int nd = t >> 5, li = t & 31;
  int idx8 = blockIdx.x * 8 + nd;
  int n;
  if (list) n = (idx8 < cnt) ? list[idx8] : list[0];
  else n = idx8;
  int st = off[n * 5], en = cur[n * 5 + 4];
  float tot = 0.0f;
  int j = st;
  for (; j + 1 < en; j += 2) {
    int p0 = perm[j], p1 = perm[j + 1];
    float i0 = invc[j], i1 = invc[j + 1];
    tot += sW0[(p0 & 31) * 32 + li] * i0 + sW0[(p1 & 31) * 32 + li] * i1;
  }
  if (j < en) tot += sW0[(perm[j] & 31) * 32 + li] * invc[j];
  float val = tanhf(tot + sRt[cls[n] * 32 + li] + sB[li]);
  hout[(long long)n * 32 + li] = val;
  if (inv) {
    int iv = inv[n];
    if (iv >= 0) xlist[iv + li] = val;
  }
}

// ---------- RGCN layers 1..3 (per-graph) ----------
__global__ void k_gatherR(const int* off, const int* cur, const int* perm,
                          const float* invc, const float* hin, const float* basis,
                          const float* comp, const float* root, const float* bias,
                          float* hout, const int* inv, float* xlist, int layer,
                          const int* list, const int* cntp) {
  int cnt = cN;
  if (cntp) {
    cnt = *cntp;
    if (blockIdx.x * 8 >= cnt) return;
  }
  __shared__ float sB0[1024];
  __shared__ float sB1[1024];
  __shared__ float sRt[1024];
  __shared__ float sZ0[8][32];
  __shared__ float sZ1[8][32];
  __shared__ float sHl[8][32];
  __shared__ float sBias[32];
  __shared__ float sC0[8];
  __shared__ float sC1[8];
  int t = threadIdx.x;
  for (int idx = t; idx < 1024; idx += 256) {
    sB0[idx] = basis[idx];
    sB1[idx] = basis[1024 + idx];
    sRt[idx] = root[idx];
  }
  if (t < 32) sBias[t] = bias[t];
  if (t < cR) { sC0[t] = comp[t * 2]; sC1[t] = comp[t * 2 + 1]; }
  __syncthreads();
  int nd = t >> 5, li = t & 31;
  int idx8 = blockIdx.x * 8 + nd;
  int n;
  if (list) n = (idx8 < cnt) ? list[idx8] : list[0];
  else n = idx8;
  sHl[nd][li] = hin[(long long)n * 32 + li];
  int st = off[n * 5], en = cur[n * 5 + 4];
  float z0 = 0.0f, z1 = 0.0f;
  int j = st;
  for (; j + 1 < en; j += 2) {
    int p0 = perm[j], p1 = perm[j + 1];
    float i0 = invc[j], i1 = invc[j + 1];
    float s0 = hin[(long long)(p0 >> 5) * 32 + li];
    float s1 = hin[(long long)(p1 >> 5) * 32 + li];
    int r0 = (p0 >> 2) & 7, r1 = (p1 >> 2) & 7;
    float w00 = sC0[r0] * i0, w10 = sC1[r0] * i0;
    float w01 = sC0[r1] * i1, w11 = sC1[r1] * i1;
    z0 += w00 * s0 + w01 * s1;
    z1 += w10 * s0 + w11 * s1;
  }
  if (j < en) {
    int p0 = perm[j];
    float i0 = invc[j];
    float s0 = hin[(long long)(p0 >> 5) * 32 + li];
    int r0 = (p0 >> 2) & 7;
    z0 += sC0[r0] * i0 * s0;
    z1 += sC1[r0] * i0 * s0;
  }
  sZ0[nd][li] = z0;
  sZ1[nd][li] = z1;
  __syncthreads();
  float a = sBias[li];
  for (int i = 0; i < 32; i++)
    a += sZ0[nd][i] * sB0[i * 32 + li] + sZ1[nd][i] * sB1[i * 32 + li] +
         sHl[nd][i] * sRt[i * 32 + li];
  float val = tanhf(a);
  hout[(long long)n * 32 + li] = val;
  if (inv) {
    int iv = inv[n];
    if (iv >= 0) xlist[iv + layer * 32 + li] = val;
  }
}

// ---------- tier2: batched layer 0 across all 5 graphs (grid = 5*GB0) ----------
__global__ void k_gather0B(const int* offA, const int* curA, const int* permA,
                           const float* invcA, const int* clsA,
                           const float* basis0, const float* comp0,
                           const float* root0, const float* bias0,
                           float* houtB, const int* inv, float* xlist,
                           const int* listA, const int* counts) {
  int g = blockIdx.x / GB0;
  int b2 = blockIdx.x - g * GB0;
  int cnt = counts[g * 4 + 3];
  if (b2 * 8 >= cnt) return;
  const int* off = offA + (long long)g * cNR;
  const int* cur = curA + (long long)g * cNR;
  const int* perm = permA + (long long)g * cE;
  const float* invc = invcA + (long long)g * cE;
  const int* cls = clsA + (long long)g * cN;
  const int* list = listA + (long long)g * cN;
  const int* invg = inv + (long long)g * cN;
  float* hout = houtB + (long long)g * cN * 32;
  __shared__ float sW0[640];
  __shared__ float sRt[128];
  __shared__ float sB[32];
  int t = threadIdx.x;
  for (int idx = t; idx < 640; idx += 256) {
    int r = idx / 128, rem = idx - r * 128;
    sW0[idx] = comp0[r * 2] * basis0[rem] + comp0[r * 2 + 1] * basis0[128 + rem];
  }
  if (t < 128) sRt[t] = root0[t];
  if (t < 32) sB[t] = bias0[t];
  __syncthreads();
  int nd = t >> 5, li = t & 31;
  int idx8 = b2 * 8 + nd;
  int n = (idx8 < cnt) ? list[idx8] : list[0];
  int st = off[n * 5], en = cur[n * 5 + 4];
  float tot = 0.0f;
  int j = st;
  for (; j + 1 < en; j += 2) {
    int p0 = perm[j], p1 = perm[j + 1];
    float i0 = invc[j], i1 = invc[j + 1];
    tot += sW0[(p0 & 31) * 32 + li] * i0 + sW0[(p1 & 31) * 32 + li] * i1;
  }
  if (j < en) tot += sW0[(perm[j] & 31) * 32 + li] * invc[j];
  float val = tanhf(tot + sRt[cls[n] * 32 + li] + sB[li]);
  hout[(long long)n * 32 + li] = val;
  int iv = invg[n];
  if (iv >= 0) xlist[iv + li] = val;
}

// ---------- tier2: batched layers 1..3 (grid = 5*GB0) ----------
__global__ void k_gatherRB(const int* offA, const int* curA, const int* permA,
                           const float* invcA, const float* hinB,
                           const float* basis, const float* comp,
                           const float* root, const float* bias,
                           float* houtB, const int* inv, float* xlist, int layer,
                           const int* listA, const int* counts, int koff) {
  int g = blockIdx.x / GB0;
  int b2 = blockIdx.x - g * GB0;
  int cnt = counts[g * 4 + koff];
  if (b2 * 8 >= cnt) return;
  const int* off = offA + (long long)g * cNR;
  const int* cur = curA + (long long)g * cNR;
  const int* perm = permA + (long long)g * cE;
  const float* invc = invcA + (long long)g * cE;
  const int* list = listA + (long long)g * cN;
  const int* invg = inv + (long long)g * cN;
  const float* hin = hinB + (long long)g * cN * 32;
  float* hout = houtB + (long long)g * cN * 32;
  __shared__ float sB0[1024];
  __shared__ float sB1[1024];
  __shared__ float sRt[1024];
  __shared__ float sZ0[8][32];
  __shared__ float sZ1[8][32];
  __shared__ float sHl[8][32];
  __shared__ float sBias[32];
  __shared__ float sC0[8];
  __shared__ float sC1[8];
  int t = threadIdx.x;
  for (int idx = t; idx < 1024; idx += 256) {
    sB0[idx] = basis[idx];
    sB1[idx] = basis[1024 + idx];
    sRt[idx] = root[idx];
  }
  if (t < 32) sBias[t] = bias[t];
  if (t < cR) { sC0[t] = comp[t * 2]; sC1[t] = comp[t * 2 + 1]; }
  __syncthreads();
  int nd = t >> 5, li = t & 31;
  int idx8 = b2 * 8 + nd;
  int n = (idx8 < cnt) ? list[idx8] : list[0];
  sHl[nd][li] = hin[(long long)n * 32 + li];
  int st = off[n * 5], en = cur[n * 5 + 4];
  float z0 = 0.0f, z1 = 0.0f;
  int j = st;
  for (; j + 1 < en; j += 2) {
    int p0 = perm[j], p1 = perm[j + 1];
    float i0 = invc[j], i1 = invc[j + 1];
    float s0 = hin[(long long)(p0 >> 5) * 32 + li];
    float s1 = hin[(long long)(p1 >> 5) * 32 + li];
    int r0 = (p0 >> 2) & 7, r1 = (p1 >> 2) & 7;
    float w00 = sC0[r0] * i0, w10 = sC1[r0] * i0;
    float w01 = sC0[r1] * i1, w11 = sC1[r1] * i1;
    z0 += w00 * s0 + w01 * s1;
    z1 += w10 * s0 + w11 * s1;
  }
  if (j < en) {
    int p0 = perm[j];
    float i0 = invc[j];
    float s0 = hin[(long long)(p0 >> 5) * 32 + li];
    int r0 = (p0 >> 2) & 7;
    z0 += sC0[r0] * i0 * s0;
    z1 += sC1[r0] * i0 * s0;
  }
  sZ0[nd][li] = z0;
  sZ1[nd][li] = z1;
  __syncthreads();
  float a = sBias[li];
  for (int i = 0; i < 32; i++)
    a += sZ0[nd][i] * sB0[i * 32 + li] + sZ1[nd][i] * sB1[i * 32 + li] +
         sHl[nd][i] * sRt[i * 32 + li];
  float val = tanhf(a);
  hout[(long long)n * 32 + li] = val;
  int iv = invg[n];
  if (iv >= 0) xlist[iv + layer * 32 + li] = val;
}

// ---------- ordered compaction: first cB nodes with x[:,c]==1 ----------
__global__ void k_uidx(const float* x, int* uidx) {
  int g = blockIdx.x >> 1, c = blockIdx.x & 1;
  __shared__ int sFlag[256];
  __shared__ int sBase;
  int t = threadIdx.x;
  if (t < cB) uidx[(g * 2 + c) * cB + t] = 0;
  if (t == 0) sBase = 0;
  __syncthreads();
  for (int chunk = 0; chunk < cN; chunk += 256) {
    int n = chunk + t;
    sFlag[t] = (n < cN && x[((long long)g * cN + n) * 4 + c] == 1.0f) ? 1 : 0;
    __syncthreads();
    if (t == 0) {
      int base = sBase;
      for (int t2 = 0; t2 < 256; t2++) {
        if (sFlag[t2]) {
          if (base < cB) uidx[(g * 2 + c) * cB + base] = chunk + t2;
          base++;
        }
      }
      sBase = base;
    }
    __syncthreads();
    if (sBase >= cB) break;
  }
}

__global__ void k_extract(const float* h, const int* uidx, float* xlist, int g, int layer) {
  int i = blockIdx.x * 256 + threadIdx.x;
  if (i >= 2 * cB * 32) return;
  int o = i & 31;
  int rest = i >> 5;
  int b = rest % cB, c = rest / cB;
  int node = uidx[(g * 2 + c) * cB + b];
  xlist[(g * cB + b) * 256 + c * 128 + layer * 32 + o] = h[(long long)node * 32 + o];
}

// ---------- STAM: fused QKV + attention v6 ----------
__global__ void k_attn2(const int* tt, const float* emb, const float* pos,
                        const float* Qw, const float* Kw, const float* Vw,
                        float* hatt, int gb_base) {
  int gbl = blockIdx.x >> 2, hh = blockIdx.x & 3;
  int gb = gb_base + gbl;
  __shared__ float smem[12160];          // 48640 B: QKV 9600 + sT 2*1280
  float* sQ = smem;
  float* sK = smem + 3200;
  float* sV = smem + 6400;
  float* sT = smem + 9600;               // 2 bufs x 20 rows x 64
  int t = threadIdx.x;
  float wreg[64];
  int c48 = t % 48, rgrp = t / 48;       // rgrp<4 for t<192
  int mat = c48 >> 4, dh = c48 & 15;
  if (t < 192) {
    const float* W = (mat == 0) ? Qw : ((mat == 1) ? Kw : Vw);
    const float* wp = W + hh * 16 + dh;
#pragma unroll
    for (int i = 0; i < 64; i += 4) {
      wreg[i] = wp[i * 64];
      wreg[i + 1] = wp[(i + 1) * 64];
      wreg[i + 2] = wp[(i + 2) * 64];
      wreg[i + 3] = wp[(i + 3) * 64];
    }
  }
  const int* ttg = tt + (long long)gb * 200;
  float r[5];
#define LOADC(c)                                                        \
  {                                                                     \
    _Pragma("unroll")                                                   \
    for (int k = 0; k < 5; k++) {                                       \
      int idx = k * 256 + t;                                            \
      int row = idx >> 6, d2 = idx & 63;                                \
      int l = (c) * 20 + row;                                           \
      r[k] = emb[(long long)ttg[l] * 64 + d2] + pos[l * 64 + d2];       \
    }                                                                   \
  }
#define STOREC(pb)                                                      \
  {                                                                     \
    _Pragma("unroll")                                                   \
    for (int k = 0; k < 5; k++) sT[(pb) * 1280 + k * 256 + t] = r[k];   \
  }
  LOADC(0)
  STOREC(0)
  LOADC(1)
  for (int c = 0; c < 10; c++) {
    int p = c & 1;
    if (c >= 1) __syncthreads();
    if (c + 1 < 10) STOREC(1 - p)
    if (c + 2 < 10) LOADC(c + 2)
    __syncthreads();
    if (t < 192) {
      const float* base = sT + p * 1280;
      float acc0 = 0.0f, acc1 = 0.0f, acc2 = 0.0f, acc3 = 0.0f, acc4 = 0.0f;
#pragma unroll
      for (int i4 = 0; i4 < 16; i4++) {
        float w0 = wreg[i4 * 4], w1 = wreg[i4 * 4 + 1],
              w2 = wreg[i4 * 4 + 2], w3 = wreg[i4 * 4 + 3];
        float4 t0 = ((const float4*)(base + (rgrp * 5 + 0) * 64))[i4];
        float4 t1 = ((const float4*)(base + (rgrp * 5 + 1) * 64))[i4];
        float4 t2 = ((const float4*)(base + (rgrp * 5 + 2) * 64))[i4];
        float4 t3 = ((const float4*)(base + (rgrp * 5 + 3) * 64))[i4];
        float4 t4 = ((const float4*)(base + (rgrp * 5 + 4) * 64))[i4];
        acc0 += t0.x * w0 + t0.y * w1 + t0.z * w2 + t0.w * w3;
        acc1 += t1.x * w0 + t1.y * w1 + t1.z * w2 + t1.w * w3;
        acc2 += t2.x * w0 + t2.y * w1 + t2.z * w2 + t2.w * w3;
        acc3 += t3.x * w0 + t3.y * w1 + t3.z * w2 + t3.w * w3;
        acc4 += t4.x * w0 + t4.y * w1 + t4.z * w2 + t4.w * w3;
      }
      float* dst = (mat == 0) ? sQ : ((mat == 1) ? sK : sV);
      int ll = c * 20 + rgrp * 5;
      dst[(ll + 0) * 16 + dh] = acc0;
      dst[(ll + 1) * 16 + dh] = acc1;
      dst[(ll + 2) * 16 + dh] = acc2;
      dst[(ll + 3) * 16 + dh] = acc3;
      dst[(ll + 4) * 16 + dh] = acc4;
    }
  }
#undef LOADC
#undef STOREC
  __syncthreads();
  float4 oa0 = {0,0,0,0}, oa1 = {0,0,0,0}, oa2 = {0,0,0,0}, oa3 = {0,0,0,0};
  float4 ob0 = {0,0,0,0}, ob1 = {0,0,0,0}, ob2 = {0,0,0,0}, ob3 = {0,0,0,0};
  float lsa = 0.0f, lsb = 0.0f;
  if (t < 200) {
    int a = t % 100, mh = t / 100;
    float scale = 1.0f / sqrtf(200.0f);
    const float4* q4 = (const float4*)sQ;
    float4 qa0 = q4[(2 * a) * 4], qa1 = q4[(2 * a) * 4 + 1],
           qa2 = q4[(2 * a) * 4 + 2], qa3 = q4[(2 * a) * 4 + 3];
    float4 qb0 = q4[(2 * a + 1) * 4], qb1 = q4[(2 * a + 1) * 4 + 1],
           qb2 = q4[(2 * a + 1) * 4 + 2], qb3 = q4[(2 * a + 1) * 4 + 3];
    qa0.x *= scale; qa0.y *= scale; qa0.z *= scale; qa0.w *= scale;
    qa1.x *= scale; qa1.y *= scale; qa1.z *= scale; qa1.w *= scale;
    qa2.x *= scale; qa2.y *= scale; qa2.z *= scale; qa2.w *= scale;
    qa3.x *= scale; qa3.y *= scale; qa3.z *= scale; qa3.w *= scale;
    qb0.x *= scale; qb0.y *= scale; qb0.z *= scale; qb0.w *= scale;
    qb1.x *= scale; qb1.y *= scale; qb1.z *= scale; qb1.w *= scale;
    qb2.x *= scale; qb2.y *= scale; qb2.z *= scale; qb2.w *= scale;
    qb3.x *= scale; qb3.y *= scale; qb3.z *= scale; qb3.w *= scale;
    const float4* kk = ((const float4*)sK) + mh * 400;
    const float4* vv = ((const float4*)sV) + mh * 400;
#pragma unroll 2
    for (int m = 0; m < 100; m++) {
      float4 k0 = kk[m * 4], k1 = kk[m * 4 + 1], k2 = kk[m * 4 + 2],
             k3 = kk[m * 4 + 3];
      float sa = qa0.x * k0.x + qa0.y * k0.y + qa0.z * k0.z + qa0.w * k0.w +
                 qa1.x * k1.x + qa1.y * k1.y + qa1.z * k1.z + qa1.w * k1.w +
                 qa2.x * k2.x + qa2.y * k2.y + qa2.z * k2.z + qa2.w * k2.w +
                 qa3.x * k3.x + qa3.y * k3.y + qa3.z * k3.z + qa3.w * k3.w;
      float sb = qb0.x * k0.x + qb0.y * k0.y + qb0.z * k0.z + qb0.w * k0.w +
                 qb1.x * k1.x + qb1.y * k1.y + qb1.z * k1.z + qb1.w * k1.w +
                 qb2.x * k2.x + qb2.y * k2.y + qb2.z * k2.z + qb2.w * k2.w +
                 qb3.x * k3.x + qb3.y * k3.y + qb3.z * k3.z + qb3.w * k3.w;
      float ea = __expf(sa);
      float eb = __expf(sb);
      float4 v0 = vv[m * 4], v1 = vv[m * 4 + 1], v2 = vv[m * 4 + 2],
             v3 = vv[m * 4 + 3];
      lsa += ea; lsb += eb;
      oa0.x += ea * v0.x; oa0.y += ea * v0.y; oa0.z += ea * v0.z; oa0.w += ea * v0.w;
      oa1.x += ea * v1.x; oa1.y += ea * v1.y; oa1.z += ea * v1.z; oa1.w += ea * v1.w;
      oa2.x += ea * v2.x; oa2.y += ea * v2.y; oa2.z += ea * v2.z; oa2.w += ea * v2.w;
      oa3.x += ea * v3.x; oa3.y += ea * v3.y; oa3.z += ea * v3.z; oa3.w += ea * v3.w;
      ob0.x += eb * v0.x; ob0.y += eb * v0.y; ob0.z += eb * v0.z; ob0.w += eb * v0.w;
      ob1.x += eb * v1.x; ob1.y += eb * v1.y; ob1.z += eb * v1.z; ob1.w += eb * v1.w;
      ob2.x += eb * v2.x; ob2.y += eb * v2.y; ob2.z += eb * v2.z; ob2.w += eb * v2.w;
      ob3.x += eb * v3.x; ob3.y += eb * v3.y; ob3.z += eb * v3.z; ob3.w += eb * v3.w;
    }
  }
  __syncthreads();
  if (t < 200) {
    float* pp = smem + t * 34;
    pp[0]  = oa0.x; pp[1]  = oa0.y; pp[2]  = oa0.z; pp[3]  = oa0.w;
    pp[4]  = oa1.x; pp[5]  = oa1.y; pp[6]  = oa1.z; pp[7]  = oa1.w;
    pp[8]  = oa2.x; pp[9]  = oa2.y; pp[10] = oa2.z; pp[11] = oa2.w;
    pp[12] = oa3.x; pp[13] = oa3.y; pp[14] = oa3.z; pp[15] = oa3.w;
    pp[16] = lsa;
    pp[17] = ob0.x; pp[18] = ob0.y; pp[19] = ob0.z; pp[20] = ob0.w;
    pp[21] = ob1.x; pp[22] = ob1.y; pp[23] = ob1.z; pp[24] = ob1.w;
    pp[25] = ob2.x; pp[26] = ob2.y; pp[27] = ob2.z; pp[28] = ob2.w;
    pp[29] = ob3.x; pp[30] = ob3.y; pp[31] = ob3.z; pp[32] = ob3.w;
    pp[33] = lsb;
  }
  __syncthreads();
  if (t < 200) {
    int a = t >> 1, r2 = t & 1;
    const float* p0 = smem + a * 34 + r2 * 17;
    const float* p1 = smem + (100 + a) * 34 + r2 * 17;
    float inv = 1.0f / (p0[16] + p1[16]);
    float4 o0, o1, o2, o3;
    o0.x = (p0[0]  + p1[0])  * inv; o0.y = (p0[1]  + p1[1])  * inv;
    o0.z = (p0[2]  + p1[2])  * inv; o0.w = (p0[3]  + p1[3])  * inv;
    o1.x = (p0[4]  + p1[4])  * inv; o1.y = (p0[5]  + p1[5])  * inv;
    o1.z = (p0[6]  + p1[6])  * inv; o1.w = (p0[7]  + p1[7])  * inv;
    o2.x = (p0[8]  + p1[8])  * inv; o2.y = (p0[9]  + p1[9])  * inv;
    o2.z = (p0[10] + p1[10]) * inv; o2.w = (p0[11] + p1[11]) * inv;
    o3.x = (p0[12] + p1[12]) * inv; o3.y = (p0[13] + p1[13]) * inv;
    o3.z = (p0[14] + p1[14]) * inv; o3.w = (p0[15] + p1[15]) * inv;
    float4* outp = (float4*)(hatt + ((long long)gbl * 200 + t) * 64 + hh * 16);
    outp[0] = o0; outp[1] = o1; outp[2] = o2; outp[3] = o3;
  }
}

// ---------- STAM phase A: conv -> sAg ----------
__global__ void __launch_bounds__(512, 4) k_conv(
    const float* hatt, const int* tt, const int* cen,
    const float* emb, const float* pos, const float* convW,
    const float* convb, float* sAg, int gb_base) {
  int gbl = blockIdx.x;
  int gb = gb_base + gbl;
  __shared__ float sH[12800];
  int t = threadIdx.x;
  const float4* hb4 = (const float4*)(hatt + (long long)gbl * 12800);
  float4* sH4 = (float4*)sH;
  for (int i = t; i < 3200; i += 512) sH4[i] = hb4[i];
  int og = t >> 6, d = t & 63;
  float w1 = emb[(long long)cen[gb] * 64 + d];
  __syncthreads();
  int o0 = og * 25;
  {
    const float* cwb = convW + o0 * 200;
    float acc[13];
#pragma unroll
    for (int q = 0; q < 13; q++) acc[q] = 0.0f;
    for (int l2 = 0; l2 < 200; l2 += 4) {
      float s0 = sH[(l2 + 0) * 64 + d];
      float s1 = sH[(l2 + 1) * 64 + d];
      float s2 = sH[(l2 + 2) * 64 + d];
      float s3 = sH[(l2 + 3) * 64 + d];
#pragma unroll
      for (int q = 0; q < 13; q++) {
        float4 c4 = *(const float4*)(cwb + q * 200 + l2);
        acc[q] += c4.x * s0 + c4.y * s1 + c4.z * s2 + c4.w * s3;
      }
    }
    float tv[13];
#pragma unroll
    for (int q = 0; q < 13; q++) {
      int o = o0 + q;
      tv[q] = emb[(long long)tt[(long long)gb * 200 + o] * 64 + d] + pos[o * 64 + d];
    }
#pragma unroll
    for (int q = 0; q < 13; q++) {
      int o = o0 + q;
      float outv = tv[q] + acc[q] + convb[o] + sH[o * 64 + d];
      float r1 = outv * outv;
      float r2 = outv * w1;
      for (int s = 32; s > 0; s >>= 1) {
        r1 += __shfl_xor(r1, s);
        r2 += __shfl_xor(r2, s);
      }
      if (d == 0) {
        float dn = sqrtf(r1);
        if (dn < 1e-12f) dn = 1e-12f;
        sAg[(long long)gb * 200 + o] = r2 / dn;
      }
    }
  }
  {
    const float* cwb = convW + (o0 + 13) * 200;
    float acc[12];
#pragma unroll
    for (int q = 0; q < 12; q++) acc[q] = 0.0f;
    for (int l2 = 0; l2 < 200; l2 += 4) {
      float s0 = sH[(l2 + 0) * 64 + d];
      float s1 = sH[(l2 + 1) * 64 + d];
      float s2 = sH[(l2 + 2) * 64 + d];
      float s3 = sH[(l2 + 3) * 64 + d];
#pragma unroll
      for (int q = 0; q < 12; q++) {
        float4 c4 = *(const float4*)(cwb + q * 200 + l2);
        acc[q] += c4.x * s0 + c4.y * s1 + c4.z * s2 + c4.w * s3;
      }
    }
    float tv[12];
#pragma unroll
    for (int q = 0; q < 12; q++) {
      int o = o0 + 13 + q;
      tv[q] = emb[(long long)tt[(long long)gb * 200 + o] * 64 + d] + pos[o * 64 + d];
    }
#pragma unroll
    for (int q = 0; q < 12; q++) {
      int o = o0 + 13 + q;
      float outv = tv[q] + acc[q] + convb[o] + sH[o * 64 + d];
      float r1 = outv * outv;
      float r2 = outv * w1;
      for (int s = 32; s > 0; s >>= 1) {
        r1 += __shfl_xor(r1, s);
        r2 += __shfl_xor(r2, s);
      }
      if (d == 0) {
        float dn = sqrtf(r1);
        if (dn < 1e-12f) dn = 1e-12f;
        sAg[(long long)gb * 200 + o] = r2 / dn;
      }
    }
  }
}

// ---------- STAM phase B+C ----------
__global__ void k_tw(const float* sAg, const int* tt, const float* lab,
                     const float* emb, float* embout) {
  int gb = blockIdx.x;
  __shared__ float sA[200];
  __shared__ float sP[256];
  __shared__ float sR[256];
  int t = threadIdx.x;
  float a0 = (t < 200) ? sAg[(long long)gb * 200 + t] : -1e30f;
  sP[t] = a0;
  __syncthreads();
  for (int s = 128; s > 0; s >>= 1) {
    if (t < s) { float o2 = sP[t + s]; if (o2 > sP[t]) sP[t] = o2; }
    __syncthreads();
  }
  float mx = sP[0];
  __syncthreads();
  float a = 0.0f;
  if (t < 200) a = expf(a0 - mx) * lab[(long long)gb * 200 + t];
  sP[t] = a;
  __syncthreads();
  for (int s = 128; s > 0; s >>= 1) {
    if (t < s) sP[t] += sP[t + s];
    __syncthreads();
  }
  float sum = sP[0];
  __syncthreads();
  if (t < 200) sA[t] = (sum > 0.0f) ? a / sum : 0.0f;
  __syncthreads();
  int og = t >> 6, d = t & 63;
  float acc2 = 0.0f;
  for (int l = og * 50; l < og * 50 + 50; l++)
    acc2 += sA[l] * emb[(long long)tt[(long long)gb * 200 + l] * 64 + d];
  sR[t] = acc2;
  __syncthreads();
  if (t < 64)
    embout[(long long)gb * 64 + t] = sR[t] + sR[64 + t] + sR[128 + t] + sR[192 + t];
}

// ---------- head ----------
__global__ void k_att1(const float* xlist, const float* aw1, const float* ab1,
                       const float* aw2, float* attK) {
  int blk = blockIdx.x;
  int b = blk / cG, g = blk - b * cG;
  int j = threadIdx.x;
  __shared__ float sRed[256];
  const float* sub = xlist + (g * cB + b) * 256;
  float acc = ab1[j];
  for (int i = 0; i < 256; i++) acc += sub[i] * aw1[i * 256 + j];
  if (acc < 0.0f) acc = 0.0f;
  sRed[j] = acc * aw2[j];
  __syncthreads();
  for (int s = 128; s > 0; s >>= 1) {
    if (j < s) sRed[j] += sRed[j + s];
    __syncthreads();
  }
  if (j == 0) attK[b * cG + g] = sRed[0];
}

__global__ void k_hm(const float* attK, const float* xlist, const float* mw1,
                     const float* mb1, float* metah) {
  int b = blockIdx.x;
  __shared__ float sAgg[256];
  int t = threadIdx.x;
  float a0 = attK[b * 5 + 0], a1 = attK[b * 5 + 1], a2 = attK[b * 5 + 2],
        a3 = attK[b * 5 + 3], a4 = attK[b * 5 + 4];
  float mx = a0;
  if (a1 > mx) mx = a1;
  if (a2 > mx) mx = a2;
  if (a3 > mx) mx = a3;
  if (a4 > mx) mx = a4;
  float e0 = expf(a0 - mx), e1 = expf(a1 - mx), e2 = expf(a2 - mx),
        e3 = expf(a3 - mx), e4 = expf(a4 - mx);
  float s = e0 + e1 + e2 + e3 + e4;
  sAgg[t] = (e0 * xlist[(0 * cB + b) * 256 + t] + e1 * xlist[(1 * cB + b) * 256 + t] +
             e2 * xlist[(2 * cB + b) * 256 + t] + e3 * xlist[(3 * cB + b) * 256 + t] +
             e4 * xlist[(4 * cB + b) * 256 + t]) / s;
  __syncthreads();
  for (int j = t; j < 512; j += 256) {
    float acc = mb1[j];
    for (int i = 0; i < 256; i++) acc += sAgg[i] * mw1[i * 512 + j];
    if (acc < 0.0f) acc = 0.0f;
    metah[b * 512 + j] = acc;
  }
}

__global__ void k_m2(const float* metah, const float* mw2, const float* mb2,
                     const float* xlist, const float* embout, float* xcat) {
  int i = blockIdx.x * 256 + threadIdx.x;
  if (i >= cB * 1920) return;
  int b = i / 1920, j = i - b * 1920;
  if (j < 1280) {
    float acc = mb2[j];
    const float* mh = metah + b * 512;
    for (int k = 0; k < 512; k++) acc += mh[k] * mw2[k * 1280 + j];
    int g = j >> 8, jj = j & 255;
    xcat[b * 1920 + j] = acc * xlist[(g * cB + b) * 256 + jj];
  } else {
    int jj = j - 1280;
    int g = jj >> 7, r = jj & 127;
    xcat[b * 1920 + j] = embout[(g * 100 + 2 * b + (r >> 6)) * 64 + (r & 63)];
  }
}

__global__ void k_l12(const float* xcat, const float* l1w, const float* l1b,
                      const float* l2w, const float* l2b, float* out) {
  int b = blockIdx.x;
  int t = threadIdx.x;
  __shared__ float sHH[128];
  float acc = l1b[t];
  const float* xc = xcat + b * 1920;
  for (int i = 0; i < 1920; i++) acc += xc[i] * l1w[i * 128 + t];
  if (acc < 0.0f) acc = 0.0f;
  sHH[t] = acc * l2w[t];
  __syncthreads();
  for (int s = 64; s > 0; s >>= 1) {
    if (t < s) sHH[t] += sHH[t + s];
    __syncthreads();
  }
  if (t == 0) out[b] = sHH[0] + l2b[0];
}

extern "C" void kernel_launch(void* const* d_in, const int* in_sizes, int n_in,
                              void* d_out, int out_size, void* d_ws, size_t ws_size,
                              hipStream_t stream) {
  const float* x      = (const float*)d_in[0];
  const int* ei       = (const int*)d_in[1];
  const int* et       = (const int*)d_in[2];
  const int* cen      = (const int*)d_in[3];
  const int* tt       = (const int*)d_in[4];
  const float* lab    = (const float*)d_in[5];
  const float* emb    = (const float*)d_in[6];
  const float* basis0 = (const float*)d_in[7];
  const float* comp0  = (const float*)d_in[8];
  const float* root0  = (const float*)d_in[9];
  const float* bias0  = (const float*)d_in[10];
  const float* basisR = (const float*)d_in[11];
  const float* compR  = (const float*)d_in[12];
  const float* rootR  = (const float*)d_in[13];
  const float* biasR  = (const float*)d_in[14];
  const float* pos    = (const float*)d_in[15];
  const float* Qw     = (const float*)d_in[16];
  const float* Kw     = (const float*)d_in[17];
  const float* Vw     = (const float*)d_in[18];
  const float* convW  = (const float*)d_in[19];
  const float* convb  = (const float*)d_in[20];
  const float* aw1    = (const float*)d_in[21];
  const float* ab1    = (const float*)d_in[22];
  const float* aw2    = (const float*)d_in[23];
  const float* mw1    = (const float*)d_in[24];
  const float* mb1    = (const float*)d_in[25];
  const float* mw2    = (const float*)d_in[26];
  const float* mb2    = (const float*)d_in[27];
  const float* l1w    = (const float*)d_in[28];
  const float* l1b    = (const float*)d_in[29];
  const float* l2w    = (const float*)d_in[30];
  const float* l2b    = (const float*)d_in[31];
  float* out          = (float*)d_out;
  char* p = (char*)d_ws;
  (void)in_sizes; (void)n_in; (void)out_size;

  if (ws_size >= FP_NEED) {
    int*   uidx   = (int*)(p + FP_UIDX);
    int*   bsumA  = (int*)(p + FP_BSUM);
    float* xlist  = (float*)(p + FP_XLIST);
    float* embout = (float*)(p + FP_EMBOUT);
    float* attK   = (float*)(p + FP_ATTK);
    float* metah  = (float*)(p + FP_METAH);
    float* xcat   = (float*)(p + FP_XCAT);
    float* sAg    = (float*)(p + FP_SAG);
    int*   inv    = (int*)(p + FP_INV);
    int*   clsA   = (int*)(p + FP_CLS);
    float* h_a    = (float*)(p + FP_HA);
    float* h_b    = (float*)(p + FP_HB);
    int*   curA   = (int*)(p + FP_CUR);
    int*   offA   = (int*)(p + FP_OFF);
    int*   permA  = (int*)(p + FP_PERM);
    float* invcA  = (float*)(p + FP_INVC);

    bool pruned  = (ws_size >= FP2_NEED);
    bool batched = (ws_size >= FP3_NEED);   // implies pruned
    int* markA  = pruned ? (int*)(p + FP2_MARK) : nullptr;
    int* listA  = pruned ? (int*)(p + FP2_LIST) : nullptr;
    int* cntA   = pruned ? (int*)(p + FP2_CNT) : nullptr;
    int* counts = pruned ? (int*)(p + FP2_COUNTS) : nullptr;
    float* hA5  = batched ? (float*)(p + FP3_HA) : nullptr;
    float* hB5  = batched ? (float*)(p + FP3_HB) : nullptr;
    // hatt: tier2 aliases hA5 (dead after gathers); else spans h_a..curA.
    float* hatt = batched ? hA5 : h_a;

    k_invinit<<<NBLK, 256, 0, stream>>>(inv);
    k_uidx<<<cG * 2, 256, 0, stream>>>(x, uidx);
    k_mkinv<<<1, 512, 0, stream>>>(uidx, inv);

    k_prepB<<<cG * NBLK, 256, 0, stream>>>(x, clsA, curA, markA);
    k_histgB<<<cG * NBLK, 256, 0, stream>>>(ei, et, curA);
    k_bsumB<<<cG * NBLK, 256, 0, stream>>>(curA, bsumA);
    k_bscanB<<<cG, 1024, 0, stream>>>(bsumA);
    k_mkoffB<<<cG * NBLK, 256, 0, stream>>>(curA, offA, bsumA, invcA);
    k_scatterB<<<cG * NBLK, 256, 0, stream>>>(ei, et, clsA, curA, permA);

    if (pruned) {
      k_mark<<<cG, 128, 0, stream>>>(uidx, markA, listA, cntA, counts);
      for (int k = 1; k <= 3; k++) {
        k_expand<<<cG * EXB, 256, 0, stream>>>(offA, curA, permA, markA, listA,
                                               cntA, counts, k);
        k_snap<<<1, 64, 0, stream>>>(counts, cntA, k);
      }
    }

    if (batched) {
      // one launch per layer across all 5 graphs (independent chains)
      k_gather0B<<<cG * GB0, 256, 0, stream>>>(offA, curA, permA, invcA, clsA,
                                               basis0, comp0, root0, bias0, hB5,
                                               inv, xlist, listA, counts);
      float* hinB = hB5;
      float* houB = hA5;
      for (int l = 0; l < 3; l++) {
        k_gatherRB<<<cG * GB0, 256, 0, stream>>>(offA, curA, permA, invcA, hinB,
                                                 basisR + l * 2048, compR + l * 10,
                                                 rootR + l * 1024, biasR + l * 32,
                                                 houB, inv, xlist, l + 1, listA,
                                                 counts, 2 - l);
        float* tmp = hinB; hinB = houB; houB = tmp;
      }
    } else {
      for (int g = 0; g < cG; g++) {
        const int*   offg  = offA + (long long)g * cNR;
        const int*   curg  = curA + (long long)g * cNR;
        const int*   permg = permA + (long long)g * cE;
        const float* invcg = invcA + (long long)g * cE;
        const int*   clsg  = clsA + (long long)g * cN;
        const int*   invg  = inv + (long long)g * cN;
        const int*   listg = pruned ? (listA + (long long)g * cN) : nullptr;
        const int* c0 = pruned ? (counts + g * 4 + 3) : nullptr;
        k_gather0<<<GB0, 256, 0, stream>>>(offg, curg, permg, invcg, clsg, basis0,
                                           comp0, root0, bias0, h_b, invg, xlist,
                                           listg, c0);
        float* hin = h_b;
        float* hou = h_a;
        for (int l = 0; l < 3; l++) {
          const int* cl = pruned ? (counts + g * 4 + (2 - l)) : nullptr;
          k_gatherR<<<GB0, 256, 0, stream>>>(offg, curg, permg, invcg, hin,
                                             basisR + l * 2048, compR + l * 10,
                                             rootR + l * 1024, biasR + l * 32, hou,
                                             invg, xlist, l + 1, listg, cl);
          float* tmp = hin; hin = hou; hou = tmp;
        }
      }
    }

    // single launches: all 500 gb in one grid (hatt is full-size here)
    k_attn2<<<2000, 256, 0, stream>>>(tt, emb, pos, Qw, Kw, Vw, hatt, 0);
    k_conv<<<500, 512, 0, stream>>>(hatt, tt, cen, emb, pos, convW, convb, sAg, 0);
    k_tw<<<500, 256, 0, stream>>>(sAg, tt, lab, emb, embout);

    k_att1<<<cB * cG, 256, 0, stream>>>(xlist, aw1, ab1, aw2, attK);
    k_hm<<<cB, 256, 0, stream>>>(attK, xlist, mw1, mb1, metah);
    k_m2<<<375, 256, 0, stream>>>(metah, mw2, mb2, xlist, embout, xcat);
    k_l12<<<cB, 128, 0, stream>>>(xcat, l1w, l1b, l2w, l2b, out);
    return;
  }

  // ---------------- fallback: exact R5 layout & schedule ----------------
  int*   uidx   = (int*)(p);
  int*   clsb   = (int*)(p + 4096);
  int*   cur    = (int*)(p + 208896);
  int*   off    = (int*)(p + 1212416);
  int*   perm   = (int*)(p + 2215936);
  float* invc   = (float*)(p + 3219456);
  int*   bsum   = (int*)(p + 4222976);
  float* xlist  = (float*)(p + 4227072);
  float* embout = (float*)(p + 4741120);
  float* attK   = (float*)(p + 4870144);
  float* metah  = (float*)(p + 4874240);
  float* xcat   = (float*)(p + 4980736);
  char*  arena  = p + 5368832;
  float* h_a    = (float*)(arena);
  float* h_b    = (float*)(arena + 6400000);
  float* hatt   = (float*)(arena);
  float* sAg    = (float*)(p + 4874240);

  k_uidx<<<cG * 2, 256, 0, stream>>>(x, uidx);

  for (int g = 0; g < cG; g++) {
    const int* eis = ei + (long long)g * 2 * cE;
    const int* eid = eis + cE;
    const int* etg = et + (long long)g * cE;
    const float* xg = x + (long long)g * cN * 4;
    k_prep<<<NBLK, 256, 0, stream>>>(xg, clsb, cur);
    k_histg<<<NBLK, 256, 0, stream>>>(eid, etg, cur);
    k_bsum<<<NBLK, 256, 0, stream>>>(cur, bsum);
    k_bscan<<<1, 1024, 0, stream>>>(bsum);
    k_mkoff<<<NBLK, 256, 0, stream>>>(cur, off, bsum);
    k_scatter<<<NBLK, 256, 0, stream>>>(eis, eid, etg, clsb, cur, perm);
    k_invc<<<NBLK, 256, 0, stream>>>(off, cur, invc);
    k_gather0<<<GB0, 256, 0, stream>>>(off, cur, perm, invc, clsb, basis0, comp0,
                                       root0, bias0, h_b, nullptr, nullptr,
                                       nullptr, nullptr);
    k_extract<<<13, 256, 0, stream>>>(h_b, uidx, xlist, g, 0);
    float* hin = h_b;
    float* hou = h_a;
    for (int l = 0; l < 3; l++) {
      k_gatherR<<<GB0, 256, 0, stream>>>(off, cur, perm, invc, hin,
                                         basisR + l * 2048, compR + l * 10,
                                         rootR + l * 1024, biasR + l * 32, hou,
                                         nullptr, nullptr, 0, nullptr, nullptr);
      k_extract<<<13, 256, 0, stream>>>(hou, uidx, xlist, g, l + 1);
      float* tmp = hin; hin = hou; hou = tmp;
    }
  }

  for (int c = 0; c < 2; c++) {
    k_attn2<<<1000, 256, 0, stream>>>(tt, emb, pos, Qw, Kw, Vw, hatt, c * 250);
    k_conv<<<250, 512, 0, stream>>>(hatt, tt, cen, emb, pos, convW, convb, sAg,
                                    c * 250);
  }
  k_tw<<<500, 256, 0, stream>>>(sAg, tt, lab, emb, embout);

  k_att1<<<cB * cG, 256, 0, stream>>>(xlist, aw1, ab1, aw2, attK);
  k_hm<<<cB, 256, 0, stream>>>(attK, xlist, mw1, mb1, metah);
  k_m2<<<375, 256, 0, stream>>>(metah, mw2, mb2, xlist, embout, xcat);
  k_l12<<<cB, 128, 0, stream>>>(xcat, l1w, l1b, l2w, l2b, out);
}

// Round 15
// 870.059 us; speedup vs baseline: 1.2416x; 1.0171x over previous
//
#include <hip/hip_runtime.h>
#include <hip/hip_bf16.h>

__global__ void IGMC_15247133901635_kernel() {}

#define cG 5
#define cN 50000
#define cE 250000
#define cB 50
#define cL 200
#define cD 64
#define cR 5
#define cNR 250000
#define cGB 500
#define NBLK 977
#define GB0 6250

// ---------------- fast-path workspace layout (bytes) ----------------
#define FP_UIDX   0
#define FP_BSUM   4096
#define FP_XLIST  28672
#define FP_EMBOUT 540672
#define FP_ATTK   668672
#define FP_METAH  672768
#define FP_XCAT   775168
#define FP_SAG    1159168
#define FP_INV    1559168
#define FP_CLS    2559168
#define FP_HA     3559168
#define FP_HB     9959168
#define FP_CUR    16359168
#define FP_OFF    21359168
#define FP_PERM   26359168
#define FP_INVC   31359168
#define FP_NEED   36359168ULL
// ---- pruned-path extras (tier 1) ----
#define FP2_MARK   36359168
#define FP2_LIST   37359168
#define FP2_CNT    38359168
#define FP2_COUNTS 38363264
#define FP2_NEED   38367360ULL
// ---- batched-gather extras (tier 2): per-graph h buffers ----
#define FP3_HA     38367360            // 5 * cN * 32 * 4 = 32,000,000
#define FP3_HB     70367360            // 32,000,000
#define FP3_NEED   102367360ULL
// tier2: hatt[500] (25.6 MB) aliases hA5 (dead after gathers).

// ---------- per-graph prep (fallback) ----------
__global__ void k_prep(const float* xg, int* cls, int* cur) {
  int i = blockIdx.x * 256 + threadIdx.x;
  if (i < cNR) cur[i] = 0;
  if (i < cN) {
    int c = 0;
    if (xg[i * 4 + 1] == 1.0f) c = 1;
    else if (xg[i * 4 + 2] == 1.0f) c = 2;
    else if (xg[i * 4 + 3] == 1.0f) c = 3;
    cls[i] = c;
  }
}

__global__ void k_histg(const int* eid, const int* etg, int* cur) {
  int e = blockIdx.x * 256 + threadIdx.x;
  if (e < cE) atomicAdd(&cur[eid[e] * cR + etg[e]], 1);
}

__global__ void k_bsum(const int* cur, int* bsum) {
  __shared__ int sC[256];
  int t = threadIdx.x;
  int i = blockIdx.x * 256 + t;
  sC[t] = (i < cNR) ? cur[i] : 0;
  __syncthreads();
  for (int s = 128; s > 0; s >>= 1) {
    if (t < s) sC[t] += sC[t + s];
    __syncthreads();
  }
  if (t == 0) bsum[blockIdx.x] = sC[0];
}

__global__ void __launch_bounds__(1024) k_bscan(int* bsum) {
  __shared__ int sS[1024];
  int t = threadIdx.x;
  int v = (t < NBLK) ? bsum[t] : 0;
  sS[t] = v;
  __syncthreads();
  for (int off = 1; off < 1024; off <<= 1) {
    int add = (t >= off) ? sS[t - off] : 0;
    __syncthreads();
    sS[t] += add;
    __syncthreads();
  }
  if (t < NBLK) bsum[t] = sS[t] - v;
}

__global__ void k_mkoff(int* cur, int* off, const int* bbase) {
  __shared__ int sC[256];
  __shared__ int sO[256];
  int t = threadIdx.x;
  int i = blockIdx.x * 256 + t;
  int c = (i < cNR) ? cur[i] : 0;
  sC[t] = c;
  __syncthreads();
  if (t == 0) {
    int run = 0;
    for (int k = 0; k < 256; k++) { sO[k] = run; run += sC[k]; }
  }
  __syncthreads();
  if (i < cNR) {
    int v = bbase[blockIdx.x] + sO[t];
    off[i] = v;
    cur[i] = v;
  }
}

__global__ void k_scatter(const int* eis, const int* eid, const int* etg,
                          const int* cls, int* cur, int* perm) {
  int e = blockIdx.x * 256 + threadIdx.x;
  if (e >= cE) return;
  int src = eis[e];
  int r = etg[e];
  int bin = eid[e] * cR + r;
  int pos = atomicAdd(&cur[bin], 1);
  perm[pos] = src * 32 + r * 4 + cls[src];
}

__global__ void k_invc(const int* off, const int* cur, float* invc) {
  int i = blockIdx.x * 256 + threadIdx.x;
  if (i >= cNR) return;
  int st = off[i], en = cur[i];
  if (en > st) {
    float ic = 1.0f / (float)(en - st);
    for (int j = st; j < en; j++) invc[j] = ic;
  }
}

// ---------- batched CSR build (fast path): grid = 5*NBLK ----------
// v2: inv[] init folded in (covers exactly i < cN per g); k_invinit removed.
__global__ void k_prepB(const float* x, int* clsA, int* curA, int* markA,
                        int* inv) {
  int g = blockIdx.x / NBLK;
  int i = (blockIdx.x - g * NBLK) * 256 + threadIdx.x;
  if (i < cNR) curA[g * cNR + i] = 0;
  if (i < cN) {
    const float* xg = x + (long long)g * cN * 4;
    int c = 0;
    if (xg[i * 4 + 1] == 1.0f) c = 1;
    else if (xg[i * 4 + 2] == 1.0f) c = 2;
    else if (xg[i * 4 + 3] == 1.0f) c = 3;
    clsA[g * cN + i] = c;
    inv[g * cN + i] = -1;
    if (markA) markA[g * cN + i] = 0;
  }
}

__global__ void k_histgB(const int* ei, const int* et, int* curA) {
  int g = blockIdx.x / NBLK;
  int e = (blockIdx.x - g * NBLK) * 256 + threadIdx.x;
  if (e >= cE) return;
  const int* eid = ei + (long long)g * 2 * cE + cE;
  const int* etg = et + (long long)g * cE;
  atomicAdd(&curA[g * cNR + eid[e] * cR + etg[e]], 1);
}

__global__ void k_bsumB(const int* curA, int* bsumA) {
  __shared__ int sC[256];
  int g = blockIdx.x / NBLK;
  int b2 = blockIdx.x - g * NBLK;
  int t = threadIdx.x;
  int i = b2 * 256 + t;
  sC[t] = (i < cNR) ? curA[g * cNR + i] : 0;
  __syncthreads();
  for (int s = 128; s > 0; s >>= 1) {
    if (t < s) sC[t] += sC[t + s];
    __syncthreads();
  }
  if (t == 0) bsumA[g * NBLK + b2] = sC[0];
}

__global__ void __launch_bounds__(1024) k_bscanB(int* bsumA) {
  __shared__ int sS[1024];
  int g = blockIdx.x;   // grid = 5
  int t = threadIdx.x;
  int v = (t < NBLK) ? bsumA[g * NBLK + t] : 0;
  sS[t] = v;
  __syncthreads();
  for (int off = 1; off < 1024; off <<= 1) {
    int add = (t >= off) ? sS[t - off] : 0;
    __syncthreads();
    sS[t] += add;
    __syncthreads();
  }
  if (t < NBLK) bsumA[g * NBLK + t] = sS[t] - v;
}

// invc fill fused (curA holds bin counts here; identical values/positions).
__global__ void k_mkoffB(int* curA, int* offA, const int* bsumA, float* invcA) {
  __shared__ int sC[256];
  __shared__ int sO[256];
  int g = blockIdx.x / NBLK;
  int b2 = blockIdx.x - g * NBLK;
  int t = threadIdx.x;
  int i = b2 * 256 + t;
  int c = (i < cNR) ? curA[g * cNR + i] : 0;
  sC[t] = c;
  __syncthreads();
  if (t == 0) {
    int run = 0;
    for (int k = 0; k < 256; k++) { sO[k] = run; run += sC[k]; }
  }
  __syncthreads();
  if (i < cNR) {
    int v = bsumA[g * NBLK + b2] + sO[t];
    offA[g * cNR + i] = v;
    curA[g * cNR + i] = v;
    if (c > 0) {
      float ic = 1.0f / (float)c;
      float* invc = invcA + (long long)g * cE;
      for (int j = v; j < v + c; j++) invc[j] = ic;
    }
  }
}

__global__ void k_scatterB(const int* ei, const int* et, const int* clsA,
                           int* curA, int* permA) {
  int g = blockIdx.x / NBLK;
  int e = (blockIdx.x - g * NBLK) * 256 + threadIdx.x;
  if (e >= cE) return;
  const int* eis = ei + (long long)g * 2 * cE;
  const int* eid = eis + cE;
  const int* etg = et + (long long)g * cE;
  int src = eis[e];
  int r = etg[e];
  int pos = atomicAdd(&curA[g * cNR + eid[e] * cR + r], 1);
  permA[g * cE + pos] = src * 32 + r * 4 + clsA[g * cN + src];
}

// ---------- inverse extraction map ----------
__global__ void k_mkinv(const int* uidx, int* inv) {
  int t = threadIdx.x;
  if (t < cG * 2 * cB) {
    int g = t / (2 * cB), r = t - g * 2 * cB;
    int c = r / cB, b = r - c * cB;
    int node = uidx[(g * 2 + c) * cB + b];
    inv[g * cN + node] = (g * cB + b) * 256 + c * 128;
  }
}

// ---------- dependency pruning: BFS over dst-keyed bins ----------
__global__ void k_mark(const int* uidx, int* markA, int* listA, int* cntA,
                       int* counts) {
  int g = blockIdx.x;   // grid = 5, 128 threads
  int t = threadIdx.x;
  if (t == 0) cntA[g] = 0;
  __syncthreads();
  if (t < 2 * cB) {
    int c = t / cB, b = t - c * cB;
    int node = uidx[(g * 2 + c) * cB + b];
    if (atomicExch(&markA[g * cN + node], 1) == 0) {
      int pos = atomicAdd(&cntA[g], 1);
      listA[g * cN + pos] = node;
    }
  }
  __syncthreads();
  if (t == 0) counts[g * 4 + 0] = atomicAdd(&cntA[g], 0);
}

#define EXB 196
__global__ void k_expand(const int* offA, const int* curA, const int* permA,
                         int* markA, int* listA, int* cntA, const int* counts,
                         int k) {
  int g = blockIdx.x / EXB;
  int i = (blockIdx.x - g * EXB) * 256 + threadIdx.x;
  int lo = (k == 1) ? 0 : counts[g * 4 + k - 2];
  int hi = counts[g * 4 + k - 1];
  int idx = lo + i;
  if (idx >= hi) return;
  int n = listA[g * cN + idx];
  int st = offA[g * cNR + n * 5], en = curA[g * cNR + n * 5 + 4];
  const int* perm = permA + (long long)g * cE;
  for (int j = st; j < en; j++) {
    int src = perm[j] >> 5;
    if (atomicExch(&markA[g * cN + src], 1) == 0) {
      int pos = atomicAdd(&cntA[g], 1);
      listA[g * cN + pos] = src;
    }
  }
}

__global__ void k_snap(int* counts, int* cntA, int k) {
  int t = threadIdx.x;
  if (t < cG) counts[t * 4 + k] = atomicAdd(&cntA[t], 0);
}

// ---------- RGCN layer 0 (per-graph; optional pruning + fused extract) ----------
__global__ void k_gather0(const int* off, const int* cur, const int* perm,
                          const float* invc, const int* cls, const float* basis0,
                          const float* comp0, const float* root0, const float* bias0,
                          float* hout, const int* inv, float* xlist,
                          const int* list, const int* cntp) {
  int cnt = cN;
  if (cntp) {
    cnt = *cntp;
    if (blockIdx.x * 8 >= cnt) return;
  }
  __shared__ float sW0[640];
  __shared__ float sRt[128];
  __shared__ float sB[32];
  int t = threadIdx.x;
  for (int idx = t; idx < 640; idx += 256) {
    int r = idx / 128, rem = idx - r * 128;
    sW0[idx] = comp0[r * 2] * basis0[rem] + comp0[r * 2 + 1] * basis0[128 + rem];
  }
  if (t < 128) sRt[t] = root0[t];
  if (t < 32) sB[t] = bias0[t];
  __syncthreads();
  int nd = t >> 5, li = t & 31;
  int idx8 = blockIdx.x * 8 + nd;
  int n;
  if (list) n = (idx8 < cnt) ? list[idx8] : list[0];
  else n = idx8;
  int st = off[n * 5], en = cur[n * 5 + 4];
  float tot = 0.0f;
  int j = st;
  for (; j + 1 < en; j += 2) {
    int p0 = perm[j], p1 = perm[j + 1];
    float i0 = invc[j], i1 = invc[j + 1];
    tot += sW0[(p0 & 31) * 32 + li] * i0 + sW0[(p1 & 31) * 32 + li] * i1;
  }
  if (j < en) tot += sW0[(perm[j] & 31) * 32 + li] * invc[j];
  float val = tanhf(tot + sRt[cls[n] * 32 + li] + sB[li]);
  hout[(long long)n * 32 + li] = val;
  if (inv) {
    int iv = inv[n];
    if (iv >= 0) xlist[iv + li] = val;
  }
}

// ---------- RGCN layers 1..3 (per-graph) ----------
__global__ void k_gatherR(const int* off, const int* cur, const int* perm,
                          const float* invc, const float* hin, const float* basis,
                          const float* comp, const float* root, const float* bias,
                          float* hout, const int* inv, float* xlist, int layer,
                          const int* list, const int* cntp) {
  int cnt = cN;
  if (cntp) {
    cnt = *cntp;
    if (blockIdx.x * 8 >= cnt) return;
  }
  __shared__ float sB0[1024];
  __shared__ float sB1[1024];
  __shared__ float sRt[1024];
  __shared__ float sZ0[8][32];
  __shared__ float sZ1[8][32];
  __shared__ float sHl[8][32];
  __shared__ float sBias[32];
  __shared__ float sC0[8];
  __shared__ float sC1[8];
  int t = threadIdx.x;
  for (int idx = t; idx < 1024; idx += 256) {
    sB0[idx] = basis[idx];
    sB1[idx] = basis[1024 + idx];
    sRt[idx] = root[idx];
  }
  if (t < 32) sBias[t] = bias[t];
  if (t < cR) { sC0[t] = comp[t * 2]; sC1[t] = comp[t * 2 + 1]; }
  __syncthreads();
  int nd = t >> 5, li = t & 31;
  int idx8 = blockIdx.x * 8 + nd;
  int n;
  if (list) n = (idx8 < cnt) ? list[idx8] : list[0];
  else n = idx8;
  sHl[nd][li] = hin[(long long)n * 32 + li];
  int st = off[n * 5], en = cur[n * 5 + 4];
  float z0 = 0.0f, z1 = 0.0f;
  int j = st;
  for (; j + 1 < en; j += 2) {
    int p0 = perm[j], p1 = perm[j + 1];
    float i0 = invc[j], i1 = invc[j + 1];
    float s0 = hin[(long long)(p0 >> 5) * 32 + li];
    float s1 = hin[(long long)(p1 >> 5) * 32 + li];
    int r0 = (p0 >> 2) & 7, r1 = (p1 >> 2) & 7;
    float w00 = sC0[r0] * i0, w10 = sC1[r0] * i0;
    float w01 = sC0[r1] * i1, w11 = sC1[r1] * i1;
    z0 += w00 * s0 + w01 * s1;
    z1 += w10 * s0 + w11 * s1;
  }
  if (j < en) {
    int p0 = perm[j];
    float i0 = invc[j];
    float s0 = hin[(long long)(p0 >> 5) * 32 + li];
    int r0 = (p0 >> 2) & 7;
    z0 += sC0[r0] * i0 * s0;
    z1 += sC1[r0] * i0 * s0;
  }
  sZ0[nd][li] = z0;
  sZ1[nd][li] = z1;
  __syncthreads();
  float a = sBias[li];
  for (int i = 0; i < 32; i++)
    a += sZ0[nd][i] * sB0[i * 32 + li] + sZ1[nd][i] * sB1[i * 32 + li] +
         sHl[nd][i] * sRt[i * 32 + li];
  float val = tanhf(a);
  hout[(long long)n * 32 + li] = val;
  if (inv) {
    int iv = inv[n];
    if (iv >= 0) xlist[iv + layer * 32 + li] = val;
  }
}

// ---------- tier2: batched layer 0 across all 5 graphs (grid = 5*GB0) ----------
__global__ void k_gather0B(const int* offA, const int* curA, const int* permA,
                           const float* invcA, const int* clsA,
                           const float* basis0, const float* comp0,
                           const float* root0, const float* bias0,
                           float* houtB, const int* inv, float* xlist,
                           const int* listA, const int* counts) {
  int g = blockIdx.x / GB0;
  int b2 = blockIdx.x - g * GB0;
  int cnt = counts[g * 4 + 3];
  if (b2 * 8 >= cnt) return;
  const int* off = offA + (long long)g * cNR;
  const int* cur = curA + (long long)g * cNR;
  const int* perm = permA + (long long)g * cE;
  const float* invc = invcA + (long long)g * cE;
  const int* cls = clsA + (long long)g * cN;
  const int* list = listA + (long long)g * cN;
  const int* invg = inv + (long long)g * cN;
  float* hout = houtB + (long long)g * cN * 32;
  __shared__ float sW0[640];
  __shared__ float sRt[128];
  __shared__ float sB[32];
  int t = threadIdx.x;
  for (int idx = t; idx < 640; idx += 256) {
    int r = idx / 128, rem = idx - r * 128;
    sW0[idx] = comp0[r * 2] * basis0[rem] + comp0[r * 2 + 1] * basis0[128 + rem];
  }
  if (t < 128) sRt[t] = root0[t];
  if (t < 32) sB[t] = bias0[t];
  __syncthreads();
  int nd = t >> 5, li = t & 31;
  int idx8 = b2 * 8 + nd;
  int n = (idx8 < cnt) ? list[idx8] : list[0];
  int st = off[n * 5], en = cur[n * 5 + 4];
  float tot = 0.0f;
  int j = st;
  for (; j + 1 < en; j += 2) {
    int p0 = perm[j], p1 = perm[j + 1];
    float i0 = invc[j], i1 = invc[j + 1];
    tot += sW0[(p0 & 31) * 32 + li] * i0 + sW0[(p1 & 31) * 32 + li] * i1;
  }
  if (j < en) tot += sW0[(perm[j] & 31) * 32 + li] * invc[j];
  float val = tanhf(tot + sRt[cls[n] * 32 + li] + sB[li]);
  hout[(long long)n * 32 + li] = val;
  int iv = invg[n];
  if (iv >= 0) xlist[iv + li] = val;
}

// ---------- tier2: batched layers 1..3 (grid = 5*GB0) ----------
__global__ void k_gatherRB(const int* offA, const int* curA, const int* permA,
                           const float* invcA, const float* hinB,
                           const float* basis, const float* comp,
                           const float* root, const float* bias,
                           float* houtB, const int* inv, float* xlist, int layer,
                           const int* listA, const int* counts, int koff) {
  int g = blockIdx.x / GB0;
  int b2 = blockIdx.x - g * GB0;
  int cnt = counts[g * 4 + koff];
  if (b2 * 8 >= cnt) return;
  const int* off = offA + (long long)g * cNR;
  const int* cur = curA + (long long)g * cNR;
  const int* perm = permA + (long long)g * cE;
  const float* invc = invcA + (long long)g * cE;
  const int* list = listA + (long long)g * cN;
  const int* invg = inv + (long long)g * cN;
  const float* hin = hinB + (long long)g * cN * 32;
  float* hout = houtB + (long long)g * cN * 32;
  __shared__ float sB0[1024];
  __shared__ float sB1[1024];
  __shared__ float sRt[1024];
  __shared__ float sZ0[8][32];
  __shared__ float sZ1[8][32];
  __shared__ float sHl[8][32];
  __shared__ float sBias[32];
  __shared__ float sC0[8];
  __shared__ float sC1[8];
  int t = threadIdx.x;
  for (int idx = t; idx < 1024; idx += 256) {
    sB0[idx] = basis[idx];
    sB1[idx] = basis[1024 + idx];
    sRt[idx] = root[idx];
  }
  if (t < 32) sBias[t] = bias[t];
  if (t < cR) { sC0[t] = comp[t * 2]; sC1[t] = comp[t * 2 + 1]; }
  __syncthreads();
  int nd = t >> 5, li = t & 31;
  int idx8 = b2 * 8 + nd;
  int n = (idx8 < cnt) ? list[idx8] : list[0];
  sHl[nd][li] = hin[(long long)n * 32 + li];
  int st = off[n * 5], en = cur[n * 5 + 4];
  float z0 = 0.0f, z1 = 0.0f;
  int j = st;
  for (; j + 1 < en; j += 2) {
    int p0 = perm[j], p1 = perm[j + 1];
    float i0 = invc[j], i1 = invc[j + 1];
    float s0 = hin[(long long)(p0 >> 5) * 32 + li];
    float s1 = hin[(long long)(p1 >> 5) * 32 + li];
    int r0 = (p0 >> 2) & 7, r1 = (p1 >> 2) & 7;
    float w00 = sC0[r0] * i0, w10 = sC1[r0] * i0;
    float w01 = sC0[r1] * i1, w11 = sC1[r1] * i1;
    z0 += w00 * s0 + w01 * s1;
    z1 += w10 * s0 + w11 * s1;
  }
  if (j < en) {
    int p0 = perm[j];
    float i0 = invc[j];
    float s0 = hin[(long long)(p0 >> 5) * 32 + li];
    int r0 = (p0 >> 2) & 7;
    z0 += sC0[r0] * i0 * s0;
    z1 += sC1[r0] * i0 * s0;
  }
  sZ0[nd][li] = z0;
  sZ1[nd][li] = z1;
  __syncthreads();
  float a = sBias[li];
  for (int i = 0; i < 32; i++)
    a += sZ0[nd][i] * sB0[i * 32 + li] + sZ1[nd][i] * sB1[i * 32 + li] +
         sHl[nd][i] * sRt[i * 32 + li];
  float val = tanhf(a);
  hout[(long long)n * 32 + li] = val;
  int iv = invg[n];
  if (iv >= 0) xlist[iv + layer * 32 + li] = val;
}

// ---------- ordered compaction: first cB nodes with x[:,c]==1 ----------
__global__ void k_uidx(const float* x, int* uidx) {
  int g = blockIdx.x >> 1, c = blockIdx.x & 1;
  __shared__ int sFlag[256];
  __shared__ int sBase;
  int t = threadIdx.x;
  if (t < cB) uidx[(g * 2 + c) * cB + t] = 0;
  if (t == 0) sBase = 0;
  __syncthreads();
  for (int chunk = 0; chunk < cN; chunk += 256) {
    int n = chunk + t;
    sFlag[t] = (n < cN && x[((long long)g * cN + n) * 4 + c] == 1.0f) ? 1 : 0;
    __syncthreads();
    if (t == 0) {
      int base = sBase;
      for (int t2 = 0; t2 < 256; t2++) {
        if (sFlag[t2]) {
          if (base < cB) uidx[(g * 2 + c) * cB + base] = chunk + t2;
          base++;
        }
      }
      sBase = base;
    }
    __syncthreads();
    if (sBase >= cB) break;
  }
}

__global__ void k_extract(const float* h, const int* uidx, float* xlist, int g, int layer) {
  int i = blockIdx.x * 256 + threadIdx.x;
  if (i >= 2 * cB * 32) return;
  int o = i & 31;
  int rest = i >> 5;
  int b = rest % cB, c = rest / cB;
  int node = uidx[(g * 2 + c) * cB + b];
  xlist[(g * cB + b) * 256 + c * 128 + layer * 32 + o] = h[(long long)node * 32 + o];
}

// ---------- STAM: fused QKV + attention v6 ----------
__global__ void k_attn2(const int* tt, const float* emb, const float* pos,
                        const float* Qw, const float* Kw, const float* Vw,
                        float* hatt, int gb_base) {
  int gbl = blockIdx.x >> 2, hh = blockIdx.x & 3;
  int gb = gb_base + gbl;
  __shared__ float smem[12160];          // 48640 B: QKV 9600 + sT 2*1280
  float* sQ = smem;
  float* sK = smem + 3200;
  float* sV = smem + 6400;
  float* sT = smem + 9600;               // 2 bufs x 20 rows x 64
  int t = threadIdx.x;
  float wreg[64];
  int c48 = t % 48, rgrp = t / 48;       // rgrp<4 for t<192
  int mat = c48 >> 4, dh = c48 & 15;
  if (t < 192) {
    const float* W = (mat == 0) ? Qw : ((mat == 1) ? Kw : Vw);
    const float* wp = W + hh * 16 + dh;
#pragma unroll
    for (int i = 0; i < 64; i += 4) {
      wreg[i] = wp[i * 64];
      wreg[i + 1] = wp[(i + 1) * 64];
      wreg[i + 2] = wp[(i + 2) * 64];
      wreg[i + 3] = wp[(i + 3) * 64];
    }
  }
  const int* ttg = tt + (long long)gb * 200;
  float r[5];
#define LOADC(c)                                                        \
  {                                                                     \
    _Pragma("unroll")                                                   \
    for (int k = 0; k < 5; k++) {                                       \
      int idx = k * 256 + t;                                            \
      int row = idx >> 6, d2 = idx & 63;                                \
      int l = (c) * 20 + row;                                           \
      r[k] = emb[(long long)ttg[l] * 64 + d2] + pos[l * 64 + d2];       \
    }                                                                   \
  }
#define STOREC(pb)                                                      \
  {                                                                     \
    _Pragma("unroll")                                                   \
    for (int k = 0; k < 5; k++) sT[(pb) * 1280 + k * 256 + t] = r[k];   \
  }
  LOADC(0)
  STOREC(0)
  LOADC(1)
  for (int c = 0; c < 10; c++) {
    int p = c & 1;
    if (c >= 1) __syncthreads();
    if (c + 1 < 10) STOREC(1 - p)
    if (c + 2 < 10) LOADC(c + 2)
    __syncthreads();
    if (t < 192) {
      const float* base = sT + p * 1280;
      float acc0 = 0.0f, acc1 = 0.0f, acc2 = 0.0f, acc3 = 0.0f, acc4 = 0.0f;
#pragma unroll
      for (int i4 = 0; i4 < 16; i4++) {
        float w0 = wreg[i4 * 4], w1 = wreg[i4 * 4 + 1],
              w2 = wreg[i4 * 4 + 2], w3 = wreg[i4 * 4 + 3];
        float4 t0 = ((const float4*)(base + (rgrp * 5 + 0) * 64))[i4];
        float4 t1 = ((const float4*)(base + (rgrp * 5 + 1) * 64))[i4];
        float4 t2 = ((const float4*)(base + (rgrp * 5 + 2) * 64))[i4];
        float4 t3 = ((const float4*)(base + (rgrp * 5 + 3) * 64))[i4];
        float4 t4 = ((const float4*)(base + (rgrp * 5 + 4) * 64))[i4];
        acc0 += t0.x * w0 + t0.y * w1 + t0.z * w2 + t0.w * w3;
        acc1 += t1.x * w0 + t1.y * w1 + t1.z * w2 + t1.w * w3;
        acc2 += t2.x * w0 + t2.y * w1 + t2.z * w2 + t2.w * w3;
        acc3 += t3.x * w0 + t3.y * w1 + t3.z * w2 + t3.w * w3;
        acc4 += t4.x * w0 + t4.y * w1 + t4.z * w2 + t4.w * w3;
      }
      float* dst = (mat == 0) ? sQ : ((mat == 1) ? sK : sV);
      int ll = c * 20 + rgrp * 5;
      dst[(ll + 0) * 16 + dh] = acc0;
      dst[(ll + 1) * 16 + dh] = acc1;
      dst[(ll + 2) * 16 + dh] = acc2;
      dst[(ll + 3) * 16 + dh] = acc3;
      dst[(ll + 4) * 16 + dh] = acc4;
    }
  }
#undef LOADC
#undef STOREC
  __syncthreads();
  float4 oa0 = {0,0,0,0}, oa1 = {0,0,0,0}, oa2 = {0,0,0,0}, oa3 = {0,0,0,0};
  float4 ob0 = {0,0,0,0}, ob1 = {0,0,0,0}, ob2 = {0,0,0,0}, ob3 = {0,0,0,0};
  float lsa = 0.0f, lsb = 0.0f;
  if (t < 200) {
    int a = t % 100, mh = t / 100;
    float scale = 1.0f / sqrtf(200.0f);
    const float4* q4 = (const float4*)sQ;
    float4 qa0 = q4[(2 * a) * 4], qa1 = q4[(2 * a) * 4 + 1],
           qa2 = q4[(2 * a) * 4 + 2], qa3 = q4[(2 * a) * 4 + 3];
    float4 qb0 = q4[(2 * a + 1) * 4], qb1 = q4[(2 * a + 1) * 4 + 1],
           qb2 = q4[(2 * a + 1) * 4 + 2], qb3 = q4[(2 * a + 1) * 4 + 3];
    qa0.x *= scale; qa0.y *= scale; qa0.z *= scale; qa0.w *= scale;
    qa1.x *= scale; qa1.y *= scale; qa1.z *= scale; qa1.w *= scale;
    qa2.x *= scale; qa2.y *= scale; qa2.z *= scale; qa2.w *= scale;
    qa3.x *= scale; qa3.y *= scale; qa3.z *= scale; qa3.w *= scale;
    qb0.x *= scale; qb0.y *= scale; qb0.z *= scale; qb0.w *= scale;
    qb1.x *= scale; qb1.y *= scale; qb1.z *= scale; qb1.w *= scale;
    qb2.x *= scale; qb2.y *= scale; qb2.z *= scale; qb2.w *= scale;
    qb3.x *= scale; qb3.y *= scale; qb3.z *= scale; qb3.w *= scale;
    const float4* kk = ((const float4*)sK) + mh * 400;
    const float4* vv = ((const float4*)sV) + mh * 400;
#pragma unroll 2
    for (int m = 0; m < 100; m++) {
      float4 k0 = kk[m * 4], k1 = kk[m * 4 + 1], k2 = kk[m * 4 + 2],
             k3 = kk[m * 4 + 3];
      float sa = qa0.x * k0.x + qa0.y * k0.y + qa0.z * k0.z + qa0.w * k0.w +
                 qa1.x * k1.x + qa1.y * k1.y + qa1.z * k1.z + qa1.w * k1.w +
                 qa2.x * k2.x + qa2.y * k2.y + qa2.z * k2.z + qa2.w * k2.w +
                 qa3.x * k3.x + qa3.y * k3.y + qa3.z * k3.z + qa3.w * k3.w;
      float sb = qb0.x * k0.x + qb0.y * k0.y + qb0.z * k0.z + qb0.w * k0.w +
                 qb1.x * k1.x + qb1.y * k1.y + qb1.z * k1.z + qb1.w * k1.w +
                 qb2.x * k2.x + qb2.y * k2.y + qb2.z * k2.z + qb2.w * k2.w +
                 qb3.x * k3.x + qb3.y * k3.y + qb3.z * k3.z + qb3.w * k3.w;
      float ea = __expf(sa);
      float eb = __expf(sb);
      float4 v0 = vv[m * 4], v1 = vv[m * 4 + 1], v2 = vv[m * 4 + 2],
             v3 = vv[m * 4 + 3];
      lsa += ea; lsb += eb;
      oa0.x += ea * v0.x; oa0.y += ea * v0.y; oa0.z += ea * v0.z; oa0.w += ea * v0.w;
      oa1.x += ea * v1.x; oa1.y += ea * v1.y; oa1.z += ea * v1.z; oa1.w += ea * v1.w;
      oa2.x += ea * v2.x; oa2.y += ea * v2.y; oa2.z += ea * v2.z; oa2.w += ea * v2.w;
      oa3.x += ea * v3.x; oa3.y += ea * v3.y; oa3.z += ea * v3.z; oa3.w += ea * v3.w;
      ob0.x += eb * v0.x; ob0.y += eb * v0.y; ob0.z += eb * v0.z; ob0.w += eb * v0.w;
      ob1.x += eb * v1.x; ob1.y += eb * v1.y; ob1.z += eb * v1.z; ob1.w += eb * v1.w;
      ob2.x += eb * v2.x; ob2.y += eb * v2.y; ob2.z += eb * v2.z; ob2.w += eb * v2.w;
      ob3.x += eb * v3.x; ob3.y += eb * v3.y; ob3.z += eb * v3.z; ob3.w += eb * v3.w;
    }
  }
  __syncthreads();
  if (t < 200) {
    float* pp = smem + t * 34;
    pp[0]  = oa0.x; pp[1]  = oa0.y; pp[2]  = oa0.z; pp[3]  = oa0.w;
    pp[4]  = oa1.x; pp[5]  = oa1.y; pp[6]  = oa1.z; pp[7]  = oa1.w;
    pp[8]  = oa2.x; pp[9]  = oa2.y; pp[10] = oa2.z; pp[11] = oa2.w;
    pp[12] = oa3.x; pp[13] = oa3.y; pp[14] = oa3.z; pp[15] = oa3.w;
    pp[16] = lsa;
    pp[17] = ob0.x; pp[18] = ob0.y; pp[19] = ob0.z; pp[20] = ob0.w;
    pp[21] = ob1.x; pp[22] = ob1.y; pp[23] = ob1.z; pp[24] = ob1.w;
    pp[25] = ob2.x; pp[26] = ob2.y; pp[27] = ob2.z; pp[28] = ob2.w;
    pp[29] = ob3.x; pp[30] = ob3.y; pp[31] = ob3.z; pp[32] = ob3.w;
    pp[33] = lsb;
  }
  __syncthreads();
  if (t < 200) {
    int a = t >> 1, r2 = t & 1;
    const float* p0 = smem + a * 34 + r2 * 17;
    const float* p1 = smem + (100 + a) * 34 + r2 * 17;
    float inv = 1.0f / (p0[16] + p1[16]);
    float4 o0, o1, o2, o3;
    o0.x = (p0[0]  + p1[0])  * inv; o0.y = (p0[1]  + p1[1])  * inv;
    o0.z = (p0[2]  + p1[2])  * inv; o0.w = (p0[3]  + p1[3])  * inv;
    o1.x = (p0[4]  + p1[4])  * inv; o1.y = (p0[5]  + p1[5])  * inv;
    o1.z = (p0[6]  + p1[6])  * inv; o1.w = (p0[7]  + p1[7])  * inv;
    o2.x = (p0[8]  + p1[8])  * inv; o2.y = (p0[9]  + p1[9])  * inv;
    o2.z = (p0[10] + p1[10]) * inv; o2.w = (p0[11] + p1[11]) * inv;
    o3.x = (p0[12] + p1[12]) * inv; o3.y = (p0[13] + p1[13]) * inv;
    o3.z = (p0[14] + p1[14]) * inv; o3.w = (p0[15] + p1[15]) * inv;
    float4* outp = (float4*)(hatt + ((long long)gbl * 200 + t) * 64 + hh * 16);
    outp[0] = o0; outp[1] = o1; outp[2] = o2; outp[3] = o3;
  }
}

// ---------- STAM phase A: conv -> sAg (v7: software-pipelined LDS reads) ----------
__global__ void __launch_bounds__(512, 4) k_conv(
    const float* hatt, const int* tt, const int* cen,
    const float* emb, const float* pos, const float* convW,
    const float* convb, float* sAg, int gb_base) {
  int gbl = blockIdx.x;
  int gb = gb_base + gbl;
  __shared__ float sH[12800];
  int t = threadIdx.x;
  const float4* hb4 = (const float4*)(hatt + (long long)gbl * 12800);
  float4* sH4 = (float4*)sH;
  for (int i = t; i < 3200; i += 512) sH4[i] = hb4[i];
  int og = t >> 6, d = t & 63;
  float w1 = emb[(long long)cen[gb] * 64 + d];
  __syncthreads();
  int o0 = og * 25;
  {
    const float* cwb = convW + o0 * 200;
    float acc[13];
#pragma unroll
    for (int q = 0; q < 13; q++) acc[q] = 0.0f;
    float s0n = sH[0 * 64 + d], s1n = sH[1 * 64 + d],
          s2n = sH[2 * 64 + d], s3n = sH[3 * 64 + d];
    for (int l2 = 0; l2 < 200; l2 += 4) {
      float s0 = s0n, s1 = s1n, s2 = s2n, s3 = s3n;
      if (l2 + 4 < 200) {
        s0n = sH[(l2 + 4) * 64 + d];
        s1n = sH[(l2 + 5) * 64 + d];
        s2n = sH[(l2 + 6) * 64 + d];
        s3n = sH[(l2 + 7) * 64 + d];
      }
#pragma unroll
      for (int q = 0; q < 13; q++) {
        float4 c4 = *(const float4*)(cwb + q * 200 + l2);
        acc[q] += c4.x * s0 + c4.y * s1 + c4.z * s2 + c4.w * s3;
      }
    }
    float tv[13];
#pragma unroll
    for (int q = 0; q < 13; q++) {
      int o = o0 + q;
      tv[q] = emb[(long long)tt[(long long)gb * 200 + o] * 64 + d] + pos[o * 64 + d];
    }
#pragma unroll
    for (int q = 0; q < 13; q++) {
      int o = o0 + q;
      float outv = tv[q] + acc[q] + convb[o] + sH[o * 64 + d];
      float r1 = outv * outv;
      float r2 = outv * w1;
      for (int s = 32; s > 0; s >>= 1) {
        r1 += __shfl_xor(r1, s);
        r2 += __shfl_xor(r2, s);
      }
      if (d == 0) {
        float dn = sqrtf(r1);
        if (dn < 1e-12f) dn = 1e-12f;
        sAg[(long long)gb * 200 + o] = r2 / dn;
      }
    }
  }
  {
    const float* cwb = convW + (o0 + 13) * 200;
    float acc[12];
#pragma unroll
    for (int q = 0; q < 12; q++) acc[q] = 0.0f;
    float s0n = sH[0 * 64 + d], s1n = sH[1 * 64 + d],
          s2n = sH[2 * 64 + d], s3n = sH[3 * 64 + d];
    for (int l2 = 0; l2 < 200; l2 += 4) {
      float s0 = s0n, s1 = s1n, s2 = s2n, s3 = s3n;
      if (l2 + 4 < 200) {
        s0n = sH[(l2 + 4) * 64 + d];
        s1n = sH[(l2 + 5) * 64 + d];
        s2n = sH[(l2 + 6) * 64 + d];
        s3n = sH[(l2 + 7) * 64 + d];
      }
#pragma unroll
      for (int q = 0; q < 12; q++) {
        float4 c4 = *(const float4*)(cwb + q * 200 + l2);
        acc[q] += c4.x * s0 + c4.y * s1 + c4.z * s2 + c4.w * s3;
      }
    }
    float tv[12];
#pragma unroll
    for (int q = 0; q < 12; q++) {
      int o = o0 + 13 + q;
      tv[q] = emb[(long long)tt[(long long)gb * 200 + o] * 64 + d] + pos[o * 64 + d];
    }
#pragma unroll
    for (int q = 0; q < 12; q++) {
      int o = o0 + 13 + q;
      float outv = tv[q] + acc[q] + convb[o] + sH[o * 64 + d];
      float r1 = outv * outv;
      float r2 = outv * w1;
      for (int s = 32; s > 0; s >>= 1) {
        r1 += __shfl_xor(r1, s);
        r2 += __shfl_xor(r2, s);
      }
      if (d == 0) {
        float dn = sqrtf(r1);
        if (dn < 1e-12f) dn = 1e-12f;
        sAg[(long long)gb * 200 + o] = r2 / dn;
      }
    }
  }
}

// ---------- STAM phase B+C ----------
__global__ void k_tw(const float* sAg, const int* tt, const float* lab,
                     const float* emb, float* embout) {
  int gb = blockIdx.x;
  __shared__ float sA[200];
  __shared__ float sP[256];
  __shared__ float sR[256];
  int t = threadIdx.x;
  float a0 = (t < 200) ? sAg[(long long)gb * 200 + t] : -1e30f;
  sP[t] = a0;
  __syncthreads();
  for (int s = 128; s > 0; s >>= 1) {
    if (t < s) { float o2 = sP[t + s]; if (o2 > sP[t]) sP[t] = o2; }
    __syncthreads();
  }
  float mx = sP[0];
  __syncthreads();
  float a = 0.0f;
  if (t < 200) a = expf(a0 - mx) * lab[(long long)gb * 200 + t];
  sP[t] = a;
  __syncthreads();
  for (int s = 128; s > 0; s >>= 1) {
    if (t < s) sP[t] += sP[t + s];
    __syncthreads();
  }
  float sum = sP[0];
  __syncthreads();
  if (t < 200) sA[t] = (sum > 0.0f) ? a / sum : 0.0f;
  __syncthreads();
  int og = t >> 6, d = t & 63;
  float acc2 = 0.0f;
  for (int l = og * 50; l < og * 50 + 50; l++)
    acc2 += sA[l] * emb[(long long)tt[(long long)gb * 200 + l] * 64 + d];
  sR[t] = acc2;
  __syncthreads();
  if (t < 64)
    embout[(long long)gb * 64 + t] = sR[t] + sR[64 + t] + sR[128 + t] + sR[192 + t];
}

// ---------- head ----------
__global__ void k_att1(const float* xlist, const float* aw1, const float* ab1,
                       const float* aw2, float* attK) {
  int blk = blockIdx.x;
  int b = blk / cG, g = blk - b * cG;
  int j = threadIdx.x;
  __shared__ float sRed[256];
  const float* sub = xlist + (g * cB + b) * 256;
  float acc = ab1[j];
  for (int i = 0; i < 256; i++) acc += sub[i] * aw1[i * 256 + j];
  if (acc < 0.0f) acc = 0.0f;
  sRed[j] = acc * aw2[j];
  __syncthreads();
  for (int s = 128; s > 0; s >>= 1) {
    if (j < s) sRed[j] += sRed[j + s];
    __syncthreads();
  }
  if (j == 0) attK[b * cG + g] = sRed[0];
}

__global__ void k_hm(const float* attK, const float* xlist, const float* mw1,
                     const float* mb1, float* metah) {
  int b = blockIdx.x;
  __shared__ float sAgg[256];
  int t = threadIdx.x;
  float a0 = attK[b * 5 + 0], a1 = attK[b * 5 + 1], a2 = attK[b * 5 + 2],
        a3 = attK[b * 5 + 3], a4 = attK[b * 5 + 4];
  float mx = a0;
  if (a1 > mx) mx = a1;
  if (a2 > mx) mx = a2;
  if (a3 > mx) mx = a3;
  if (a4 > mx) mx = a4;
  float e0 = expf(a0 - mx), e1 = expf(a1 - mx), e2 = expf(a2 - mx),
        e3 = expf(a3 - mx), e4 = expf(a4 - mx);
  float s = e0 + e1 + e2 + e3 + e4;
  sAgg[t] = (e0 * xlist[(0 * cB + b) * 256 + t] + e1 * xlist[(1 * cB + b) * 256 + t] +
             e2 * xlist[(2 * cB + b) * 256 + t] + e3 * xlist[(3 * cB + b) * 256 + t] +
             e4 * xlist[(4 * cB + b) * 256 + t]) / s;
  __syncthreads();
  for (int j = t; j < 512; j += 256) {
    float acc = mb1[j];
    for (int i = 0; i < 256; i++) acc += sAgg[i] * mw1[i * 512 + j];
    if (acc < 0.0f) acc = 0.0f;
    metah[b * 512 + j] = acc;
  }
}

__global__ void k_m2(const float* metah, const float* mw2, const float* mb2,
                     const float* xlist, const float* embout, float* xcat) {
  int i = blockIdx.x * 256 + threadIdx.x;
  if (i >= cB * 1920) return;
  int b = i / 1920, j = i - b * 1920;
  if (j < 1280) {
    float acc = mb2[j];
    const float* mh = metah + b * 512;
    for (int k = 0; k < 512; k++) acc += mh[k] * mw2[k * 1280 + j];
    int g = j >> 8, jj = j & 255;
    xcat[b * 1920 + j] = acc * xlist[(g * cB + b) * 256 + jj];
  } else {
    int jj = j - 1280;
    int g = jj >> 7, r = jj & 127;
    xcat[b * 1920 + j] = embout[(g * 100 + 2 * b + (r >> 6)) * 64 + (r & 63)];
  }
}

__global__ void k_l12(const float* xcat, const float* l1w, const float* l1b,
                      const float* l2w, const float* l2b, float* out) {
  int b = blockIdx.x;
  int t = threadIdx.x;
  __shared__ float sHH[128];
  float acc = l1b[t];
  const float* xc = xcat + b * 1920;
  for (int i = 0; i < 1920; i++) acc += xc[i] * l1w[i * 128 + t];
  if (acc < 0.0f) acc = 0.0f;
  sHH[t] = acc * l2w[t];
  __syncthreads();
  for (int s = 64; s > 0; s >>= 1) {
    if (t < s) sHH[t] += sHH[t + s];
    __syncthreads();
  }
  if (t == 0) out[b] = sHH[0] + l2b[0];
}

extern "C" void kernel_launch(void* const* d_in, const int* in_sizes, int n_in,
                              void* d_out, int out_size, void* d_ws, size_t ws_size,
                              hipStream_t stream) {
  const float* x      = (const float*)d_in[0];
  const int* ei       = (const int*)d_in[1];
  const int* et       = (const int*)d_in[2];
  const int* cen      = (const int*)d_in[3];
  const int* tt       = (const int*)d_in[4];
  const float* lab    = (const float*)d_in[5];
  const float* emb    = (const float*)d_in[6];
  const float* basis0 = (const float*)d_in[7];
  const float* comp0  = (const float*)d_in[8];
  const float* root0  = (const float*)d_in[9];
  const float* bias0  = (const float*)d_in[10];
  const float* basisR = (const float*)d_in[11];
  const float* compR  = (const float*)d_in[12];
  const float* rootR  = (const float*)d_in[13];
  const float* biasR  = (const float*)d_in[14];
  const float* pos    = (const float*)d_in[15];
  const float* Qw     = (const float*)d_in[16];
  const float* Kw     = (const float*)d_in[17];
  const float* Vw     = (const float*)d_in[18];
  const float* convW  = (const float*)d_in[19];
  const float* convb  = (const float*)d_in[20];
  const float* aw1    = (const float*)d_in[21];
  const float* ab1    = (const float*)d_in[22];
  const float* aw2    = (const float*)d_in[23];
  const float* mw1    = (const float*)d_in[24];
  const float* mb1    = (const float*)d_in[25];
  const float* mw2    = (const float*)d_in[26];
  const float* mb2    = (const float*)d_in[27];
  const float* l1w    = (const float*)d_in[28];
  const float* l1b    = (const float*)d_in[29];
  const float* l2w    = (const float*)d_in[30];
  const float* l2b    = (const float*)d_in[31];
  float* out          = (float*)d_out;
  char* p = (char*)d_ws;
  (void)in_sizes; (void)n_in; (void)out_size;

  if (ws_size >= FP_NEED) {
    int*   uidx   = (int*)(p + FP_UIDX);
    int*   bsumA  = (int*)(p + FP_BSUM);
    float* xlist  = (float*)(p + FP_XLIST);
    float* embout = (float*)(p + FP_EMBOUT);
    float* attK   = (float*)(p + FP_ATTK);
    float* metah  = (float*)(p + FP_METAH);
    float* xcat   = (float*)(p + FP_XCAT);
    float* sAg    = (float*)(p + FP_SAG);
    int*   inv    = (int*)(p + FP_INV);
    int*   clsA   = (int*)(p + FP_CLS);
    float* h_a    = (float*)(p + FP_HA);
    float* h_b    = (float*)(p + FP_HB);
    int*   curA   = (int*)(p + FP_CUR);
    int*   offA   = (int*)(p + FP_OFF);
    int*   permA  = (int*)(p + FP_PERM);
    float* invcA  = (float*)(p + FP_INVC);

    bool pruned  = (ws_size >= FP2_NEED);
    bool batched = (ws_size >= FP3_NEED);   // implies pruned
    int* markA  = pruned ? (int*)(p + FP2_MARK) : nullptr;
    int* listA  = pruned ? (int*)(p + FP2_LIST) : nullptr;
    int* cntA   = pruned ? (int*)(p + FP2_CNT) : nullptr;
    int* counts = pruned ? (int*)(p + FP2_COUNTS) : nullptr;
    float* hA5  = batched ? (float*)(p + FP3_HA) : nullptr;
    float* hB5  = batched ? (float*)(p + FP3_HB) : nullptr;
    // hatt: tier2 aliases hA5 (dead after gathers); else spans h_a..curA.
    float* hatt = batched ? hA5 : h_a;

    k_uidx<<<cG * 2, 256, 0, stream>>>(x, uidx);
    k_prepB<<<cG * NBLK, 256, 0, stream>>>(x, clsA, curA, markA, inv);
    k_mkinv<<<1, 512, 0, stream>>>(uidx, inv);   // after prepB's inv=-1 init
    k_histgB<<<cG * NBLK, 256, 0, stream>>>(ei, et, curA);
    k_bsumB<<<cG * NBLK, 256, 0, stream>>>(curA, bsumA);
    k_bscanB<<<cG, 1024, 0, stream>>>(bsumA);
    k_mkoffB<<<cG * NBLK, 256, 0, stream>>>(curA, offA, bsumA, invcA);
    k_scatterB<<<cG * NBLK, 256, 0, stream>>>(ei, et, clsA, curA, permA);

    if (pruned) {
      k_mark<<<cG, 128, 0, stream>>>(uidx, markA, listA, cntA, counts);
      for (int k = 1; k <= 3; k++) {
        k_expand<<<cG * EXB, 256, 0, stream>>>(offA, curA, permA, markA, listA,
                                               cntA, counts, k);
        k_snap<<<1, 64, 0, stream>>>(counts, cntA, k);
      }
    }

    if (batched) {
      // one launch per layer across all 5 graphs (independent chains)
      k_gather0B<<<cG * GB0, 256, 0, stream>>>(offA, curA, permA, invcA, clsA,
                                               basis0, comp0, root0, bias0, hB5,
                                               inv, xlist, listA, counts);
      float* hinB = hB5;
      float* houB = hA5;
      for (int l = 0; l < 3; l++) {
        k_gatherRB<<<cG * GB0, 256, 0, stream>>>(offA, curA, permA, invcA, hinB,
                                                 basisR + l * 2048, compR + l * 10,
                                                 rootR + l * 1024, biasR + l * 32,
                                                 houB, inv, xlist, l + 1, listA,
                                                 counts, 2 - l);
        float* tmp = hinB; hinB = houB; houB = tmp;
      }
    } else {
      for (int g = 0; g < cG; g++) {
        const int*   offg  = offA + (long long)g * cNR;
        const int*   curg  = curA + (long long)g * cNR;
        const int*   permg = permA + (long long)g * cE;
        const float* invcg = invcA + (long long)g * cE;
        const int*   clsg  = clsA + (long long)g * cN;
        const int*   invg  = inv + (long long)g * cN;
        const int*   listg = pruned ? (listA + (long long)g * cN) : nullptr;
        const int* c0 = pruned ? (counts + g * 4 + 3) : nullptr;
        k_gather0<<<GB0, 256, 0, stream>>>(offg, curg, permg, invcg, clsg, basis0,
                                           comp0, root0, bias0, h_b, invg, xlist,
                                           listg, c0);
        float* hin = h_b;
        float* hou = h_a;
        for (int l = 0; l < 3; l++) {
          const int* cl = pruned ? (counts + g * 4 + (2 - l)) : nullptr;
          k_gatherR<<<GB0, 256, 0, stream>>>(offg, curg, permg, invcg, hin,
                                             basisR + l * 2048, compR + l * 10,
                                             rootR + l * 1024, biasR + l * 32, hou,
                                             invg, xlist, l + 1, listg, cl);
          float* tmp = hin; hin = hou; hou = tmp;
        }
      }
    }

    // single launches: all 500 gb in one grid (hatt is full-size here)
    k_attn2<<<2000, 256, 0, stream>>>(tt, emb, pos, Qw, Kw, Vw, hatt, 0);
    k_conv<<<500, 512, 0, stream>>>(hatt, tt, cen, emb, pos, convW, convb, sAg, 0);
    k_tw<<<500, 256, 0, stream>>>(sAg, tt, lab, emb, embout);

    k_att1<<<cB * cG, 256, 0, stream>>>(xlist, aw1, ab1, aw2, attK);
    k_hm<<<cB, 256, 0, stream>>>(attK, xlist, mw1, mb1, metah);
    k_m2<<<375, 256, 0, stream>>>(metah, mw2, mb2, xlist, embout, xcat);
    k_l12<<<cB, 128, 0, stream>>>(xcat, l1w, l1b, l2w, l2b, out);
    return;
  }

  // ---------------- fallback: exact R5 layout & schedule ----------------
  int*   uidx   = (int*)(p);
  int*   clsb   = (int*)(p + 4096);
  int*   cur    = (int*)(p + 208896);
  int*   off    = (int*)(p + 1212416);
  int*   perm   = (int*)(p + 2215936);
  float* invc   = (float*)(p + 3219456);
  int*   bsum   = (int*)(p + 4222976);
  float* xlist  = (float*)(p + 4227072);
  float* embout = (float*)(p + 4741120);
  float* attK   = (float*)(p + 4870144);
  float* metah  = (float*)(p + 4874240);
  float* xcat   = (float*)(p + 4980736);
  char*  arena  = p + 5368832;
  float* h_a    = (float*)(arena);
  float* h_b    = (float*)(arena + 6400000);
  float* hatt   = (float*)(arena);
  float* sAg    = (float*)(p + 4874240);

  k_uidx<<<cG * 2, 256, 0, stream>>>(x, uidx);

  for (int g = 0; g < cG; g++) {
    const int* eis = ei + (long long)g * 2 * cE;
    const int* eid = eis + cE;
    const int* etg = et + (long long)g * cE;
    const float* xg = x + (long long)g * cN * 4;
    k_prep<<<NBLK, 256, 0, stream>>>(xg, clsb, cur);
    k_histg<<<NBLK, 256, 0, stream>>>(eid, etg, cur);
    k_bsum<<<NBLK, 256, 0, stream>>>(cur, bsum);
    k_bscan<<<1, 1024, 0, stream>>>(bsum);
    k_mkoff<<<NBLK, 256, 0, stream>>>(cur, off, bsum);
    k_scatter<<<NBLK, 256, 0, stream>>>(eis, eid, etg, clsb, cur, perm);
    k_invc<<<NBLK, 256, 0, stream>>>(off, cur, invc);
    k_gather0<<<GB0, 256, 0, stream>>>(off, cur, perm, invc, clsb, basis0, comp0,
                                       root0, bias0, h_b, nullptr, nullptr,
                                       nullptr, nullptr);
    k_extract<<<13, 256, 0, stream>>>(h_b, uidx, xlist, g, 0);
    float* hin = h_b;
    float* hou = h_a;
    for (int l = 0; l < 3; l++) {
      k_gatherR<<<GB0, 256, 0, stream>>>(off, cur, perm, invc, hin,
                                         basisR + l * 2048, compR + l * 10,
                                         rootR + l * 1024, biasR + l * 32, hou,
                                         nullptr, nullptr, 0, nullptr, nullptr);
      k_extract<<<13, 256, 0, stream>>>(hou, uidx, xlist, g, l + 1);
      float* tmp = hin; hin = hou; hou = tmp;
    }
  }

  for (int c = 0; c < 2; c++) {
    k_attn2<<<1000, 256, 0, stream>>>(tt, emb, pos, Qw, Kw, Vw, hatt, c * 250);
    k_conv<<<250, 512, 0, stream>>>(hatt, tt, cen, emb, pos, convW, convb, sAg,
                                    c * 250);
  }
  k_tw<<<500, 256, 0, stream>>>(sAg, tt, lab, emb, embout);

  k_att1<<<cB * cG, 256, 0, stream>>>(xlist, aw1, ab1, aw2, attK);
  k_hm<<<cB, 256, 0, stream>>>(attK, xlist, mw1, mb1, metah);
  k_m2<<<375, 256, 0, stream>>>(metah, mw2, mb2, xlist, embout, xcat);
  k_l12<<<cB, 128, 0, stream>>>(xcat, l1w, l1b, l2w, l2b, out);
}